// Round 2
// baseline (1764.738 us; speedup 1.0000x reference)
//
#include <hip/hip_runtime.h>
#include <hip/hip_bf16.h>
#include <math.h>

#define N_B 4
#define H_H 12
#define T_T 1024
#define D_H 64
#define F_F 266
#define N_H 48          // N_B*H_H
#define TM_ 128
#define KSEL 98304u     // kk*T*H = 8*1024*12
#define PER_BATCH 1572864  // H*T*TM
#define FCHUNK 14
#define NCHUNK 19       // 19*14 = 266

static __device__ __forceinline__ float waveSum(float v){
  for(int o=32;o;o>>=1) v += __shfl_xor(v,o,64);
  return v;
}
static __device__ __forceinline__ float waveMax(float v){
  for(int o=32;o;o>>=1) v = fmaxf(v,__shfl_xor(v,o,64));
  return v;
}

#define DN_C 0.35355339059327373f   // 64^-0.25 = 2^-1.5
#define DIAG_C 0.0625f              // 0.5 * 64^-0.5
#define RATIO_C 0.06131393394849658f // 266^-0.5
#define EPS_C 1e-4f

// ---------------- Kernel A: per-(head, t-chunk) max of dd for keys ----------
__global__ __launch_bounds__(256) void kmax_kern(
    const float* __restrict__ kfa, const float* __restrict__ pm,
    float* __restrict__ keymax){
  int head = blockIdx.x, tc = blockIdx.y;
  __shared__ float xs[64][65];
  __shared__ float red[4];
  const float* xp = kfa + ((size_t)head*T_T + (size_t)tc*64)*D_H;
  for(int i=threadIdx.x;i<64*64;i+=256) xs[i>>6][i&63] = xp[i];
  __syncthreads();
  int lane = threadIdx.x&63, w = threadIdx.x>>6;
  float mx = -3.4e38f;
  for(int f=w; f<F_F; f+=4){
    const float* pr = pm + f*D_H;
    float s0=0,s1=0,s2=0,s3=0;
    for(int d=0; d<64; d+=4){
      s0 += xs[lane][d]*pr[d];   s1 += xs[lane][d+1]*pr[d+1];
      s2 += xs[lane][d+2]*pr[d+2]; s3 += xs[lane][d+3]*pr[d+3];
    }
    mx = fmaxf(mx, DN_C*((s0+s1)+(s2+s3)));
  }
  mx = waveMax(mx);
  if(lane==0) red[w]=mx;
  __syncthreads();
  if(threadIdx.x==0)
    keymax[head*16+tc] = fmaxf(fmaxf(red[0],red[1]),fmaxf(red[2],red[3]));
}

// ---------------- Kernel B: key features -> ctx[head][f][d], ksum[head][f] --
__global__ __launch_bounds__(256) void keyfeat_kern(
    const float* __restrict__ kfa, const float* __restrict__ pm,
    const float* __restrict__ mask, const float* __restrict__ keymax,
    float* __restrict__ ctx, float* __restrict__ ksum){
  int head = blockIdx.x, fc = blockIdx.y;
  int f0 = fc*FCHUNK, nf = FCHUNK;
  int n = head / H_H;
  __shared__ float pms[FCHUNK*64];
  __shared__ float xs[64][65];
  __shared__ float ctxs[FCHUNK][64];
  __shared__ float ksums[FCHUNK];
  float m = keymax[head*16];
  for(int i=1;i<16;i++) m = fmaxf(m, keymax[head*16+i]);
  for(int i=threadIdx.x;i<FCHUNK*64;i+=256) ((float*)ctxs)[i]=0.f;
  for(int i=threadIdx.x;i<FCHUNK;i+=256) ksums[i]=0.f;
  for(int i=threadIdx.x;i<nf*64;i+=256) pms[i] = pm[f0*64+i];
  int lane = threadIdx.x&63, w = threadIdx.x>>6;
  const float* mrow = mask + n*T_T;
  for(int tc=0;tc<16;tc++){
    __syncthreads();
    const float* xp = kfa + ((size_t)head*T_T + (size_t)tc*64)*D_H;
    for(int i=threadIdx.x;i<64*64;i+=256) xs[i>>6][i&63]=xp[i];
    __syncthreads();
    float diag=0.f;
    for(int d=0;d<64;d++){ float xv=xs[lane][d]; diag += xv*xv; }
    diag *= DIAG_C;
    int tg = tc*64 + lane;
    float vfac = (mrow[tg] > -1.0f) ? 1.f : 0.f;
    for(int fl=w; fl<nf; fl+=4){
      const float* pr = pms + fl*64;
      float s0=0,s1=0,s2=0,s3=0;
      for(int d=0;d<64;d+=4){
        s0+=xs[lane][d]*pr[d];   s1+=xs[lane][d+1]*pr[d+1];
        s2+=xs[lane][d+2]*pr[d+2]; s3+=xs[lane][d+3]*pr[d+3];
      }
      float dd = DN_C*((s0+s1)+(s2+s3));
      float kp = RATIO_C*(expf(dd - diag - m) + EPS_C);
      float tot = waveSum(kp);
      if(lane==0) ksums[fl] += tot;
      float kv = kp*vfac;
      kv += __shfl_down(kv,4,64); kv += __shfl_down(kv,2,64); kv += __shfl_down(kv,1,64);
      if((lane&15)==0) ctxs[fl][tg>>4] += kv;   // only t%16==0 lanes (t//8 even)
    }
  }
  __syncthreads();
  float* co = ctx + ((size_t)head*F_F + f0)*64;
  for(int i=threadIdx.x;i<nf*64;i+=256) co[i] = ((float*)ctxs)[i];
  float* ko = ksum + head*F_F + f0;
  for(int i=threadIdx.x;i<nf;i+=256) ko[i] = ksums[i];
}

// ---------------- Kernel C: query features + pcl --------------------------
// thread = (row, f-slice): 4 adjacent lanes share a row, each owns f ≡ fs mod 4
__global__ __launch_bounds__(256) void qfeat_kern(
    const float* __restrict__ qfa, const float* __restrict__ pm,
    const float* __restrict__ ctx, const float* __restrict__ ksum,
    float* __restrict__ pcl){
  int head = blockIdx.x, tc = blockIdx.y;   // grid (48,16), 256 threads
  int rl = threadIdx.x >> 2, fs = threadIdx.x & 3;
  int t = tc*64 + rl;
  const float* xp = qfa + ((size_t)head*T_T + t)*D_H;
  float4 xr[16];
  #pragma unroll
  for(int kk=0;kk<16;kk++) xr[kk] = ((const float4*)xp)[kk];
  float diag = 0.f;
  #pragma unroll
  for(int kk=0;kk<16;kk++)
    diag += xr[kk].x*xr[kk].x + xr[kk].y*xr[kk].y + xr[kk].z*xr[kk].z + xr[kk].w*xr[kk].w;
  diag *= DIAG_C;
  int nf = (269 - fs) >> 2;              // 67,67,66,66
  const float* pf = pm + (size_t)fs*64;
  // sweep 1: row max of dd over this slice
  float m = -3.4e38f;
  for(int fi=0; fi<nf; fi++){
    const float4* pr = (const float4*)(pf + (size_t)fi*256);
    float s0=0,s1=0,s2=0,s3=0;
    #pragma unroll
    for(int kk=0;kk<16;kk++){ float4 w4 = pr[kk];
      s0+=xr[kk].x*w4.x; s1+=xr[kk].y*w4.y; s2+=xr[kk].z*w4.z; s3+=xr[kk].w*w4.w; }
    m = fmaxf(m, DN_C*((s0+s1)+(s2+s3)));
  }
  m = fmaxf(m, __shfl_xor(m,1,64));
  m = fmaxf(m, __shfl_xor(m,2,64));
  // sweep 2: qp, denominator, pcl accumulation over this slice
  float4 acc[16];
  #pragma unroll
  for(int kk=0;kk<16;kk++) acc[kk] = make_float4(0.f,0.f,0.f,0.f);
  float den = 0.f;
  const float* ksb = ksum + head*F_F;
  const float* ctb = ctx + (size_t)head*F_F*64;
  for(int fi=0; fi<nf; fi++){
    int f = fs + 4*fi;
    const float4* pr = (const float4*)(pf + (size_t)fi*256);
    float s0=0,s1=0,s2=0,s3=0;
    #pragma unroll
    for(int kk=0;kk<16;kk++){ float4 w4 = pr[kk];
      s0+=xr[kk].x*w4.x; s1+=xr[kk].y*w4.y; s2+=xr[kk].z*w4.z; s3+=xr[kk].w*w4.w; }
    float dd = DN_C*((s0+s1)+(s2+s3));
    float qp = RATIO_C*(expf(dd - diag - m) + EPS_C);
    den += qp*ksb[f];
    const float4* cr = (const float4*)(ctb + (size_t)f*64);
    #pragma unroll
    for(int kk=0;kk<16;kk++){ float4 c4=cr[kk];
      acc[kk].x+=qp*c4.x; acc[kk].y+=qp*c4.y; acc[kk].z+=qp*c4.z; acc[kk].w+=qp*c4.w; }
  }
  // butterfly-combine the 4 f-slices (all 4 lanes end with full sums)
  den += __shfl_xor(den,1,64);
  den += __shfl_xor(den,2,64);
  #pragma unroll
  for(int kk=0;kk<16;kk++){
    acc[kk].x += __shfl_xor(acc[kk].x,1,64); acc[kk].x += __shfl_xor(acc[kk].x,2,64);
    acc[kk].y += __shfl_xor(acc[kk].y,1,64); acc[kk].y += __shfl_xor(acc[kk].y,2,64);
    acc[kk].z += __shfl_xor(acc[kk].z,1,64); acc[kk].z += __shfl_xor(acc[kk].z,2,64);
    acc[kk].w += __shfl_xor(acc[kk].w,1,64); acc[kk].w += __shfl_xor(acc[kk].w,2,64);
  }
  float dinv = 1.0f/den;
  // each slice-thread stores its quarter of d (compile-time indices only)
  float4 w0,w1,w2,w3;
  if(fs==0){ w0=acc[0]; w1=acc[1]; w2=acc[2]; w3=acc[3]; }
  else if(fs==1){ w0=acc[4]; w1=acc[5]; w2=acc[6]; w3=acc[7]; }
  else if(fs==2){ w0=acc[8]; w1=acc[9]; w2=acc[10]; w3=acc[11]; }
  else { w0=acc[12]; w1=acc[13]; w2=acc[14]; w3=acc[15]; }
  float4* po = (float4*)(pcl + ((size_t)head*T_T + t)*D_H) + fs*4;
  po[0] = make_float4(w0.x*dinv, w0.y*dinv, w0.z*dinv, w0.w*dinv);
  po[1] = make_float4(w1.x*dinv, w1.y*dinv, w1.z*dinv, w1.w*dinv);
  po[2] = make_float4(w2.x*dinv, w2.y*dinv, w2.z*dinv, w2.w*dinv);
  po[3] = make_float4(w3.x*dinv, w3.y*dinv, w3.z*dinv, w3.w*dinv);
}

// ---------------- Kernel D: MLP + LN + GELU + score + softmax -------------
__global__ __launch_bounds__(256) void mlp_kern(
    const float* __restrict__ pcl, const float* __restrict__ v,
    const float* __restrict__ mask,
    const float* __restrict__ encw, const float* __restrict__ encb,
    const float* __restrict__ lng, const float* __restrict__ lnb,
    const float* __restrict__ decw, const float* __restrict__ decb,
    float* __restrict__ probsout, float* __restrict__ scoreout){
  int head = blockIdx.x, tblk = blockIdx.y;   // grid (48,32)
  int t0 = tblk*32;
  int n = head / H_H;
  __shared__ float pvs[32][129];
  __shared__ float wts[32][128];
  __shared__ float h1s[32][129];
  const float* pclrow = pcl + ((size_t)head*T_T + t0)*D_H;
  const float* vrow   = v   + ((size_t)head*T_T + t0)*D_H;
  for(int i=threadIdx.x;i<32*64;i+=256){
    int r=i>>6, c=i&63;
    pvs[r][c]   = pclrow[i];
    pvs[r][64+c]= vrow[i];
  }
  int tl = threadIdx.x>>3, g = threadIdx.x&7;  // row, col-group
  float acc[16];
  #pragma unroll
  for(int jj=0;jj<16;jj++) acc[jj] = encb[g+8*jj];
  for(int kc=0;kc<4;kc++){
    __syncthreads();
    for(int i=threadIdx.x;i<32*128;i+=256) ((float*)wts)[i] = encw[kc*32*128 + i];
    __syncthreads();
    for(int k=0;k<32;k++){
      float x = pvs[tl][kc*32+k];
      #pragma unroll
      for(int jj=0;jj<16;jj++) acc[jj] += x*wts[k][g+8*jj];
    }
  }
  // LayerNorm (two-pass, matches reference)
  float s1=0;
  #pragma unroll
  for(int jj=0;jj<16;jj++) s1+=acc[jj];
  for(int o=1;o<8;o<<=1) s1 += __shfl_xor(s1,o,64);
  float mu = s1*(1.0f/128.0f);
  float s2=0;
  #pragma unroll
  for(int jj=0;jj<16;jj++){ float d=acc[jj]-mu; s2+=d*d; }
  for(int o=1;o<8;o<<=1) s2 += __shfl_xor(s2,o,64);
  float var = s2*(1.0f/128.0f);
  float denom = sqrtf(var+1e-5f);
  #pragma unroll
  for(int jj=0;jj<16;jj++){
    int j=g+8*jj;
    float hv = (acc[jj]-mu)/denom*lng[j]+lnb[j];
    hv = hv*0.5f*(1.0f+erff(hv*0.70710678118654752f));  // exact gelu
    h1s[tl][j]=hv;
  }
  float acc2[16];
  #pragma unroll
  for(int jj=0;jj<16;jj++) acc2[jj]=decb[g+8*jj];
  for(int kc=0;kc<4;kc++){
    __syncthreads();
    for(int i=threadIdx.x;i<32*128;i+=256) ((float*)wts)[i]=decw[kc*32*128+i];
    __syncthreads();
    for(int k=0;k<32;k++){
      float x=h1s[tl][kc*32+k];
      #pragma unroll
      for(int jj=0;jj<16;jj++) acc2[jj]+=x*wts[k][g+8*jj];
    }
  }
  // masked softmax (rmask = mask[..., j*8])
  const float* mrow = mask + n*T_T;
  float sm[16]; float mx=-3.4e38f;
  #pragma unroll
  for(int jj=0;jj<16;jj++){
    int j=g+8*jj;
    float rm = mrow[j*8];
    float val = (rm < -1.0f) ? -10000.0f : acc2[jj];
    sm[jj]=val; mx=fmaxf(mx,val);
  }
  for(int o=1;o<8;o<<=1) mx=fmaxf(mx,__shfl_xor(mx,o,64));
  float Z=0;
  #pragma unroll
  for(int jj=0;jj<16;jj++){ sm[jj]=expf(sm[jj]-mx); Z+=sm[jj]; }
  for(int o=1;o<8;o<<=1) Z+=__shfl_xor(Z,o,64);
  float zi=1.0f/Z;
  size_t rbase=((size_t)head*T_T + t0+tl)*TM_;
  #pragma unroll
  for(int jj=0;jj<16;jj++){
    int j=g+8*jj;
    probsout[rbase+j]=sm[jj]*zi;
    scoreout[rbase+j]=acc2[jj];
  }
}

// ---------------- Kernel E: per-row KL + MSE ------------------------------
__global__ __launch_bounds__(256) void loss_kern(
    const float* __restrict__ truth, const float* __restrict__ mask,
    const float* __restrict__ score, float* __restrict__ klrow,
    float* __restrict__ mserow){
  int row = blockIdx.x;               // head*1024 + t
  int n = row / (H_H*T_T);
  __shared__ float a[1024];
  __shared__ float mk[1024];
  __shared__ float sc[128];
  __shared__ float red4[4];
  const float* ar = truth + (size_t)row*T_T;
  const float* mr = mask + n*T_T;
  const float* sr = score + (size_t)row*TM_;
  if(threadIdx.x < 256){
    ((float4*)a)[threadIdx.x]  = ((const float4*)ar)[threadIdx.x];
    ((float4*)mk)[threadIdx.x] = ((const float4*)mr)[threadIdx.x];
  }
  for(int i=threadIdx.x;i<128;i+=256) sc[i]=sr[i];
  __syncthreads();
  float ma=-3.4e38f, ms=-3.4e38f;
  for(int j=threadIdx.x;j<1024;j+=256){
    ma=fmaxf(ma,a[j]+mk[j]);
    ms=fmaxf(ms,sc[j>>3]+mk[j]);
  }
  ma = waveMax(ma);
  if((threadIdx.x&63)==0) red4[threadIdx.x>>6]=ma;
  __syncthreads();
  ma = fmaxf(fmaxf(red4[0],red4[1]),fmaxf(red4[2],red4[3]));
  __syncthreads();
  ms = waveMax(ms);
  if((threadIdx.x&63)==0) red4[threadIdx.x>>6]=ms;
  __syncthreads();
  ms = fmaxf(fmaxf(red4[0],red4[1]),fmaxf(red4[2],red4[3]));
  __syncthreads();
  float Za=0, Zs=0;
  for(int j=threadIdx.x;j<1024;j+=256){
    Za += expf(a[j]+mk[j]-ma);
    Zs += expf(sc[j>>3]+mk[j]-ms);
  }
  Za = waveSum(Za);
  if((threadIdx.x&63)==0) red4[threadIdx.x>>6]=Za;
  __syncthreads();
  Za = (red4[0]+red4[1])+(red4[2]+red4[3]);
  __syncthreads();
  Zs = waveSum(Zs);
  if((threadIdx.x&63)==0) red4[threadIdx.x>>6]=Zs;
  __syncthreads();
  Zs = (red4[0]+red4[1])+(red4[2]+red4[3]);
  __syncthreads();
  float lZs = logf(Zs);
  float kl=0, mse=0;
  for(int j=threadIdx.x;j<1024;j+=256){
    float mkj = mk[j];
    float scj = sc[j>>3];
    float aj = a[j];
    if(mkj > -1.0f){
      float pt = expf(aj+mkj-ma)/Za;
      float logpt = logf(fmaxf(pt,1e-12f));
      float logp = (scj+mkj-ms) - lZs;
      kl += pt*(logpt-logp);
    }
    float sv = (mkj < -1.0f)?0.f:scj;
    float av = (mkj < -1.0f)?0.f:aj;
    float d = sv-av; mse += d*d;
  }
  kl = waveSum(kl);
  if((threadIdx.x&63)==0) red4[threadIdx.x>>6]=kl;
  __syncthreads();
  kl = (red4[0]+red4[1])+(red4[2]+red4[3]);
  __syncthreads();
  mse = waveSum(mse);
  if((threadIdx.x&63)==0) red4[threadIdx.x>>6]=mse;
  __syncthreads();
  if(threadIdx.x==0){
    mse = (red4[0]+red4[1])+(red4[2]+red4[3]);
    klrow[row]=kl; mserow[row]=mse;
  }
}

// ---------------- Kernel F: final loss ------------------------------------
__global__ __launch_bounds__(256) void finloss_kern(
    const float* __restrict__ klrow, const float* __restrict__ mserow,
    const float* __restrict__ mask, float* __restrict__ out0){
  __shared__ double reds[256];
  double kls=0, mses=0;
  for(int i=threadIdx.x;i<N_H*T_T;i+=256){ kls+=(double)klrow[i]; mses+=(double)mserow[i]; }
  double vcnt=0;
  for(int i=threadIdx.x;i<N_B*T_T;i+=256) if(mask[i] > -1.0f) vcnt+=1.0;
  reds[threadIdx.x]=kls; __syncthreads();
  for(int o=128;o;o>>=1){ if(threadIdx.x<o) reds[threadIdx.x]+=reds[threadIdx.x+o]; __syncthreads(); }
  double klsum = reds[0]; __syncthreads();
  reds[threadIdx.x]=mses; __syncthreads();
  for(int o=128;o;o>>=1){ if(threadIdx.x<o) reds[threadIdx.x]+=reds[threadIdx.x+o]; __syncthreads(); }
  double msesum = reds[0]; __syncthreads();
  reds[threadIdx.x]=vcnt; __syncthreads();
  for(int o=128;o;o>>=1){ if(threadIdx.x<o) reds[threadIdx.x]+=reds[threadIdx.x+o]; __syncthreads(); }
  if(threadIdx.x==0){
    double denom = reds[0] * (double)(H_H*T_T);
    double loss = klsum/denom*0.25 + msesum/((double)N_B*H_H*T_T*T_T);
    out0[0]=(float)loss;
  }
}

// ---------------- Top-k pipeline ------------------------------------------
__global__ void topk_init(unsigned* __restrict__ hist, unsigned* __restrict__ state,
                          unsigned* __restrict__ tiecnt){
  int i = blockIdx.x*256+threadIdx.x;
  if(i < 4*256) hist[i]=0;
  if(i < 4){ state[i*4+0]=0u; state[i*4+1]=KSEL; state[i*4+2]=0u; tiecnt[i]=0u; }
}

__global__ __launch_bounds__(256) void topk_hist(
    const float* __restrict__ probs, const float* __restrict__ mask,
    const unsigned* __restrict__ state, unsigned* __restrict__ hist, int level){
  __shared__ unsigned lh[4*256];
  for(int i=threadIdx.x;i<1024;i+=256) lh[i]=0;
  __syncthreads();
  unsigned pmask = (level==0)?0u:(0xFFFFFFFFu << (32-8*level));
  unsigned pref[4];
  for(int b=0;b<4;b++) pref[b]=state[b*4+0] & pmask;
  int shift = 24-8*level;
  size_t total = (size_t)N_B*PER_BATCH;
  for(size_t idx = (size_t)blockIdx.x*256+threadIdx.x; idx < total; idx += (size_t)gridDim.x*256){
    int b = (int)(idx / PER_BATCH);
    unsigned r = (unsigned)(idx - (size_t)b*PER_BATCH);
    int t = (int)((r>>7)&1023u);
    float val = probs[idx];
    if(!(mask[b*T_T+t] > -1.0f)) val = 0.0f;
    unsigned u = __float_as_uint(val);
    if((u & pmask) == pref[b]) atomicAdd(&lh[b*256+((u>>shift)&255u)],1u);
  }
  __syncthreads();
  for(int i=threadIdx.x;i<1024;i+=256){
    unsigned c = lh[i];
    if(c) atomicAdd(&hist[i], c);
  }
}

__global__ void topk_scan(unsigned* __restrict__ hist, unsigned* __restrict__ state, int level){
  int b = blockIdx.x;
  if(threadIdx.x==0){
    const unsigned* h = hist + b*256;
    unsigned remk = state[b*4+1];
    unsigned cum = 0; int sel=0;
    for(int bin=255; bin>=0; bin--){
      unsigned c = h[bin];
      if(remk <= cum + c){ sel=bin; break; }
      cum += c;
    }
    state[b*4+0] |= ((unsigned)sel) << (24-8*level);
    state[b*4+1] = remk - cum;
    state[b*4+2] += cum;
  }
  __syncthreads();
  for(int i=threadIdx.x;i<256;i+=blockDim.x) hist[b*256+i]=0;
}

__global__ __launch_bounds__(256) void topk_write(
    const float* __restrict__ probs, const float* __restrict__ mask,
    const unsigned* __restrict__ state, float* __restrict__ pam,
    unsigned* __restrict__ ties, unsigned* __restrict__ tiecnt){
  unsigned thr[4];
  for(int b=0;b<4;b++) thr[b]=state[b*4+0];
  size_t total=(size_t)N_B*PER_BATCH;
  for(size_t idx=(size_t)blockIdx.x*256+threadIdx.x; idx<total; idx += (size_t)gridDim.x*256){
    int b = (int)(idx / PER_BATCH);
    unsigned r = (unsigned)(idx - (size_t)b*PER_BATCH);
    int t = (int)((r>>7)&1023u);
    float val = probs[idx];
    if(!(mask[b*T_T+t] > -1.0f)) val=0.0f;
    unsigned u=__float_as_uint(val);
    float o = -10000.0f;
    if(u > thr[b]) o = 0.0f;
    else if(u == thr[b]){
      unsigned pos = atomicAdd(&tiecnt[b],1u);
      if(pos < 65536u) ties[(size_t)b*65536+pos]=r;
    }
    pam[idx]=o;
  }
}

__global__ __launch_bounds__(256) void topk_ties(
    const unsigned* __restrict__ state, const unsigned* __restrict__ ties,
    const unsigned* __restrict__ tiecnt, float* __restrict__ pam){
  int b = blockIdx.x;
  unsigned needed = state[b*4+1];
  unsigned nt = min(tiecnt[b], 65536u);
  __shared__ unsigned redu[256];
  __shared__ unsigned lohi[2];
  if(threadIdx.x==0){ lohi[0]=0u; lohi[1]=PER_BATCH; }
  __syncthreads();
  if(needed == 0 || nt == 0) return;
  while(true){
    __syncthreads();
    unsigned lo=lohi[0], hi=lohi[1];
    if(hi-lo<=1u) break;
    unsigned mid=(lo+hi)>>1;
    unsigned c=0;
    for(unsigned i=threadIdx.x;i<nt;i+=256) c += (ties[(size_t)b*65536+i] < mid)?1u:0u;
    redu[threadIdx.x]=c; __syncthreads();
    for(int o=128;o;o>>=1){ if(threadIdx.x<o) redu[threadIdx.x]+=redu[threadIdx.x+o]; __syncthreads(); }
    if(threadIdx.x==0){ if(redu[0]>=needed) lohi[1]=mid; else lohi[0]=mid; }
  }
  __syncthreads();
  unsigned X=lohi[1];
  for(unsigned i=threadIdx.x;i<nt;i+=256){
    unsigned r=ties[(size_t)b*65536+i];
    if(r < X) pam[(size_t)b*PER_BATCH + r]=0.0f;
  }
}

// ---------------- launcher ------------------------------------------------
extern "C" void kernel_launch(void* const* d_in, const int* in_sizes, int n_in,
                              void* d_out, int out_size, void* d_ws, size_t ws_size,
                              hipStream_t stream) {
  const float* v     = (const float*)d_in[2];
  const float* qfa   = (const float*)d_in[3];
  const float* kfa   = (const float*)d_in[4];
  const float* mask  = (const float*)d_in[8];
  const float* truth = (const float*)d_in[9];
  const float* pm    = (const float*)d_in[11];
  const float* encw  = (const float*)d_in[12];
  const float* encb  = (const float*)d_in[13];
  const float* lng   = (const float*)d_in[14];
  const float* lnb   = (const float*)d_in[15];
  const float* decw  = (const float*)d_in[16];
  const float* decb  = (const float*)d_in[17];
  float* out = (float*)d_out;
  float* ws  = (float*)d_ws;

  float* keymax = ws;                          // 768
  float* ctx    = ws + 1024;                   // 48*266*64 = 817152
  float* ksum   = ctx + (size_t)N_H*F_F*64;    // 12768
  float* klrow  = ksum + N_H*F_F;              // 49152
  float* mserow = klrow + N_H*T_T;             // 49152
  unsigned* hist   = (unsigned*)(mserow + N_H*T_T); // 1024
  unsigned* state  = hist + 1024;              // 16
  unsigned* tiecnt = state + 16;               // 4
  unsigned* ties   = tiecnt + 12;              // 4*65536

  float* pcl   = out + 1;
  float* probs = pcl + (size_t)N_H*T_T*D_H;
  float* pam   = probs + (size_t)N_H*T_T*TM_;

  kmax_kern<<<dim3(N_H,16),256,0,stream>>>(kfa, pm, keymax);
  keyfeat_kern<<<dim3(N_H,NCHUNK),256,0,stream>>>(kfa, pm, mask, keymax, ctx, ksum);
  qfeat_kern<<<dim3(N_H,16),256,0,stream>>>(qfa, pm, ctx, ksum, pcl);
  mlp_kern<<<dim3(N_H,32),256,0,stream>>>(pcl, v, mask, encw, encb, lng, lnb,
                                          decw, decb, probs, pam /*score*/);
  loss_kern<<<N_H*T_T,256,0,stream>>>(truth, mask, pam /*score*/, klrow, mserow);
  finloss_kern<<<1,256,0,stream>>>(klrow, mserow, mask, out);
  topk_init<<<4,256,0,stream>>>(hist, state, tiecnt);
  for(int lvl=0;lvl<4;lvl++){
    topk_hist<<<2048,256,0,stream>>>(probs, mask, state, hist, lvl);
    topk_scan<<<4,64,0,stream>>>(hist, state, lvl);
  }
  topk_write<<<2048,256,0,stream>>>(probs, mask, state, pam, ties, tiecnt);
  topk_ties<<<4,256,0,stream>>>(state, ties, tiecnt, pam);
}

// Round 3
// 899.535 us; speedup vs baseline: 1.9618x; 1.9618x over previous
//
#include <hip/hip_runtime.h>
#include <hip/hip_bf16.h>
#include <math.h>

#define N_B 4
#define H_H 12
#define T_T 1024
#define D_H 64
#define F_F 266
#define N_H 48          // N_B*H_H
#define TM_ 128
#define KSEL 98304u     // kk*T*H = 8*1024*12
#define PER_BATCH 1572864  // H*T*TM
#define FCHUNK 14
#define NCHUNK 19       // 19*14 = 266

static __device__ __forceinline__ float waveSum(float v){
  for(int o=32;o;o>>=1) v += __shfl_xor(v,o,64);
  return v;
}
static __device__ __forceinline__ float waveMax(float v){
  for(int o=32;o;o>>=1) v = fmaxf(v,__shfl_xor(v,o,64));
  return v;
}

#define DN_C 0.35355339059327373f   // 64^-0.25 = 2^-1.5
#define DIAG_C 0.0625f              // 0.5 * 64^-0.5
#define RATIO_C 0.06131393394849658f // 266^-0.5
#define EPS_C 1e-4f

// ---------------- Kernel A: per-(head, t-chunk) max of dd for keys ----------
__global__ __launch_bounds__(256) void kmax_kern(
    const float* __restrict__ kfa, const float* __restrict__ pm,
    float* __restrict__ keymax){
  int head = blockIdx.x, tc = blockIdx.y;
  __shared__ float xs[64][65];
  __shared__ float red[4];
  const float* xp = kfa + ((size_t)head*T_T + (size_t)tc*64)*D_H;
  for(int i=threadIdx.x;i<64*64;i+=256) xs[i>>6][i&63] = xp[i];
  __syncthreads();
  int lane = threadIdx.x&63, w = threadIdx.x>>6;
  float mx = -3.4e38f;
  for(int f=w; f<F_F; f+=4){
    const float* pr = pm + f*D_H;
    float s0=0,s1=0,s2=0,s3=0;
    for(int d=0; d<64; d+=4){
      s0 += xs[lane][d]*pr[d];   s1 += xs[lane][d+1]*pr[d+1];
      s2 += xs[lane][d+2]*pr[d+2]; s3 += xs[lane][d+3]*pr[d+3];
    }
    mx = fmaxf(mx, DN_C*((s0+s1)+(s2+s3)));
  }
  mx = waveMax(mx);
  if(lane==0) red[w]=mx;
  __syncthreads();
  if(threadIdx.x==0)
    keymax[head*16+tc] = fmaxf(fmaxf(red[0],red[1]),fmaxf(red[2],red[3]));
}

// ---------------- Kernel B: key features -> ctx[head][f][d], ksum[head][f] --
__global__ __launch_bounds__(256) void keyfeat_kern(
    const float* __restrict__ kfa, const float* __restrict__ pm,
    const float* __restrict__ mask, const float* __restrict__ keymax,
    float* __restrict__ ctx, float* __restrict__ ksum){
  int head = blockIdx.x, fc = blockIdx.y;
  int f0 = fc*FCHUNK, nf = FCHUNK;
  int n = head / H_H;
  __shared__ float pms[FCHUNK*64];
  __shared__ float xs[64][65];
  __shared__ float ctxs[FCHUNK][64];
  __shared__ float ksums[FCHUNK];
  float m = keymax[head*16];
  for(int i=1;i<16;i++) m = fmaxf(m, keymax[head*16+i]);
  for(int i=threadIdx.x;i<FCHUNK*64;i+=256) ((float*)ctxs)[i]=0.f;
  for(int i=threadIdx.x;i<FCHUNK;i+=256) ksums[i]=0.f;
  for(int i=threadIdx.x;i<nf*64;i+=256) pms[i] = pm[f0*64+i];
  int lane = threadIdx.x&63, w = threadIdx.x>>6;
  const float* mrow = mask + n*T_T;
  for(int tc=0;tc<16;tc++){
    __syncthreads();
    const float* xp = kfa + ((size_t)head*T_T + (size_t)tc*64)*D_H;
    for(int i=threadIdx.x;i<64*64;i+=256) xs[i>>6][i&63]=xp[i];
    __syncthreads();
    float diag=0.f;
    for(int d=0;d<64;d++){ float xv=xs[lane][d]; diag += xv*xv; }
    diag *= DIAG_C;
    int tg = tc*64 + lane;
    float vfac = (mrow[tg] > -1.0f) ? 1.f : 0.f;
    for(int fl=w; fl<nf; fl+=4){
      const float* pr = pms + fl*64;
      float s0=0,s1=0,s2=0,s3=0;
      for(int d=0;d<64;d+=4){
        s0+=xs[lane][d]*pr[d];   s1+=xs[lane][d+1]*pr[d+1];
        s2+=xs[lane][d+2]*pr[d+2]; s3+=xs[lane][d+3]*pr[d+3];
      }
      float dd = DN_C*((s0+s1)+(s2+s3));
      float kp = RATIO_C*(expf(dd - diag - m) + EPS_C);
      float tot = waveSum(kp);
      if(lane==0) ksums[fl] += tot;
      float kv = kp*vfac;
      kv += __shfl_down(kv,4,64); kv += __shfl_down(kv,2,64); kv += __shfl_down(kv,1,64);
      if((lane&15)==0) ctxs[fl][tg>>4] += kv;   // only t%16==0 lanes (t//8 even)
    }
  }
  __syncthreads();
  float* co = ctx + ((size_t)head*F_F + f0)*64;
  for(int i=threadIdx.x;i<nf*64;i+=256) co[i] = ((float*)ctxs)[i];
  float* ko = ksum + head*F_F + f0;
  for(int i=threadIdx.x;i<nf;i+=256) ko[i] = ksums[i];
}

// ---------------- Kernel C: query features + pcl --------------------------
// thread = (row, f-slice); LDS-staged pm/ctx chunks (rows padded to 68 floats
// so the 4 f-slice lanes land on distinct banks). Arithmetic sequence is
// bitwise-identical to the validated R2 kernel.
__global__ __launch_bounds__(256) void qfeat_kern(
    const float* __restrict__ qfa, const float* __restrict__ pm,
    const float* __restrict__ ctx, const float* __restrict__ ksum,
    float* __restrict__ pcl){
  int head = blockIdx.x, tc = blockIdx.y;   // grid (48,16), 256 threads
  int rl = threadIdx.x >> 2, fs = threadIdx.x & 3;
  int t = tc*64 + rl;
  __shared__ float pms[56*68];
  __shared__ float ctxs[56*68];
  __shared__ float ksums[56];
  const float* xp = qfa + ((size_t)head*T_T + t)*D_H;
  float4 xr[16];
  #pragma unroll
  for(int kk=0;kk<16;kk++) xr[kk] = ((const float4*)xp)[kk];
  float diag = 0.f;
  #pragma unroll
  for(int kk=0;kk<16;kk++)
    diag += xr[kk].x*xr[kk].x + xr[kk].y*xr[kk].y + xr[kk].z*xr[kk].z + xr[kk].w*xr[kk].w;
  diag *= DIAG_C;
  // sweep 1: row max of dd over this slice (chunked pm staging)
  float m = -3.4e38f;
  for(int c=0;c<5;c++){
    int f0 = c*56, CF = min(56, F_F-f0);
    __syncthreads();
    for(int i=threadIdx.x;i<CF*16;i+=256){
      int fl=i>>4, d4=i&15;
      ((float4*)(pms+fl*68))[d4] = ((const float4*)(pm+(size_t)(f0+fl)*64))[d4];
    }
    __syncthreads();
    int nj = (CF - fs + 3)>>2;
    for(int j=0;j<nj;j++){
      const float4* pr = (const float4*)(pms + (fs+4*j)*68);
      float s0=0,s1=0,s2=0,s3=0;
      #pragma unroll
      for(int kk=0;kk<16;kk++){ float4 w4 = pr[kk];
        s0+=xr[kk].x*w4.x; s1+=xr[kk].y*w4.y; s2+=xr[kk].z*w4.z; s3+=xr[kk].w*w4.w; }
      m = fmaxf(m, DN_C*((s0+s1)+(s2+s3)));
    }
  }
  m = fmaxf(m, __shfl_xor(m,1,64));
  m = fmaxf(m, __shfl_xor(m,2,64));
  // sweep 2: qp, denominator, pcl accumulation (chunked pm+ctx+ksum staging)
  float4 acc[16];
  #pragma unroll
  for(int kk=0;kk<16;kk++) acc[kk] = make_float4(0.f,0.f,0.f,0.f);
  float den = 0.f;
  for(int c=0;c<5;c++){
    int f0 = c*56, CF = min(56, F_F-f0);
    __syncthreads();
    for(int i=threadIdx.x;i<CF*16;i+=256){
      int fl=i>>4, d4=i&15;
      ((float4*)(pms+fl*68))[d4]  = ((const float4*)(pm+(size_t)(f0+fl)*64))[d4];
      ((float4*)(ctxs+fl*68))[d4] = ((const float4*)(ctx+((size_t)head*F_F+f0+fl)*64))[d4];
    }
    for(int i=threadIdx.x;i<CF;i+=256) ksums[i]=ksum[head*F_F+f0+i];
    __syncthreads();
    int nj = (CF - fs + 3)>>2;
    for(int j=0;j<nj;j++){
      int fl = fs+4*j;
      const float4* pr = (const float4*)(pms + fl*68);
      float s0=0,s1=0,s2=0,s3=0;
      #pragma unroll
      for(int kk=0;kk<16;kk++){ float4 w4 = pr[kk];
        s0+=xr[kk].x*w4.x; s1+=xr[kk].y*w4.y; s2+=xr[kk].z*w4.z; s3+=xr[kk].w*w4.w; }
      float dd = DN_C*((s0+s1)+(s2+s3));
      float qp = RATIO_C*(expf(dd - diag - m) + EPS_C);
      den += qp*ksums[fl];
      const float4* cr = (const float4*)(ctxs + fl*68);
      #pragma unroll
      for(int kk=0;kk<16;kk++){ float4 c4=cr[kk];
        acc[kk].x+=qp*c4.x; acc[kk].y+=qp*c4.y; acc[kk].z+=qp*c4.z; acc[kk].w+=qp*c4.w; }
    }
  }
  // butterfly-combine the 4 f-slices (all 4 lanes end with full sums)
  den += __shfl_xor(den,1,64);
  den += __shfl_xor(den,2,64);
  #pragma unroll
  for(int kk=0;kk<16;kk++){
    acc[kk].x += __shfl_xor(acc[kk].x,1,64); acc[kk].x += __shfl_xor(acc[kk].x,2,64);
    acc[kk].y += __shfl_xor(acc[kk].y,1,64); acc[kk].y += __shfl_xor(acc[kk].y,2,64);
    acc[kk].z += __shfl_xor(acc[kk].z,1,64); acc[kk].z += __shfl_xor(acc[kk].z,2,64);
    acc[kk].w += __shfl_xor(acc[kk].w,1,64); acc[kk].w += __shfl_xor(acc[kk].w,2,64);
  }
  float dinv = 1.0f/den;
  // each slice-thread stores its quarter of d (compile-time indices only)
  float4 w0,w1,w2,w3;
  if(fs==0){ w0=acc[0]; w1=acc[1]; w2=acc[2]; w3=acc[3]; }
  else if(fs==1){ w0=acc[4]; w1=acc[5]; w2=acc[6]; w3=acc[7]; }
  else if(fs==2){ w0=acc[8]; w1=acc[9]; w2=acc[10]; w3=acc[11]; }
  else { w0=acc[12]; w1=acc[13]; w2=acc[14]; w3=acc[15]; }
  float4* po = (float4*)(pcl + ((size_t)head*T_T + t)*D_H) + fs*4;
  po[0] = make_float4(w0.x*dinv, w0.y*dinv, w0.z*dinv, w0.w*dinv);
  po[1] = make_float4(w1.x*dinv, w1.y*dinv, w1.z*dinv, w1.w*dinv);
  po[2] = make_float4(w2.x*dinv, w2.y*dinv, w2.z*dinv, w2.w*dinv);
  po[3] = make_float4(w3.x*dinv, w3.y*dinv, w3.z*dinv, w3.w*dinv);
}

// ---------------- Kernel D: MLP + LN + GELU + score + softmax -------------
__global__ __launch_bounds__(256) void mlp_kern(
    const float* __restrict__ pcl, const float* __restrict__ v,
    const float* __restrict__ mask,
    const float* __restrict__ encw, const float* __restrict__ encb,
    const float* __restrict__ lng, const float* __restrict__ lnb,
    const float* __restrict__ decw, const float* __restrict__ decb,
    float* __restrict__ probsout, float* __restrict__ scoreout){
  int head = blockIdx.x, tblk = blockIdx.y;   // grid (48,32)
  int t0 = tblk*32;
  int n = head / H_H;
  __shared__ float pvs[32][129];
  __shared__ float wts[32][128];
  __shared__ float h1s[32][129];
  const float* pclrow = pcl + ((size_t)head*T_T + t0)*D_H;
  const float* vrow   = v   + ((size_t)head*T_T + t0)*D_H;
  for(int i=threadIdx.x;i<32*64;i+=256){
    int r=i>>6, c=i&63;
    pvs[r][c]   = pclrow[i];
    pvs[r][64+c]= vrow[i];
  }
  int tl = threadIdx.x>>3, g = threadIdx.x&7;  // row, col-group
  float acc[16];
  #pragma unroll
  for(int jj=0;jj<16;jj++) acc[jj] = encb[g+8*jj];
  for(int kc=0;kc<4;kc++){
    __syncthreads();
    for(int i=threadIdx.x;i<32*128;i+=256) ((float*)wts)[i] = encw[kc*32*128 + i];
    __syncthreads();
    for(int k=0;k<32;k++){
      float x = pvs[tl][kc*32+k];
      #pragma unroll
      for(int jj=0;jj<16;jj++) acc[jj] += x*wts[k][g+8*jj];
    }
  }
  // LayerNorm (two-pass, matches reference)
  float s1=0;
  #pragma unroll
  for(int jj=0;jj<16;jj++) s1+=acc[jj];
  for(int o=1;o<8;o<<=1) s1 += __shfl_xor(s1,o,64);
  float mu = s1*(1.0f/128.0f);
  float s2=0;
  #pragma unroll
  for(int jj=0;jj<16;jj++){ float d=acc[jj]-mu; s2+=d*d; }
  for(int o=1;o<8;o<<=1) s2 += __shfl_xor(s2,o,64);
  float var = s2*(1.0f/128.0f);
  float denom = sqrtf(var+1e-5f);
  #pragma unroll
  for(int jj=0;jj<16;jj++){
    int j=g+8*jj;
    float hv = (acc[jj]-mu)/denom*lng[j]+lnb[j];
    hv = hv*0.5f*(1.0f+erff(hv*0.70710678118654752f));  // exact gelu
    h1s[tl][j]=hv;
  }
  float acc2[16];
  #pragma unroll
  for(int jj=0;jj<16;jj++) acc2[jj]=decb[g+8*jj];
  for(int kc=0;kc<4;kc++){
    __syncthreads();
    for(int i=threadIdx.x;i<32*128;i+=256) ((float*)wts)[i]=decw[kc*32*128+i];
    __syncthreads();
    for(int k=0;k<32;k++){
      float x=h1s[tl][kc*32+k];
      #pragma unroll
      for(int jj=0;jj<16;jj++) acc2[jj]+=x*wts[k][g+8*jj];
    }
  }
  // masked softmax (rmask = mask[..., j*8])
  const float* mrow = mask + n*T_T;
  float sm[16]; float mx=-3.4e38f;
  #pragma unroll
  for(int jj=0;jj<16;jj++){
    int j=g+8*jj;
    float rm = mrow[j*8];
    float val = (rm < -1.0f) ? -10000.0f : acc2[jj];
    sm[jj]=val; mx=fmaxf(mx,val);
  }
  for(int o=1;o<8;o<<=1) mx=fmaxf(mx,__shfl_xor(mx,o,64));
  float Z=0;
  #pragma unroll
  for(int jj=0;jj<16;jj++){ sm[jj]=expf(sm[jj]-mx); Z+=sm[jj]; }
  for(int o=1;o<8;o<<=1) Z+=__shfl_xor(Z,o,64);
  float zi=1.0f/Z;
  size_t rbase=((size_t)head*T_T + t0+tl)*TM_;
  #pragma unroll
  for(int jj=0;jj<16;jj++){
    int j=g+8*jj;
    probsout[rbase+j]=sm[jj]*zi;
    scoreout[rbase+j]=acc2[jj];
  }
}

// ---------------- Kernel E: per-row KL + MSE ------------------------------
__global__ __launch_bounds__(256) void loss_kern(
    const float* __restrict__ truth, const float* __restrict__ mask,
    const float* __restrict__ score, float* __restrict__ klrow,
    float* __restrict__ mserow){
  int row = blockIdx.x;               // head*1024 + t
  int n = row / (H_H*T_T);
  __shared__ float a[1024];
  __shared__ float mk[1024];
  __shared__ float sc[128];
  __shared__ float red4[4];
  const float* ar = truth + (size_t)row*T_T;
  const float* mr = mask + n*T_T;
  const float* sr = score + (size_t)row*TM_;
  if(threadIdx.x < 256){
    ((float4*)a)[threadIdx.x]  = ((const float4*)ar)[threadIdx.x];
    ((float4*)mk)[threadIdx.x] = ((const float4*)mr)[threadIdx.x];
  }
  for(int i=threadIdx.x;i<128;i+=256) sc[i]=sr[i];
  __syncthreads();
  float ma=-3.4e38f, ms=-3.4e38f;
  for(int j=threadIdx.x;j<1024;j+=256){
    ma=fmaxf(ma,a[j]+mk[j]);
    ms=fmaxf(ms,sc[j>>3]+mk[j]);
  }
  ma = waveMax(ma);
  if((threadIdx.x&63)==0) red4[threadIdx.x>>6]=ma;
  __syncthreads();
  ma = fmaxf(fmaxf(red4[0],red4[1]),fmaxf(red4[2],red4[3]));
  __syncthreads();
  ms = waveMax(ms);
  if((threadIdx.x&63)==0) red4[threadIdx.x>>6]=ms;
  __syncthreads();
  ms = fmaxf(fmaxf(red4[0],red4[1]),fmaxf(red4[2],red4[3]));
  __syncthreads();
  float Za=0, Zs=0;
  for(int j=threadIdx.x;j<1024;j+=256){
    Za += expf(a[j]+mk[j]-ma);
    Zs += expf(sc[j>>3]+mk[j]-ms);
  }
  Za = waveSum(Za);
  if((threadIdx.x&63)==0) red4[threadIdx.x>>6]=Za;
  __syncthreads();
  Za = (red4[0]+red4[1])+(red4[2]+red4[3]);
  __syncthreads();
  Zs = waveSum(Zs);
  if((threadIdx.x&63)==0) red4[threadIdx.x>>6]=Zs;
  __syncthreads();
  Zs = (red4[0]+red4[1])+(red4[2]+red4[3]);
  __syncthreads();
  float lZs = logf(Zs);
  float kl=0, mse=0;
  for(int j=threadIdx.x;j<1024;j+=256){
    float mkj = mk[j];
    float scj = sc[j>>3];
    float aj = a[j];
    if(mkj > -1.0f){
      float pt = expf(aj+mkj-ma)/Za;
      float logpt = logf(fmaxf(pt,1e-12f));
      float logp = (scj+mkj-ms) - lZs;
      kl += pt*(logpt-logp);
    }
    float sv = (mkj < -1.0f)?0.f:scj;
    float av = (mkj < -1.0f)?0.f:aj;
    float d = sv-av; mse += d*d;
  }
  kl = waveSum(kl);
  if((threadIdx.x&63)==0) red4[threadIdx.x>>6]=kl;
  __syncthreads();
  kl = (red4[0]+red4[1])+(red4[2]+red4[3]);
  __syncthreads();
  mse = waveSum(mse);
  if((threadIdx.x&63)==0) red4[threadIdx.x>>6]=mse;
  __syncthreads();
  if(threadIdx.x==0){
    mse = (red4[0]+red4[1])+(red4[2]+red4[3]);
    klrow[row]=kl; mserow[row]=mse;
  }
}

// ---------------- Kernel F: final loss ------------------------------------
__global__ __launch_bounds__(256) void finloss_kern(
    const float* __restrict__ klrow, const float* __restrict__ mserow,
    const float* __restrict__ mask, float* __restrict__ out0){
  __shared__ double reds[256];
  double kls=0, mses=0;
  for(int i=threadIdx.x;i<N_H*T_T;i+=256){ kls+=(double)klrow[i]; mses+=(double)mserow[i]; }
  double vcnt=0;
  for(int i=threadIdx.x;i<N_B*T_T;i+=256) if(mask[i] > -1.0f) vcnt+=1.0;
  reds[threadIdx.x]=kls; __syncthreads();
  for(int o=128;o;o>>=1){ if(threadIdx.x<o) reds[threadIdx.x]+=reds[threadIdx.x+o]; __syncthreads(); }
  double klsum = reds[0]; __syncthreads();
  reds[threadIdx.x]=mses; __syncthreads();
  for(int o=128;o;o>>=1){ if(threadIdx.x<o) reds[threadIdx.x]+=reds[threadIdx.x+o]; __syncthreads(); }
  double msesum = reds[0]; __syncthreads();
  reds[threadIdx.x]=vcnt; __syncthreads();
  for(int o=128;o;o>>=1){ if(threadIdx.x<o) reds[threadIdx.x]+=reds[threadIdx.x+o]; __syncthreads(); }
  if(threadIdx.x==0){
    double denom = reds[0] * (double)(H_H*T_T);
    double loss = klsum/denom*0.25 + msesum/((double)N_B*H_H*T_T*T_T);
    out0[0]=(float)loss;
  }
}

// ---------------- Top-k pipeline ------------------------------------------
__global__ void topk_init(unsigned* __restrict__ hist, unsigned* __restrict__ state,
                          unsigned* __restrict__ tiecnt){
  int i = blockIdx.x*256+threadIdx.x;
  if(i < 4*256) hist[i]=0;
  if(i < 4){ state[i*4+0]=0u; state[i*4+1]=KSEL; state[i*4+2]=0u; tiecnt[i]=0u; }
}

__global__ __launch_bounds__(256) void topk_hist(
    const float* __restrict__ probs, const float* __restrict__ mask,
    const unsigned* __restrict__ state, unsigned* __restrict__ hist, int level){
  __shared__ unsigned lh[4*256];
  for(int i=threadIdx.x;i<1024;i+=256) lh[i]=0;
  __syncthreads();
  unsigned pmask = (level==0)?0u:(0xFFFFFFFFu << (32-8*level));
  unsigned pref[4];
  for(int b=0;b<4;b++) pref[b]=state[b*4+0] & pmask;
  int shift = 24-8*level;
  size_t total = (size_t)N_B*PER_BATCH;
  for(size_t idx = (size_t)blockIdx.x*256+threadIdx.x; idx < total; idx += (size_t)gridDim.x*256){
    int b = (int)(idx / PER_BATCH);
    unsigned r = (unsigned)(idx - (size_t)b*PER_BATCH);
    int t = (int)((r>>7)&1023u);
    float val = probs[idx];
    if(!(mask[b*T_T+t] > -1.0f)) val = 0.0f;
    unsigned u = __float_as_uint(val);
    if((u & pmask) == pref[b]) atomicAdd(&lh[b*256+((u>>shift)&255u)],1u);
  }
  __syncthreads();
  for(int i=threadIdx.x;i<1024;i+=256){
    unsigned c = lh[i];
    if(c) atomicAdd(&hist[i], c);
  }
}

__global__ void topk_scan(unsigned* __restrict__ hist, unsigned* __restrict__ state, int level){
  int b = blockIdx.x;
  if(threadIdx.x==0){
    const unsigned* h = hist + b*256;
    unsigned remk = state[b*4+1];
    unsigned cum = 0; int sel=0;
    for(int bin=255; bin>=0; bin--){
      unsigned c = h[bin];
      if(remk <= cum + c){ sel=bin; break; }
      cum += c;
    }
    state[b*4+0] |= ((unsigned)sel) << (24-8*level);
    state[b*4+1] = remk - cum;
    state[b*4+2] += cum;
  }
  __syncthreads();
  for(int i=threadIdx.x;i<256;i+=blockDim.x) hist[b*256+i]=0;
}

__global__ __launch_bounds__(256) void topk_write(
    const float* __restrict__ probs, const float* __restrict__ mask,
    const unsigned* __restrict__ state, float* __restrict__ pam,
    unsigned* __restrict__ ties, unsigned* __restrict__ tiecnt){
  unsigned thr[4];
  for(int b=0;b<4;b++) thr[b]=state[b*4+0];
  size_t total=(size_t)N_B*PER_BATCH;
  for(size_t idx=(size_t)blockIdx.x*256+threadIdx.x; idx<total; idx += (size_t)gridDim.x*256){
    int b = (int)(idx / PER_BATCH);
    unsigned r = (unsigned)(idx - (size_t)b*PER_BATCH);
    int t = (int)((r>>7)&1023u);
    float val = probs[idx];
    if(!(mask[b*T_T+t] > -1.0f)) val=0.0f;
    unsigned u=__float_as_uint(val);
    float o = -10000.0f;
    if(u > thr[b]) o = 0.0f;
    else if(u == thr[b]){
      unsigned pos = atomicAdd(&tiecnt[b],1u);
      if(pos < 65536u) ties[(size_t)b*65536+pos]=r;
    }
    pam[idx]=o;
  }
}

__global__ __launch_bounds__(256) void topk_ties(
    const unsigned* __restrict__ state, const unsigned* __restrict__ ties,
    const unsigned* __restrict__ tiecnt, float* __restrict__ pam){
  int b = blockIdx.x;
  unsigned needed = state[b*4+1];
  unsigned nt = min(tiecnt[b], 65536u);
  __shared__ unsigned redu[256];
  __shared__ unsigned lohi[2];
  if(threadIdx.x==0){ lohi[0]=0u; lohi[1]=PER_BATCH; }
  __syncthreads();
  if(needed == 0 || nt == 0) return;
  while(true){
    __syncthreads();
    unsigned lo=lohi[0], hi=lohi[1];
    if(hi-lo<=1u) break;
    unsigned mid=(lo+hi)>>1;
    unsigned c=0;
    for(unsigned i=threadIdx.x;i<nt;i+=256) c += (ties[(size_t)b*65536+i] < mid)?1u:0u;
    redu[threadIdx.x]=c; __syncthreads();
    for(int o=128;o;o>>=1){ if(threadIdx.x<o) redu[threadIdx.x]+=redu[threadIdx.x+o]; __syncthreads(); }
    if(threadIdx.x==0){ if(redu[0]>=needed) lohi[1]=mid; else lohi[0]=mid; }
  }
  __syncthreads();
  unsigned X=lohi[1];
  for(unsigned i=threadIdx.x;i<nt;i+=256){
    unsigned r=ties[(size_t)b*65536+i];
    if(r < X) pam[(size_t)b*PER_BATCH + r]=0.0f;
  }
}

// ---------------- launcher ------------------------------------------------
extern "C" void kernel_launch(void* const* d_in, const int* in_sizes, int n_in,
                              void* d_out, int out_size, void* d_ws, size_t ws_size,
                              hipStream_t stream) {
  const float* v     = (const float*)d_in[2];
  const float* qfa   = (const float*)d_in[3];
  const float* kfa   = (const float*)d_in[4];
  const float* mask  = (const float*)d_in[8];
  const float* truth = (const float*)d_in[9];
  const float* pm    = (const float*)d_in[11];
  const float* encw  = (const float*)d_in[12];
  const float* encb  = (const float*)d_in[13];
  const float* lng   = (const float*)d_in[14];
  const float* lnb   = (const float*)d_in[15];
  const float* decw  = (const float*)d_in[16];
  const float* decb  = (const float*)d_in[17];
  float* out = (float*)d_out;
  float* ws  = (float*)d_ws;

  float* keymax = ws;                          // 768
  float* ctx    = ws + 1024;                   // 48*266*64 = 817152
  float* ksum   = ctx + (size_t)N_H*F_F*64;    // 12768
  float* klrow  = ksum + N_H*F_F;              // 49152
  float* mserow = klrow + N_H*T_T;             // 49152
  unsigned* hist   = (unsigned*)(mserow + N_H*T_T); // 1024
  unsigned* state  = hist + 1024;              // 16
  unsigned* tiecnt = state + 16;               // 4
  unsigned* ties   = tiecnt + 12;              // 4*65536

  float* pcl   = out + 1;
  float* probs = pcl + (size_t)N_H*T_T*D_H;
  float* pam   = probs + (size_t)N_H*T_T*TM_;

  kmax_kern<<<dim3(N_H,16),256,0,stream>>>(kfa, pm, keymax);
  keyfeat_kern<<<dim3(N_H,NCHUNK),256,0,stream>>>(kfa, pm, mask, keymax, ctx, ksum);
  qfeat_kern<<<dim3(N_H,16),256,0,stream>>>(qfa, pm, ctx, ksum, pcl);
  mlp_kern<<<dim3(N_H,32),256,0,stream>>>(pcl, v, mask, encw, encb, lng, lnb,
                                          decw, decb, probs, pam /*score*/);
  loss_kern<<<N_H*T_T,256,0,stream>>>(truth, mask, pam /*score*/, klrow, mserow);
  finloss_kern<<<1,256,0,stream>>>(klrow, mserow, mask, out);
  topk_init<<<4,256,0,stream>>>(hist, state, tiecnt);
  for(int lvl=0;lvl<4;lvl++){
    topk_hist<<<2048,256,0,stream>>>(probs, mask, state, hist, lvl);
    topk_scan<<<4,64,0,stream>>>(hist, state, lvl);
  }
  topk_write<<<2048,256,0,stream>>>(probs, mask, state, pam, ties, tiecnt);
  topk_ties<<<4,256,0,stream>>>(state, ties, tiecnt, pam);
}

// Round 4
// 816.396 us; speedup vs baseline: 2.1616x; 1.1018x over previous
//
#include <hip/hip_runtime.h>
#include <hip/hip_bf16.h>
#include <math.h>

#define N_B 4
#define H_H 12
#define T_T 1024
#define D_H 64
#define F_F 266
#define N_H 48          // N_B*H_H
#define TM_ 128
#define KSEL 98304u     // kk*T*H = 8*1024*12
#define PER_BATCH 1572864  // H*T*TM
#define FCHUNK 14
#define NCHUNK 19       // 19*14 = 266

static __device__ __forceinline__ float waveSum(float v){
  for(int o=32;o;o>>=1) v += __shfl_xor(v,o,64);
  return v;
}
static __device__ __forceinline__ float waveMax(float v){
  for(int o=32;o;o>>=1) v = fmaxf(v,__shfl_xor(v,o,64));
  return v;
}

#define DN_C 0.35355339059327373f   // 64^-0.25 = 2^-1.5
#define DIAG_C 0.0625f              // 0.5 * 64^-0.5
#define RATIO_C 0.06131393394849658f // 266^-0.5
#define EPS_C 1e-4f

// ---------------- Kernel A: per-(head, t-chunk) max of dd for keys ----------
__global__ __launch_bounds__(256) void kmax_kern(
    const float* __restrict__ kfa, const float* __restrict__ pm,
    float* __restrict__ keymax){
  int head = blockIdx.x, tc = blockIdx.y;
  __shared__ float xs[64][65];
  __shared__ float red[4];
  const float* xp = kfa + ((size_t)head*T_T + (size_t)tc*64)*D_H;
  for(int i=threadIdx.x;i<64*64;i+=256) xs[i>>6][i&63] = xp[i];
  __syncthreads();
  int lane = threadIdx.x&63, w = threadIdx.x>>6;
  float mx = -3.4e38f;
  for(int f=w; f<F_F; f+=4){
    const float* pr = pm + f*D_H;
    float s0=0,s1=0,s2=0,s3=0;
    for(int d=0; d<64; d+=4){
      s0 += xs[lane][d]*pr[d];   s1 += xs[lane][d+1]*pr[d+1];
      s2 += xs[lane][d+2]*pr[d+2]; s3 += xs[lane][d+3]*pr[d+3];
    }
    mx = fmaxf(mx, DN_C*((s0+s1)+(s2+s3)));
  }
  mx = waveMax(mx);
  if(lane==0) red[w]=mx;
  __syncthreads();
  if(threadIdx.x==0)
    keymax[head*16+tc] = fmaxf(fmaxf(red[0],red[1]),fmaxf(red[2],red[3]));
}

// ---------------- Kernel B: key features -> ctx[head][f][d], ksum[head][f] --
__global__ __launch_bounds__(256) void keyfeat_kern(
    const float* __restrict__ kfa, const float* __restrict__ pm,
    const float* __restrict__ mask, const float* __restrict__ keymax,
    float* __restrict__ ctx, float* __restrict__ ksum){
  int head = blockIdx.x, fc = blockIdx.y;
  int f0 = fc*FCHUNK, nf = FCHUNK;
  int n = head / H_H;
  __shared__ float pms[FCHUNK*64];
  __shared__ float xs[64][65];
  __shared__ float ctxs[FCHUNK][64];
  __shared__ float ksums[FCHUNK];
  float m = keymax[head*16];
  for(int i=1;i<16;i++) m = fmaxf(m, keymax[head*16+i]);
  for(int i=threadIdx.x;i<FCHUNK*64;i+=256) ((float*)ctxs)[i]=0.f;
  for(int i=threadIdx.x;i<FCHUNK;i+=256) ksums[i]=0.f;
  for(int i=threadIdx.x;i<nf*64;i+=256) pms[i] = pm[f0*64+i];
  int lane = threadIdx.x&63, w = threadIdx.x>>6;
  const float* mrow = mask + n*T_T;
  for(int tc=0;tc<16;tc++){
    __syncthreads();
    const float* xp = kfa + ((size_t)head*T_T + (size_t)tc*64)*D_H;
    for(int i=threadIdx.x;i<64*64;i+=256) xs[i>>6][i&63]=xp[i];
    __syncthreads();
    float diag=0.f;
    for(int d=0;d<64;d++){ float xv=xs[lane][d]; diag += xv*xv; }
    diag *= DIAG_C;
    int tg = tc*64 + lane;
    float vfac = (mrow[tg] > -1.0f) ? 1.f : 0.f;
    for(int fl=w; fl<nf; fl+=4){
      const float* pr = pms + fl*64;
      float s0=0,s1=0,s2=0,s3=0;
      for(int d=0;d<64;d+=4){
        s0+=xs[lane][d]*pr[d];   s1+=xs[lane][d+1]*pr[d+1];
        s2+=xs[lane][d+2]*pr[d+2]; s3+=xs[lane][d+3]*pr[d+3];
      }
      float dd = DN_C*((s0+s1)+(s2+s3));
      float kp = RATIO_C*(expf(dd - diag - m) + EPS_C);
      float tot = waveSum(kp);
      if(lane==0) ksums[fl] += tot;
      float kv = kp*vfac;
      kv += __shfl_down(kv,4,64); kv += __shfl_down(kv,2,64); kv += __shfl_down(kv,1,64);
      if((lane&15)==0) ctxs[fl][tg>>4] += kv;   // only t%16==0 lanes (t//8 even)
    }
  }
  __syncthreads();
  float* co = ctx + ((size_t)head*F_F + f0)*64;
  for(int i=threadIdx.x;i<nf*64;i+=256) co[i] = ((float*)ctxs)[i];
  float* ko = ksum + head*F_F + f0;
  for(int i=threadIdx.x;i<nf;i+=256) ko[i] = ksums[i];
}

// ---------------- Kernel C: query features + pcl --------------------------
// thread = (row, f-slice); LDS-staged pm/ctx chunks (rows padded to 68 floats
// so the 4 f-slice lanes land on distinct banks).
__global__ __launch_bounds__(256) void qfeat_kern(
    const float* __restrict__ qfa, const float* __restrict__ pm,
    const float* __restrict__ ctx, const float* __restrict__ ksum,
    float* __restrict__ pcl){
  int head = blockIdx.x, tc = blockIdx.y;   // grid (48,16), 256 threads
  int rl = threadIdx.x >> 2, fs = threadIdx.x & 3;
  int t = tc*64 + rl;
  __shared__ float pms[56*68];
  __shared__ float ctxs[56*68];
  __shared__ float ksums[56];
  const float* xp = qfa + ((size_t)head*T_T + t)*D_H;
  float4 xr[16];
  #pragma unroll
  for(int kk=0;kk<16;kk++) xr[kk] = ((const float4*)xp)[kk];
  float diag = 0.f;
  #pragma unroll
  for(int kk=0;kk<16;kk++)
    diag += xr[kk].x*xr[kk].x + xr[kk].y*xr[kk].y + xr[kk].z*xr[kk].z + xr[kk].w*xr[kk].w;
  diag *= DIAG_C;
  // sweep 1: row max of dd over this slice (chunked pm staging)
  float m = -3.4e38f;
  for(int c=0;c<5;c++){
    int f0 = c*56, CF = min(56, F_F-f0);
    __syncthreads();
    for(int i=threadIdx.x;i<CF*16;i+=256){
      int fl=i>>4, d4=i&15;
      ((float4*)(pms+fl*68))[d4] = ((const float4*)(pm+(size_t)(f0+fl)*64))[d4];
    }
    __syncthreads();
    int nj = (CF - fs + 3)>>2;
    for(int j=0;j<nj;j++){
      const float4* pr = (const float4*)(pms + (fs+4*j)*68);
      float s0=0,s1=0,s2=0,s3=0;
      #pragma unroll
      for(int kk=0;kk<16;kk++){ float4 w4 = pr[kk];
        s0+=xr[kk].x*w4.x; s1+=xr[kk].y*w4.y; s2+=xr[kk].z*w4.z; s3+=xr[kk].w*w4.w; }
      m = fmaxf(m, DN_C*((s0+s1)+(s2+s3)));
    }
  }
  m = fmaxf(m, __shfl_xor(m,1,64));
  m = fmaxf(m, __shfl_xor(m,2,64));
  // sweep 2: qp, denominator, pcl accumulation (chunked pm+ctx+ksum staging)
  float4 acc[16];
  #pragma unroll
  for(int kk=0;kk<16;kk++) acc[kk] = make_float4(0.f,0.f,0.f,0.f);
  float den = 0.f;
  for(int c=0;c<5;c++){
    int f0 = c*56, CF = min(56, F_F-f0);
    __syncthreads();
    for(int i=threadIdx.x;i<CF*16;i+=256){
      int fl=i>>4, d4=i&15;
      ((float4*)(pms+fl*68))[d4]  = ((const float4*)(pm+(size_t)(f0+fl)*64))[d4];
      ((float4*)(ctxs+fl*68))[d4] = ((const float4*)(ctx+((size_t)head*F_F+f0+fl)*64))[d4];
    }
    for(int i=threadIdx.x;i<CF;i+=256) ksums[i]=ksum[head*F_F+f0+i];
    __syncthreads();
    int nj = (CF - fs + 3)>>2;
    for(int j=0;j<nj;j++){
      int fl = fs+4*j;
      const float4* pr = (const float4*)(pms + fl*68);
      float s0=0,s1=0,s2=0,s3=0;
      #pragma unroll
      for(int kk=0;kk<16;kk++){ float4 w4 = pr[kk];
        s0+=xr[kk].x*w4.x; s1+=xr[kk].y*w4.y; s2+=xr[kk].z*w4.z; s3+=xr[kk].w*w4.w; }
      float dd = DN_C*((s0+s1)+(s2+s3));
      float qp = RATIO_C*(expf(dd - diag - m) + EPS_C);
      den += qp*ksums[fl];
      const float4* cr = (const float4*)(ctxs + fl*68);
      #pragma unroll
      for(int kk=0;kk<16;kk++){ float4 c4=cr[kk];
        acc[kk].x+=qp*c4.x; acc[kk].y+=qp*c4.y; acc[kk].z+=qp*c4.z; acc[kk].w+=qp*c4.w; }
    }
  }
  // butterfly-combine the 4 f-slices (all 4 lanes end with full sums)
  den += __shfl_xor(den,1,64);
  den += __shfl_xor(den,2,64);
  #pragma unroll
  for(int kk=0;kk<16;kk++){
    acc[kk].x += __shfl_xor(acc[kk].x,1,64); acc[kk].x += __shfl_xor(acc[kk].x,2,64);
    acc[kk].y += __shfl_xor(acc[kk].y,1,64); acc[kk].y += __shfl_xor(acc[kk].y,2,64);
    acc[kk].z += __shfl_xor(acc[kk].z,1,64); acc[kk].z += __shfl_xor(acc[kk].z,2,64);
    acc[kk].w += __shfl_xor(acc[kk].w,1,64); acc[kk].w += __shfl_xor(acc[kk].w,2,64);
  }
  float dinv = 1.0f/den;
  float4 w0,w1,w2,w3;
  if(fs==0){ w0=acc[0]; w1=acc[1]; w2=acc[2]; w3=acc[3]; }
  else if(fs==1){ w0=acc[4]; w1=acc[5]; w2=acc[6]; w3=acc[7]; }
  else if(fs==2){ w0=acc[8]; w1=acc[9]; w2=acc[10]; w3=acc[11]; }
  else { w0=acc[12]; w1=acc[13]; w2=acc[14]; w3=acc[15]; }
  float4* po = (float4*)(pcl + ((size_t)head*T_T + t)*D_H) + fs*4;
  po[0] = make_float4(w0.x*dinv, w0.y*dinv, w0.z*dinv, w0.w*dinv);
  po[1] = make_float4(w1.x*dinv, w1.y*dinv, w1.z*dinv, w1.w*dinv);
  po[2] = make_float4(w2.x*dinv, w2.y*dinv, w2.z*dinv, w2.w*dinv);
  po[3] = make_float4(w3.x*dinv, w3.y*dinv, w3.z*dinv, w3.w*dinv);
}

// ---------------- Kernel D: MLP + LN + GELU + score + softmax -------------
// v2: register-tiled. thread = (rowT 0..15, colT 0..15); owns rows {rowT,rowT+16}
// and cols {4*colT..+3} u {64+4*colT..+3}. Weight reads are ds_read_b128 at
// 2-way bank aliasing (free); x reads are float4 per 4 k (broadcast-16).
#define FMA4(A,s,W) {A.x+=(s)*W.x; A.y+=(s)*W.y; A.z+=(s)*W.z; A.w+=(s)*W.w;}
__global__ __launch_bounds__(256) void mlp_kern(
    const float* __restrict__ pcl, const float* __restrict__ v,
    const float* __restrict__ mask,
    const float* __restrict__ encw, const float* __restrict__ encb,
    const float* __restrict__ lng, const float* __restrict__ lnb,
    const float* __restrict__ decw, const float* __restrict__ decb,
    float* __restrict__ probsout, float* __restrict__ scoreout){
  int head = blockIdx.x, tblk = blockIdx.y;   // grid (48,32)
  int t0 = tblk*32;
  int n = head / H_H;
  __shared__ float xs[32*132];
  __shared__ float wts[32*132];
  __shared__ float h1s[32*132];
  int colT = threadIdx.x & 15, rowT = threadIdx.x >> 4;
  int r0 = rowT, r1 = rowT + 16;
  // stage x = [pcl | v] rows
  const float* pclrow = pcl + ((size_t)head*T_T + t0)*D_H;
  const float* vrow   = v   + ((size_t)head*T_T + t0)*D_H;
  for(int i=threadIdx.x;i<512;i+=256){
    int r=i>>4, q=i&15;
    ((float4*)(xs + r*132))[q]      = ((const float4*)(pclrow + r*64))[q];
    ((float4*)(xs + r*132 + 64))[q] = ((const float4*)(vrow   + r*64))[q];
  }
  // ---- GEMM1: h = x @ encw + encb ----
  float4 bias0 = ((const float4*)encb)[colT];
  float4 bias1 = ((const float4*)encb)[colT+16];
  float4 A0=bias0, A1=bias1, B0=bias0, B1=bias1;
  for(int kc=0;kc<4;kc++){
    __syncthreads();
    for(int i=threadIdx.x;i<1024;i+=256){
      int k=i>>5, q=i&31;
      ((float4*)(wts + k*132))[q] = ((const float4*)(encw + (size_t)(kc*32+k)*128))[q];
    }
    __syncthreads();
    #pragma unroll
    for(int kq=0;kq<8;kq++){
      float4 x0 = ((const float4*)(xs + r0*132 + kc*32))[kq];
      float4 x1 = ((const float4*)(xs + r1*132 + kc*32))[kq];
      #pragma unroll
      for(int kk=0;kk<4;kk++){
        const float* wrow = wts + (kq*4+kk)*132;
        float4 wa = ((const float4*)wrow)[colT];
        float4 wb = ((const float4*)wrow)[colT+16];
        float xv0 = (kk==0)?x0.x:(kk==1)?x0.y:(kk==2)?x0.z:x0.w;
        float xv1 = (kk==0)?x1.x:(kk==1)?x1.y:(kk==2)?x1.z:x1.w;
        FMA4(A0,xv0,wa); FMA4(A1,xv0,wb);
        FMA4(B0,xv1,wa); FMA4(B1,xv1,wb);
      }
    }
  }
  // ---- LayerNorm (two-pass) + GELU ----
  float g0 = ((const float4*)lng)[colT].x; // load per-element below instead
  (void)g0;
  float4 lg0 = ((const float4*)lng)[colT], lg1 = ((const float4*)lng)[colT+16];
  float4 lb0 = ((const float4*)lnb)[colT], lb1 = ((const float4*)lnb)[colT+16];
  float s0 = A0.x+A0.y+A0.z+A0.w + A1.x+A1.y+A1.z+A1.w;
  float s1 = B0.x+B0.y+B0.z+B0.w + B1.x+B1.y+B1.z+B1.w;
  for(int o=1;o<16;o<<=1){ s0 += __shfl_xor(s0,o,64); s1 += __shfl_xor(s1,o,64); }
  float mu0 = s0*(1.0f/128.0f), mu1 = s1*(1.0f/128.0f);
  float v0=0.f, v1=0.f;
  { float d;
    d=A0.x-mu0; v0+=d*d; d=A0.y-mu0; v0+=d*d; d=A0.z-mu0; v0+=d*d; d=A0.w-mu0; v0+=d*d;
    d=A1.x-mu0; v0+=d*d; d=A1.y-mu0; v0+=d*d; d=A1.z-mu0; v0+=d*d; d=A1.w-mu0; v0+=d*d;
    d=B0.x-mu1; v1+=d*d; d=B0.y-mu1; v1+=d*d; d=B0.z-mu1; v1+=d*d; d=B0.w-mu1; v1+=d*d;
    d=B1.x-mu1; v1+=d*d; d=B1.y-mu1; v1+=d*d; d=B1.z-mu1; v1+=d*d; d=B1.w-mu1; v1+=d*d; }
  for(int o=1;o<16;o<<=1){ v0 += __shfl_xor(v0,o,64); v1 += __shfl_xor(v1,o,64); }
  float den0 = sqrtf(v0*(1.0f/128.0f)+1e-5f);
  float den1 = sqrtf(v1*(1.0f/128.0f)+1e-5f);
  #define GELU(x) ((x)*0.5f*(1.0f+erff((x)*0.70710678118654752f)))
  #define LNG(a,mu,dn,g,b) GELU(((a)-(mu))/(dn)*(g)+(b))
  float4 H;
  H.x=LNG(A0.x,mu0,den0,lg0.x,lb0.x); H.y=LNG(A0.y,mu0,den0,lg0.y,lb0.y);
  H.z=LNG(A0.z,mu0,den0,lg0.z,lb0.z); H.w=LNG(A0.w,mu0,den0,lg0.w,lb0.w);
  ((float4*)(h1s + r0*132))[colT] = H;
  H.x=LNG(A1.x,mu0,den0,lg1.x,lb1.x); H.y=LNG(A1.y,mu0,den0,lg1.y,lb1.y);
  H.z=LNG(A1.z,mu0,den0,lg1.z,lb1.z); H.w=LNG(A1.w,mu0,den0,lg1.w,lb1.w);
  ((float4*)(h1s + r0*132))[colT+16] = H;
  H.x=LNG(B0.x,mu1,den1,lg0.x,lb0.x); H.y=LNG(B0.y,mu1,den1,lg0.y,lb0.y);
  H.z=LNG(B0.z,mu1,den1,lg0.z,lb0.z); H.w=LNG(B0.w,mu1,den1,lg0.w,lb0.w);
  ((float4*)(h1s + r1*132))[colT] = H;
  H.x=LNG(B1.x,mu1,den1,lg1.x,lb1.x); H.y=LNG(B1.y,mu1,den1,lg1.y,lb1.y);
  H.z=LNG(B1.z,mu1,den1,lg1.z,lb1.z); H.w=LNG(B1.w,mu1,den1,lg1.w,lb1.w);
  ((float4*)(h1s + r1*132))[colT+16] = H;
  // ---- GEMM2: score = h1 @ decw + decb ----
  bias0 = ((const float4*)decb)[colT];
  bias1 = ((const float4*)decb)[colT+16];
  A0=bias0; A1=bias1; B0=bias0; B1=bias1;
  for(int kc=0;kc<4;kc++){
    __syncthreads();
    for(int i=threadIdx.x;i<1024;i+=256){
      int k=i>>5, q=i&31;
      ((float4*)(wts + k*132))[q] = ((const float4*)(decw + (size_t)(kc*32+k)*128))[q];
    }
    __syncthreads();
    #pragma unroll
    for(int kq=0;kq<8;kq++){
      float4 x0 = ((const float4*)(h1s + r0*132 + kc*32))[kq];
      float4 x1 = ((const float4*)(h1s + r1*132 + kc*32))[kq];
      #pragma unroll
      for(int kk=0;kk<4;kk++){
        const float* wrow = wts + (kq*4+kk)*132;
        float4 wa = ((const float4*)wrow)[colT];
        float4 wb = ((const float4*)wrow)[colT+16];
        float xv0 = (kk==0)?x0.x:(kk==1)?x0.y:(kk==2)?x0.z:x0.w;
        float xv1 = (kk==0)?x1.x:(kk==1)?x1.y:(kk==2)?x1.z:x1.w;
        FMA4(A0,xv0,wa); FMA4(A1,xv0,wb);
        FMA4(B0,xv1,wa); FMA4(B1,xv1,wb);
      }
    }
  }
  // ---- masked softmax over 128 cols (rmask = mask[col*8]) ----
  const float* mrow = mask + n*T_T;
  int c0 = colT*4, c1 = colT*4 + 64;
  float rm0[4], rm1[4];
  #pragma unroll
  for(int i=0;i<4;i++){ rm0[i]=mrow[(c0+i)*8]; rm1[i]=mrow[(c1+i)*8]; }
  float sA[8], sB[8];
  sA[0]=(rm0[0]<-1.f)?-10000.f:A0.x; sA[1]=(rm0[1]<-1.f)?-10000.f:A0.y;
  sA[2]=(rm0[2]<-1.f)?-10000.f:A0.z; sA[3]=(rm0[3]<-1.f)?-10000.f:A0.w;
  sA[4]=(rm1[0]<-1.f)?-10000.f:A1.x; sA[5]=(rm1[1]<-1.f)?-10000.f:A1.y;
  sA[6]=(rm1[2]<-1.f)?-10000.f:A1.z; sA[7]=(rm1[3]<-1.f)?-10000.f:A1.w;
  sB[0]=(rm0[0]<-1.f)?-10000.f:B0.x; sB[1]=(rm0[1]<-1.f)?-10000.f:B0.y;
  sB[2]=(rm0[2]<-1.f)?-10000.f:B0.z; sB[3]=(rm0[3]<-1.f)?-10000.f:B0.w;
  sB[4]=(rm1[0]<-1.f)?-10000.f:B1.x; sB[5]=(rm1[1]<-1.f)?-10000.f:B1.y;
  sB[6]=(rm1[2]<-1.f)?-10000.f:B1.z; sB[7]=(rm1[3]<-1.f)?-10000.f:B1.w;
  float mx0=sA[0], mx1=sB[0];
  #pragma unroll
  for(int i=1;i<8;i++){ mx0=fmaxf(mx0,sA[i]); mx1=fmaxf(mx1,sB[i]); }
  for(int o=1;o<16;o<<=1){ mx0=fmaxf(mx0,__shfl_xor(mx0,o,64)); mx1=fmaxf(mx1,__shfl_xor(mx1,o,64)); }
  float Z0=0.f, Z1=0.f;
  #pragma unroll
  for(int i=0;i<8;i++){ sA[i]=expf(sA[i]-mx0); Z0+=sA[i]; sB[i]=expf(sB[i]-mx1); Z1+=sB[i]; }
  for(int o=1;o<16;o<<=1){ Z0+=__shfl_xor(Z0,o,64); Z1+=__shfl_xor(Z1,o,64); }
  float zi0=1.0f/Z0, zi1=1.0f/Z1;
  size_t rb0 = ((size_t)head*T_T + t0 + r0)*TM_;
  size_t rb1 = ((size_t)head*T_T + t0 + r1)*TM_;
  ((float4*)(probsout+rb0))[colT]    = make_float4(sA[0]*zi0,sA[1]*zi0,sA[2]*zi0,sA[3]*zi0);
  ((float4*)(probsout+rb0))[colT+16] = make_float4(sA[4]*zi0,sA[5]*zi0,sA[6]*zi0,sA[7]*zi0);
  ((float4*)(probsout+rb1))[colT]    = make_float4(sB[0]*zi1,sB[1]*zi1,sB[2]*zi1,sB[3]*zi1);
  ((float4*)(probsout+rb1))[colT+16] = make_float4(sB[4]*zi1,sB[5]*zi1,sB[6]*zi1,sB[7]*zi1);
  ((float4*)(scoreout+rb0))[colT]    = A0;
  ((float4*)(scoreout+rb0))[colT+16] = A1;
  ((float4*)(scoreout+rb1))[colT]    = B0;
  ((float4*)(scoreout+rb1))[colT+16] = B1;
}

// ---------------- Kernel E: per-row KL + MSE ------------------------------
__global__ __launch_bounds__(256) void loss_kern(
    const float* __restrict__ truth, const float* __restrict__ mask,
    const float* __restrict__ score, float* __restrict__ klrow,
    float* __restrict__ mserow){
  int row = blockIdx.x;               // head*1024 + t
  int n = row / (H_H*T_T);
  __shared__ float a[1024];
  __shared__ float mk[1024];
  __shared__ float sc[128];
  __shared__ float red4[4];
  const float* ar = truth + (size_t)row*T_T;
  const float* mr = mask + n*T_T;
  const float* sr = score + (size_t)row*TM_;
  if(threadIdx.x < 256){
    ((float4*)a)[threadIdx.x]  = ((const float4*)ar)[threadIdx.x];
    ((float4*)mk)[threadIdx.x] = ((const float4*)mr)[threadIdx.x];
  }
  for(int i=threadIdx.x;i<128;i+=256) sc[i]=sr[i];
  __syncthreads();
  float ma=-3.4e38f, ms=-3.4e38f;
  for(int j=threadIdx.x;j<1024;j+=256){
    ma=fmaxf(ma,a[j]+mk[j]);
    ms=fmaxf(ms,sc[j>>3]+mk[j]);
  }
  ma = waveMax(ma);
  if((threadIdx.x&63)==0) red4[threadIdx.x>>6]=ma;
  __syncthreads();
  ma = fmaxf(fmaxf(red4[0],red4[1]),fmaxf(red4[2],red4[3]));
  __syncthreads();
  ms = waveMax(ms);
  if((threadIdx.x&63)==0) red4[threadIdx.x>>6]=ms;
  __syncthreads();
  ms = fmaxf(fmaxf(red4[0],red4[1]),fmaxf(red4[2],red4[3]));
  __syncthreads();
  float Za=0, Zs=0;
  for(int j=threadIdx.x;j<1024;j+=256){
    Za += expf(a[j]+mk[j]-ma);
    Zs += expf(sc[j>>3]+mk[j]-ms);
  }
  Za = waveSum(Za);
  if((threadIdx.x&63)==0) red4[threadIdx.x>>6]=Za;
  __syncthreads();
  Za = (red4[0]+red4[1])+(red4[2]+red4[3]);
  __syncthreads();
  Zs = waveSum(Zs);
  if((threadIdx.x&63)==0) red4[threadIdx.x>>6]=Zs;
  __syncthreads();
  Zs = (red4[0]+red4[1])+(red4[2]+red4[3]);
  __syncthreads();
  float lZs = logf(Zs);
  float kl=0, mse=0;
  for(int j=threadIdx.x;j<1024;j+=256){
    float mkj = mk[j];
    float scj = sc[j>>3];
    float aj = a[j];
    if(mkj > -1.0f){
      float pt = expf(aj+mkj-ma)/Za;
      float logpt = logf(fmaxf(pt,1e-12f));
      float logp = (scj+mkj-ms) - lZs;
      kl += pt*(logpt-logp);
    }
    float sv = (mkj < -1.0f)?0.f:scj;
    float av = (mkj < -1.0f)?0.f:aj;
    float d = sv-av; mse += d*d;
  }
  kl = waveSum(kl);
  if((threadIdx.x&63)==0) red4[threadIdx.x>>6]=kl;
  __syncthreads();
  kl = (red4[0]+red4[1])+(red4[2]+red4[3]);
  __syncthreads();
  mse = waveSum(mse);
  if((threadIdx.x&63)==0) red4[threadIdx.x>>6]=mse;
  __syncthreads();
  if(threadIdx.x==0){
    mse = (red4[0]+red4[1])+(red4[2]+red4[3]);
    klrow[row]=kl; mserow[row]=mse;
  }
}

// ---------------- Kernel F: final loss ------------------------------------
__global__ __launch_bounds__(256) void finloss_kern(
    const float* __restrict__ klrow, const float* __restrict__ mserow,
    const float* __restrict__ mask, float* __restrict__ out0){
  __shared__ double reds[256];
  double kls=0, mses=0;
  for(int i=threadIdx.x;i<N_H*T_T;i+=256){ kls+=(double)klrow[i]; mses+=(double)mserow[i]; }
  double vcnt=0;
  for(int i=threadIdx.x;i<N_B*T_T;i+=256) if(mask[i] > -1.0f) vcnt+=1.0;
  reds[threadIdx.x]=kls; __syncthreads();
  for(int o=128;o;o>>=1){ if(threadIdx.x<o) reds[threadIdx.x]+=reds[threadIdx.x+o]; __syncthreads(); }
  double klsum = reds[0]; __syncthreads();
  reds[threadIdx.x]=mses; __syncthreads();
  for(int o=128;o;o>>=1){ if(threadIdx.x<o) reds[threadIdx.x]+=reds[threadIdx.x+o]; __syncthreads(); }
  double msesum = reds[0]; __syncthreads();
  reds[threadIdx.x]=vcnt; __syncthreads();
  for(int o=128;o;o>>=1){ if(threadIdx.x<o) reds[threadIdx.x]+=reds[threadIdx.x+o]; __syncthreads(); }
  if(threadIdx.x==0){
    double denom = reds[0] * (double)(H_H*T_T);
    double loss = klsum/denom*0.25 + msesum/((double)N_B*H_H*T_T*T_T);
    out0[0]=(float)loss;
  }
}

// ---------------- Top-k pipeline ------------------------------------------
__global__ void topk_init(unsigned* __restrict__ hist, unsigned* __restrict__ state,
                          unsigned* __restrict__ tiecnt){
  int i = blockIdx.x*256+threadIdx.x;
  if(i < 4*256) hist[i]=0;
  if(i < 4){ state[i*4+0]=0u; state[i*4+1]=KSEL; state[i*4+2]=0u; tiecnt[i]=0u; }
}

__global__ __launch_bounds__(256) void topk_hist(
    const float* __restrict__ probs, const float* __restrict__ mask,
    const unsigned* __restrict__ state, unsigned* __restrict__ hist, int level){
  __shared__ unsigned lh[4*256];
  for(int i=threadIdx.x;i<1024;i+=256) lh[i]=0;
  __syncthreads();
  unsigned pmask = (level==0)?0u:(0xFFFFFFFFu << (32-8*level));
  unsigned pref[4];
  for(int b=0;b<4;b++) pref[b]=state[b*4+0] & pmask;
  int shift = 24-8*level;
  size_t total = (size_t)N_B*PER_BATCH;
  for(size_t idx = (size_t)blockIdx.x*256+threadIdx.x; idx < total; idx += (size_t)gridDim.x*256){
    int b = (int)(idx / PER_BATCH);
    unsigned r = (unsigned)(idx - (size_t)b*PER_BATCH);
    int t = (int)((r>>7)&1023u);
    float val = probs[idx];
    if(!(mask[b*T_T+t] > -1.0f)) val = 0.0f;
    unsigned u = __float_as_uint(val);
    if((u & pmask) == pref[b]) atomicAdd(&lh[b*256+((u>>shift)&255u)],1u);
  }
  __syncthreads();
  for(int i=threadIdx.x;i<1024;i+=256){
    unsigned c = lh[i];
    if(c) atomicAdd(&hist[i], c);
  }
}

__global__ void topk_scan(unsigned* __restrict__ hist, unsigned* __restrict__ state, int level){
  int b = blockIdx.x;
  if(threadIdx.x==0){
    const unsigned* h = hist + b*256;
    unsigned remk = state[b*4+1];
    unsigned cum = 0; int sel=0;
    for(int bin=255; bin>=0; bin--){
      unsigned c = h[bin];
      if(remk <= cum + c){ sel=bin; break; }
      cum += c;
    }
    state[b*4+0] |= ((unsigned)sel) << (24-8*level);
    state[b*4+1] = remk - cum;
    state[b*4+2] += cum;
  }
  __syncthreads();
  for(int i=threadIdx.x;i<256;i+=blockDim.x) hist[b*256+i]=0;
}

__global__ __launch_bounds__(256) void topk_write(
    const float* __restrict__ probs, const float* __restrict__ mask,
    const unsigned* __restrict__ state, float* __restrict__ pam,
    unsigned* __restrict__ ties, unsigned* __restrict__ tiecnt){
  unsigned thr[4];
  for(int b=0;b<4;b++) thr[b]=state[b*4+0];
  size_t total=(size_t)N_B*PER_BATCH;
  for(size_t idx=(size_t)blockIdx.x*256+threadIdx.x; idx<total; idx += (size_t)gridDim.x*256){
    int b = (int)(idx / PER_BATCH);
    unsigned r = (unsigned)(idx - (size_t)b*PER_BATCH);
    int t = (int)((r>>7)&1023u);
    float val = probs[idx];
    if(!(mask[b*T_T+t] > -1.0f)) val=0.0f;
    unsigned u=__float_as_uint(val);
    float o = -10000.0f;
    if(u > thr[b]) o = 0.0f;
    else if(u == thr[b]){
      unsigned pos = atomicAdd(&tiecnt[b],1u);
      if(pos < 65536u) ties[(size_t)b*65536+pos]=r;
    }
    pam[idx]=o;
  }
}

__global__ __launch_bounds__(256) void topk_ties(
    const unsigned* __restrict__ state, const unsigned* __restrict__ ties,
    const unsigned* __restrict__ tiecnt, float* __restrict__ pam){
  int b = blockIdx.x;
  unsigned needed = state[b*4+1];
  unsigned nt = min(tiecnt[b], 65536u);
  __shared__ unsigned redu[256];
  __shared__ unsigned lohi[2];
  if(threadIdx.x==0){ lohi[0]=0u; lohi[1]=PER_BATCH; }
  __syncthreads();
  if(needed == 0 || nt == 0) return;
  while(true){
    __syncthreads();
    unsigned lo=lohi[0], hi=lohi[1];
    if(hi-lo<=1u) break;
    unsigned mid=(lo+hi)>>1;
    unsigned c=0;
    for(unsigned i=threadIdx.x;i<nt;i+=256) c += (ties[(size_t)b*65536+i] < mid)?1u:0u;
    redu[threadIdx.x]=c; __syncthreads();
    for(int o=128;o;o>>=1){ if(threadIdx.x<o) redu[threadIdx.x]+=redu[threadIdx.x+o]; __syncthreads(); }
    if(threadIdx.x==0){ if(redu[0]>=needed) lohi[1]=mid; else lohi[0]=mid; }
  }
  __syncthreads();
  unsigned X=lohi[1];
  for(unsigned i=threadIdx.x;i<nt;i+=256){
    unsigned r=ties[(size_t)b*65536+i];
    if(r < X) pam[(size_t)b*PER_BATCH + r]=0.0f;
  }
}

// ---------------- launcher ------------------------------------------------
extern "C" void kernel_launch(void* const* d_in, const int* in_sizes, int n_in,
                              void* d_out, int out_size, void* d_ws, size_t ws_size,
                              hipStream_t stream) {
  const float* v     = (const float*)d_in[2];
  const float* qfa   = (const float*)d_in[3];
  const float* kfa   = (const float*)d_in[4];
  const float* mask  = (const float*)d_in[8];
  const float* truth = (const float*)d_in[9];
  const float* pm    = (const float*)d_in[11];
  const float* encw  = (const float*)d_in[12];
  const float* encb  = (const float*)d_in[13];
  const float* lng   = (const float*)d_in[14];
  const float* lnb   = (const float*)d_in[15];
  const float* decw  = (const float*)d_in[16];
  const float* decb  = (const float*)d_in[17];
  float* out = (float*)d_out;
  float* ws  = (float*)d_ws;

  float* keymax = ws;                          // 768
  float* ctx    = ws + 1024;                   // 48*266*64 = 817152
  float* ksum   = ctx + (size_t)N_H*F_F*64;    // 12768
  float* klrow  = ksum + N_H*F_F;              // 49152
  float* mserow = klrow + N_H*T_T;             // 49152
  unsigned* hist   = (unsigned*)(mserow + N_H*T_T); // 1024
  unsigned* state  = hist + 1024;              // 16
  unsigned* tiecnt = state + 16;               // 4
  unsigned* ties   = tiecnt + 12;              // 4*65536

  float* pcl   = out + 1;
  float* probs = pcl + (size_t)N_H*T_T*D_H;
  float* pam   = probs + (size_t)N_H*T_T*TM_;

  kmax_kern<<<dim3(N_H,16),256,0,stream>>>(kfa, pm, keymax);
  keyfeat_kern<<<dim3(N_H,NCHUNK),256,0,stream>>>(kfa, pm, mask, keymax, ctx, ksum);
  qfeat_kern<<<dim3(N_H,16),256,0,stream>>>(qfa, pm, ctx, ksum, pcl);
  mlp_kern<<<dim3(N_H,32),256,0,stream>>>(pcl, v, mask, encw, encb, lng, lnb,
                                          decw, decb, probs, pam /*score*/);
  loss_kern<<<N_H*T_T,256,0,stream>>>(truth, mask, pam /*score*/, klrow, mserow);
  finloss_kern<<<1,256,0,stream>>>(klrow, mserow, mask, out);
  topk_init<<<4,256,0,stream>>>(hist, state, tiecnt);
  for(int lvl=0;lvl<4;lvl++){
    topk_hist<<<2048,256,0,stream>>>(probs, mask, state, hist, lvl);
    topk_scan<<<4,64,0,stream>>>(hist, state, lvl);
  }
  topk_write<<<2048,256,0,stream>>>(probs, mask, state, pam, ties, tiecnt);
  topk_ties<<<4,256,0,stream>>>(state, ties, tiecnt, pam);
}

// Round 5
// 736.337 us; speedup vs baseline: 2.3966x; 1.1087x over previous
//
#include <hip/hip_runtime.h>
#include <hip/hip_bf16.h>
#include <math.h>

#define N_B 4
#define H_H 12
#define T_T 1024
#define D_H 64
#define F_F 266
#define N_H 48          // N_B*H_H
#define TM_ 128
#define KSEL 98304u     // kk*T*H = 8*1024*12
#define PER_BATCH 1572864  // H*T*TM
#define FCHUNK 14
#define NCHUNK 19       // 19*14 = 266

static __device__ __forceinline__ float waveSum(float v){
  for(int o=32;o;o>>=1) v += __shfl_xor(v,o,64);
  return v;
}
static __device__ __forceinline__ float waveMax(float v){
  for(int o=32;o;o>>=1) v = fmaxf(v,__shfl_xor(v,o,64));
  return v;
}

#define DN_C 0.35355339059327373f   // 64^-0.25 = 2^-1.5
#define DIAG_C 0.0625f              // 0.5 * 64^-0.5
#define RATIO_C 0.06131393394849658f // 266^-0.5
#define EPS_C 1e-4f

// ---------------- Kernel B: key features (online max), raw outputs ---------
// ctx_raw[f][d] = sum_t exp(dd - diag - mf[f]) * vfa ; ksum_raw[f] = sum_t exp
__global__ __launch_bounds__(256) void keyfeat_kern(
    const float* __restrict__ kfa, const float* __restrict__ pm,
    const float* __restrict__ mask,
    float* __restrict__ ctx, float* __restrict__ ksum, float* __restrict__ mf){
  int head = blockIdx.x, fc = blockIdx.y;
  int f0 = fc*FCHUNK;
  int n = head / H_H;
  __shared__ float pms[FCHUNK*64];
  __shared__ float xs[64][65];
  __shared__ float ctxs[FCHUNK][64];
  __shared__ float ksums[FCHUNK];
  for(int i=threadIdx.x;i<FCHUNK*64;i+=256) ((float*)ctxs)[i]=0.f;
  for(int i=threadIdx.x;i<FCHUNK;i+=256) ksums[i]=0.f;
  for(int i=threadIdx.x;i<FCHUNK*64;i+=256) pms[i] = pm[f0*64+i];
  int lane = threadIdx.x&63, w = threadIdx.x>>6;
  const float* mrow = mask + n*T_T;
  float mrun[4] = {-3.4e38f,-3.4e38f,-3.4e38f,-3.4e38f};
  for(int tc=0;tc<16;tc++){
    __syncthreads();
    const float* xp = kfa + ((size_t)head*T_T + (size_t)tc*64)*D_H;
    for(int i=threadIdx.x;i<64*64;i+=256) xs[i>>6][i&63]=xp[i];
    __syncthreads();
    float diag=0.f;
    for(int d=0;d<64;d++){ float xv=xs[lane][d]; diag += xv*xv; }
    diag *= DIAG_C;
    int tg = tc*64 + lane;
    float vfac = (mrow[tg] > -1.0f) ? 1.f : 0.f;
    #pragma unroll
    for(int j=0;j<4;j++){
      int fl = w + 4*j;
      if(fl < FCHUNK){
        const float* pr = pms + fl*64;
        float s0=0,s1=0,s2=0,s3=0;
        for(int d=0;d<64;d+=4){
          s0+=xs[lane][d]*pr[d];   s1+=xs[lane][d+1]*pr[d+1];
          s2+=xs[lane][d+2]*pr[d+2]; s3+=xs[lane][d+3]*pr[d+3];
        }
        float dd = DN_C*((s0+s1)+(s2+s3));
        float cmax = waveMax(dd);
        if(cmax > mrun[j]){                       // wave-uniform
          float fac = expf(mrun[j]-cmax);         // first bump: exp(-huge)=0
          ctxs[fl][lane] *= fac;
          if(lane==0) ksums[fl] *= fac;
          mrun[j] = cmax;
        }
        float e = expf(dd - diag - mrun[j]);
        float tot = waveSum(e);
        if(lane==0) ksums[fl] += tot;
        float kv = e*vfac;
        kv += __shfl_down(kv,4,64); kv += __shfl_down(kv,2,64); kv += __shfl_down(kv,1,64);
        if((lane&15)==0) ctxs[fl][tg>>4] += kv;   // lanes t%16==0: sum of t%16 in [0,8)
      }
    }
  }
  __syncthreads();
  float* co = ctx + ((size_t)head*F_F + f0)*64;
  for(int i=threadIdx.x;i<FCHUNK*64;i+=256) co[i] = ((float*)ctxs)[i];
  float* ko = ksum + head*F_F + f0;
  for(int i=threadIdx.x;i<FCHUNK;i+=256) ko[i] = ksums[i];
  if(lane==0){
    #pragma unroll
    for(int j=0;j<4;j++){ int fl=w+4*j; if(fl<FCHUNK) mf[head*F_F+f0+fl]=mrun[j]; }
  }
}

// ---------------- Kernel B2: per-head fixup (global max, ratio+EPS, totals) -
__global__ __launch_bounds__(256) void fixup_kern(
    const float* __restrict__ mf, const float* __restrict__ mask,
    float* __restrict__ ctx, float* __restrict__ ksum,
    float* __restrict__ ksum_tot, float* __restrict__ ctx_tot){
  int head = blockIdx.x; int n = head/H_H;
  __shared__ float mred[4];
  __shared__ float segc[64];
  __shared__ float part[4][64];
  __shared__ float kpart[4];
  float mx = -3.4e38f;
  for(int f=threadIdx.x; f<F_F; f+=256) mx = fmaxf(mx, mf[head*F_F+f]);
  mx = waveMax(mx);
  if((threadIdx.x&63)==0) mred[threadIdx.x>>6]=mx;
  __syncthreads();
  float m_head = fmaxf(fmaxf(mred[0],mred[1]),fmaxf(mred[2],mred[3]));
  if(threadIdx.x < 64){
    int d = threadIdx.x; float c=0.f;
    for(int i=0;i<8;i++) c += (mask[n*T_T + 16*d + i] > -1.0f) ? 1.f : 0.f;
    segc[d] = c;
  }
  __syncthreads();
  int g = threadIdx.x>>6, d = threadIdx.x&63;
  float ct = 0.f, kt = 0.f;
  for(int f=g; f<F_F; f+=4){
    float s = expf(mf[head*F_F+f] - m_head);
    size_t cidx = ((size_t)head*F_F+f)*64 + d;
    float cf = RATIO_C*(ctx[cidx]*s + EPS_C*segc[d]);
    ctx[cidx] = cf;
    ct += cf;
    if(d==0){
      float kf = RATIO_C*(ksum[head*F_F+f]*s + EPS_C*(float)T_T);
      ksum[head*F_F+f] = kf;
      kt += kf;
    }
  }
  part[g][d] = ct;
  if(d==0) kpart[g] = kt;
  __syncthreads();
  if(threadIdx.x < 64)
    ctx_tot[head*64+threadIdx.x] =
      part[0][threadIdx.x]+part[1][threadIdx.x]+part[2][threadIdx.x]+part[3][threadIdx.x];
  if(threadIdx.x==0) ksum_tot[head] = kpart[0]+kpart[1]+kpart[2]+kpart[3];
}

// ---------------- Kernel C: query features + pcl (single sweep, online max) -
__global__ __launch_bounds__(256) void qfeat_kern(
    const float* __restrict__ qfa, const float* __restrict__ pm,
    const float* __restrict__ ctx, const float* __restrict__ ksum,
    const float* __restrict__ ksum_tot, const float* __restrict__ ctx_tot,
    float* __restrict__ pcl){
  int head = blockIdx.x, tc = blockIdx.y;   // grid (48,16), 256 threads
  int rl = threadIdx.x >> 2, fs = threadIdx.x & 3;
  int t = tc*64 + rl;
  __shared__ float pms[56*68];
  __shared__ float ctxs[56*68];
  __shared__ float ksums[56];
  const float* xp = qfa + ((size_t)head*T_T + t)*D_H;
  float4 xr[16];
  #pragma unroll
  for(int kk=0;kk<16;kk++) xr[kk] = ((const float4*)xp)[kk];
  float diag = 0.f;
  #pragma unroll
  for(int kk=0;kk<16;kk++)
    diag += xr[kk].x*xr[kk].x + xr[kk].y*xr[kk].y + xr[kk].z*xr[kk].z + xr[kk].w*xr[kk].w;
  diag *= DIAG_C;
  float m_run = -3.4e38f, S = 0.f;
  float4 acc[16];
  #pragma unroll
  for(int kk=0;kk<16;kk++) acc[kk] = make_float4(0.f,0.f,0.f,0.f);
  for(int c=0;c<5;c++){
    int f0 = c*56, CF = min(56, F_F-f0);
    __syncthreads();
    for(int i=threadIdx.x;i<CF*16;i+=256){
      int fl=i>>4, d4=i&15;
      ((float4*)(pms+fl*68))[d4]  = ((const float4*)(pm+(size_t)(f0+fl)*64))[d4];
      ((float4*)(ctxs+fl*68))[d4] = ((const float4*)(ctx+((size_t)head*F_F+f0+fl)*64))[d4];
    }
    for(int i=threadIdx.x;i<CF;i+=256) ksums[i]=ksum[head*F_F+f0+i];
    __syncthreads();
    int nj = (CF - fs + 3)>>2;
    for(int j=0;j<nj;j++){
      int fl = fs+4*j;
      const float4* pr = (const float4*)(pms + fl*68);
      float s0=0,s1=0,s2=0,s3=0;
      #pragma unroll
      for(int kk=0;kk<16;kk++){ float4 w4 = pr[kk];
        s0+=xr[kk].x*w4.x; s1+=xr[kk].y*w4.y; s2+=xr[kk].z*w4.z; s3+=xr[kk].w*w4.w; }
      float dd = DN_C*((s0+s1)+(s2+s3));
      if(dd > m_run){
        float fac = expf(m_run - dd);           // first: exp(-huge)=0 on zero accs
        S *= fac;
        #pragma unroll
        for(int kk=0;kk<16;kk++){
          acc[kk].x*=fac; acc[kk].y*=fac; acc[kk].z*=fac; acc[kk].w*=fac;
        }
        m_run = dd;
      }
      float e = expf(dd - diag - m_run);
      S += e * ksums[fl];
      const float4* cr = (const float4*)(ctxs + fl*68);
      #pragma unroll
      for(int kk=0;kk<16;kk++){ float4 c4=cr[kk];
        acc[kk].x+=e*c4.x; acc[kk].y+=e*c4.y; acc[kk].z+=e*c4.z; acc[kk].w+=e*c4.w; }
    }
  }
  // combine the 4 f-slices with max-rescale (butterfly)
  for(int st=1; st<=2; st<<=1){
    float mo = __shfl_xor(m_run, st, 64);
    float mc = fmaxf(m_run, mo);
    float fac = expf(m_run - mc);
    S *= fac;
    S += __shfl_xor(S, st, 64);
    #pragma unroll
    for(int kk=0;kk<16;kk++){
      acc[kk].x*=fac; acc[kk].y*=fac; acc[kk].z*=fac; acc[kk].w*=fac;
    }
    #pragma unroll
    for(int kk=0;kk<16;kk++){
      acc[kk].x += __shfl_xor(acc[kk].x,st,64);
      acc[kk].y += __shfl_xor(acc[kk].y,st,64);
      acc[kk].z += __shfl_xor(acc[kk].z,st,64);
      acc[kk].w += __shfl_xor(acc[kk].w,st,64);
    }
    m_run = mc;
  }
  float den = S + EPS_C * ksum_tot[head];
  float dinv = 1.0f/den;
  float4 w0,w1,w2,w3;
  if(fs==0){ w0=acc[0]; w1=acc[1]; w2=acc[2]; w3=acc[3]; }
  else if(fs==1){ w0=acc[4]; w1=acc[5]; w2=acc[6]; w3=acc[7]; }
  else if(fs==2){ w0=acc[8]; w1=acc[9]; w2=acc[10]; w3=acc[11]; }
  else { w0=acc[12]; w1=acc[13]; w2=acc[14]; w3=acc[15]; }
  const float4* ctp = ((const float4*)(ctx_tot + head*64)) + fs*4;
  float4 c0=ctp[0], c1=ctp[1], c2=ctp[2], c3=ctp[3];
  float4* po = (float4*)(pcl + ((size_t)head*T_T + t)*D_H) + fs*4;
  po[0] = make_float4((w0.x+EPS_C*c0.x)*dinv,(w0.y+EPS_C*c0.y)*dinv,(w0.z+EPS_C*c0.z)*dinv,(w0.w+EPS_C*c0.w)*dinv);
  po[1] = make_float4((w1.x+EPS_C*c1.x)*dinv,(w1.y+EPS_C*c1.y)*dinv,(w1.z+EPS_C*c1.z)*dinv,(w1.w+EPS_C*c1.w)*dinv);
  po[2] = make_float4((w2.x+EPS_C*c2.x)*dinv,(w2.y+EPS_C*c2.y)*dinv,(w2.z+EPS_C*c2.z)*dinv,(w2.w+EPS_C*c2.w)*dinv);
  po[3] = make_float4((w3.x+EPS_C*c3.x)*dinv,(w3.y+EPS_C*c3.y)*dinv,(w3.z+EPS_C*c3.z)*dinv,(w3.w+EPS_C*c3.w)*dinv);
}

// ---------------- Kernel D: MLP + LN + GELU + score + softmax -------------
#define FMA4(A,s,W) {A.x+=(s)*W.x; A.y+=(s)*W.y; A.z+=(s)*W.z; A.w+=(s)*W.w;}
__global__ __launch_bounds__(256) void mlp_kern(
    const float* __restrict__ pcl, const float* __restrict__ v,
    const float* __restrict__ mask,
    const float* __restrict__ encw, const float* __restrict__ encb,
    const float* __restrict__ lng, const float* __restrict__ lnb,
    const float* __restrict__ decw, const float* __restrict__ decb,
    float* __restrict__ probsout, float* __restrict__ scoreout){
  int head = blockIdx.x, tblk = blockIdx.y;   // grid (48,32)
  int t0 = tblk*32;
  int n = head / H_H;
  __shared__ float xs[32*132];
  __shared__ float wts[32*132];
  __shared__ float h1s[32*132];
  int colT = threadIdx.x & 15, rowT = threadIdx.x >> 4;
  int r0 = rowT, r1 = rowT + 16;
  const float* pclrow = pcl + ((size_t)head*T_T + t0)*D_H;
  const float* vrow   = v   + ((size_t)head*T_T + t0)*D_H;
  for(int i=threadIdx.x;i<512;i+=256){
    int r=i>>4, q=i&15;
    ((float4*)(xs + r*132))[q]      = ((const float4*)(pclrow + r*64))[q];
    ((float4*)(xs + r*132 + 64))[q] = ((const float4*)(vrow   + r*64))[q];
  }
  float4 bias0 = ((const float4*)encb)[colT];
  float4 bias1 = ((const float4*)encb)[colT+16];
  float4 A0=bias0, A1=bias1, B0=bias0, B1=bias1;
  for(int kc=0;kc<4;kc++){
    __syncthreads();
    for(int i=threadIdx.x;i<1024;i+=256){
      int k=i>>5, q=i&31;
      ((float4*)(wts + k*132))[q] = ((const float4*)(encw + (size_t)(kc*32+k)*128))[q];
    }
    __syncthreads();
    #pragma unroll
    for(int kq=0;kq<8;kq++){
      float4 x0 = ((const float4*)(xs + r0*132 + kc*32))[kq];
      float4 x1 = ((const float4*)(xs + r1*132 + kc*32))[kq];
      #pragma unroll
      for(int kk=0;kk<4;kk++){
        const float* wrow = wts + (kq*4+kk)*132;
        float4 wa = ((const float4*)wrow)[colT];
        float4 wb = ((const float4*)wrow)[colT+16];
        float xv0 = (kk==0)?x0.x:(kk==1)?x0.y:(kk==2)?x0.z:x0.w;
        float xv1 = (kk==0)?x1.x:(kk==1)?x1.y:(kk==2)?x1.z:x1.w;
        FMA4(A0,xv0,wa); FMA4(A1,xv0,wb);
        FMA4(B0,xv1,wa); FMA4(B1,xv1,wb);
      }
    }
  }
  float4 lg0 = ((const float4*)lng)[colT], lg1 = ((const float4*)lng)[colT+16];
  float4 lb0 = ((const float4*)lnb)[colT], lb1 = ((const float4*)lnb)[colT+16];
  float s0 = A0.x+A0.y+A0.z+A0.w + A1.x+A1.y+A1.z+A1.w;
  float s1 = B0.x+B0.y+B0.z+B0.w + B1.x+B1.y+B1.z+B1.w;
  for(int o=1;o<16;o<<=1){ s0 += __shfl_xor(s0,o,64); s1 += __shfl_xor(s1,o,64); }
  float mu0 = s0*(1.0f/128.0f), mu1 = s1*(1.0f/128.0f);
  float v0=0.f, v1=0.f;
  { float d;
    d=A0.x-mu0; v0+=d*d; d=A0.y-mu0; v0+=d*d; d=A0.z-mu0; v0+=d*d; d=A0.w-mu0; v0+=d*d;
    d=A1.x-mu0; v0+=d*d; d=A1.y-mu0; v0+=d*d; d=A1.z-mu0; v0+=d*d; d=A1.w-mu0; v0+=d*d;
    d=B0.x-mu1; v1+=d*d; d=B0.y-mu1; v1+=d*d; d=B0.z-mu1; v1+=d*d; d=B0.w-mu1; v1+=d*d;
    d=B1.x-mu1; v1+=d*d; d=B1.y-mu1; v1+=d*d; d=B1.z-mu1; v1+=d*d; d=B1.w-mu1; v1+=d*d; }
  for(int o=1;o<16;o<<=1){ v0 += __shfl_xor(v0,o,64); v1 += __shfl_xor(v1,o,64); }
  float den0 = sqrtf(v0*(1.0f/128.0f)+1e-5f);
  float den1 = sqrtf(v1*(1.0f/128.0f)+1e-5f);
  #define GELU(x) ((x)*0.5f*(1.0f+erff((x)*0.70710678118654752f)))
  #define LNG(a,mu,dn,g,b) GELU(((a)-(mu))/(dn)*(g)+(b))
  float4 H;
  H.x=LNG(A0.x,mu0,den0,lg0.x,lb0.x); H.y=LNG(A0.y,mu0,den0,lg0.y,lb0.y);
  H.z=LNG(A0.z,mu0,den0,lg0.z,lb0.z); H.w=LNG(A0.w,mu0,den0,lg0.w,lb0.w);
  ((float4*)(h1s + r0*132))[colT] = H;
  H.x=LNG(A1.x,mu0,den0,lg1.x,lb1.x); H.y=LNG(A1.y,mu0,den0,lg1.y,lb1.y);
  H.z=LNG(A1.z,mu0,den0,lg1.z,lb1.z); H.w=LNG(A1.w,mu0,den0,lg1.w,lb1.w);
  ((float4*)(h1s + r0*132))[colT+16] = H;
  H.x=LNG(B0.x,mu1,den1,lg0.x,lb0.x); H.y=LNG(B0.y,mu1,den1,lg0.y,lb0.y);
  H.z=LNG(B0.z,mu1,den1,lg0.z,lb0.z); H.w=LNG(B0.w,mu1,den1,lg0.w,lb0.w);
  ((float4*)(h1s + r1*132))[colT] = H;
  H.x=LNG(B1.x,mu1,den1,lg1.x,lb1.x); H.y=LNG(B1.y,mu1,den1,lg1.y,lb1.y);
  H.z=LNG(B1.z,mu1,den1,lg1.z,lb1.z); H.w=LNG(B1.w,mu1,den1,lg1.w,lb1.w);
  ((float4*)(h1s + r1*132))[colT+16] = H;
  bias0 = ((const float4*)decb)[colT];
  bias1 = ((const float4*)decb)[colT+16];
  A0=bias0; A1=bias1; B0=bias0; B1=bias1;
  for(int kc=0;kc<4;kc++){
    __syncthreads();
    for(int i=threadIdx.x;i<1024;i+=256){
      int k=i>>5, q=i&31;
      ((float4*)(wts + k*132))[q] = ((const float4*)(decw + (size_t)(kc*32+k)*128))[q];
    }
    __syncthreads();
    #pragma unroll
    for(int kq=0;kq<8;kq++){
      float4 x0 = ((const float4*)(h1s + r0*132 + kc*32))[kq];
      float4 x1 = ((const float4*)(h1s + r1*132 + kc*32))[kq];
      #pragma unroll
      for(int kk=0;kk<4;kk++){
        const float* wrow = wts + (kq*4+kk)*132;
        float4 wa = ((const float4*)wrow)[colT];
        float4 wb = ((const float4*)wrow)[colT+16];
        float xv0 = (kk==0)?x0.x:(kk==1)?x0.y:(kk==2)?x0.z:x0.w;
        float xv1 = (kk==0)?x1.x:(kk==1)?x1.y:(kk==2)?x1.z:x1.w;
        FMA4(A0,xv0,wa); FMA4(A1,xv0,wb);
        FMA4(B0,xv1,wa); FMA4(B1,xv1,wb);
      }
    }
  }
  const float* mrow = mask + n*T_T;
  int c0 = colT*4, c1 = colT*4 + 64;
  float rm0[4], rm1[4];
  #pragma unroll
  for(int i=0;i<4;i++){ rm0[i]=mrow[(c0+i)*8]; rm1[i]=mrow[(c1+i)*8]; }
  float sA[8], sB[8];
  sA[0]=(rm0[0]<-1.f)?-10000.f:A0.x; sA[1]=(rm0[1]<-1.f)?-10000.f:A0.y;
  sA[2]=(rm0[2]<-1.f)?-10000.f:A0.z; sA[3]=(rm0[3]<-1.f)?-10000.f:A0.w;
  sA[4]=(rm1[0]<-1.f)?-10000.f:A1.x; sA[5]=(rm1[1]<-1.f)?-10000.f:A1.y;
  sA[6]=(rm1[2]<-1.f)?-10000.f:A1.z; sA[7]=(rm1[3]<-1.f)?-10000.f:A1.w;
  sB[0]=(rm0[0]<-1.f)?-10000.f:B0.x; sB[1]=(rm0[1]<-1.f)?-10000.f:B0.y;
  sB[2]=(rm0[2]<-1.f)?-10000.f:B0.z; sB[3]=(rm0[3]<-1.f)?-10000.f:B0.w;
  sB[4]=(rm1[0]<-1.f)?-10000.f:B1.x; sB[5]=(rm1[1]<-1.f)?-10000.f:B1.y;
  sB[6]=(rm1[2]<-1.f)?-10000.f:B1.z; sB[7]=(rm1[3]<-1.f)?-10000.f:B1.w;
  float mx0=sA[0], mx1=sB[0];
  #pragma unroll
  for(int i=1;i<8;i++){ mx0=fmaxf(mx0,sA[i]); mx1=fmaxf(mx1,sB[i]); }
  for(int o=1;o<16;o<<=1){ mx0=fmaxf(mx0,__shfl_xor(mx0,o,64)); mx1=fmaxf(mx1,__shfl_xor(mx1,o,64)); }
  float Z0=0.f, Z1=0.f;
  #pragma unroll
  for(int i=0;i<8;i++){ sA[i]=expf(sA[i]-mx0); Z0+=sA[i]; sB[i]=expf(sB[i]-mx1); Z1+=sB[i]; }
  for(int o=1;o<16;o<<=1){ Z0+=__shfl_xor(Z0,o,64); Z1+=__shfl_xor(Z1,o,64); }
  float zi0=1.0f/Z0, zi1=1.0f/Z1;
  size_t rb0 = ((size_t)head*T_T + t0 + r0)*TM_;
  size_t rb1 = ((size_t)head*T_T + t0 + r1)*TM_;
  ((float4*)(probsout+rb0))[colT]    = make_float4(sA[0]*zi0,sA[1]*zi0,sA[2]*zi0,sA[3]*zi0);
  ((float4*)(probsout+rb0))[colT+16] = make_float4(sA[4]*zi0,sA[5]*zi0,sA[6]*zi0,sA[7]*zi0);
  ((float4*)(probsout+rb1))[colT]    = make_float4(sB[0]*zi1,sB[1]*zi1,sB[2]*zi1,sB[3]*zi1);
  ((float4*)(probsout+rb1))[colT+16] = make_float4(sB[4]*zi1,sB[5]*zi1,sB[6]*zi1,sB[7]*zi1);
  ((float4*)(scoreout+rb0))[colT]    = A0;
  ((float4*)(scoreout+rb0))[colT+16] = A1;
  ((float4*)(scoreout+rb1))[colT]    = B0;
  ((float4*)(scoreout+rb1))[colT+16] = B1;
}

// ---------------- Kernel E: per-row KL + MSE ------------------------------
__global__ __launch_bounds__(256) void loss_kern(
    const float* __restrict__ truth, const float* __restrict__ mask,
    const float* __restrict__ score, float* __restrict__ klrow,
    float* __restrict__ mserow){
  int row = blockIdx.x;               // head*1024 + t
  int n = row / (H_H*T_T);
  __shared__ float a[1024];
  __shared__ float mk[1024];
  __shared__ float sc[128];
  __shared__ float red4[4];
  const float* ar = truth + (size_t)row*T_T;
  const float* mr = mask + n*T_T;
  const float* sr = score + (size_t)row*TM_;
  if(threadIdx.x < 256){
    ((float4*)a)[threadIdx.x]  = ((const float4*)ar)[threadIdx.x];
    ((float4*)mk)[threadIdx.x] = ((const float4*)mr)[threadIdx.x];
  }
  for(int i=threadIdx.x;i<128;i+=256) sc[i]=sr[i];
  __syncthreads();
  float ma=-3.4e38f, ms=-3.4e38f;
  for(int j=threadIdx.x;j<1024;j+=256){
    ma=fmaxf(ma,a[j]+mk[j]);
    ms=fmaxf(ms,sc[j>>3]+mk[j]);
  }
  ma = waveMax(ma);
  if((threadIdx.x&63)==0) red4[threadIdx.x>>6]=ma;
  __syncthreads();
  ma = fmaxf(fmaxf(red4[0],red4[1]),fmaxf(red4[2],red4[3]));
  __syncthreads();
  ms = waveMax(ms);
  if((threadIdx.x&63)==0) red4[threadIdx.x>>6]=ms;
  __syncthreads();
  ms = fmaxf(fmaxf(red4[0],red4[1]),fmaxf(red4[2],red4[3]));
  __syncthreads();
  float Za=0, Zs=0;
  for(int j=threadIdx.x;j<1024;j+=256){
    Za += expf(a[j]+mk[j]-ma);
    Zs += expf(sc[j>>3]+mk[j]-ms);
  }
  Za = waveSum(Za);
  if((threadIdx.x&63)==0) red4[threadIdx.x>>6]=Za;
  __syncthreads();
  Za = (red4[0]+red4[1])+(red4[2]+red4[3]);
  __syncthreads();
  Zs = waveSum(Zs);
  if((threadIdx.x&63)==0) red4[threadIdx.x>>6]=Zs;
  __syncthreads();
  Zs = (red4[0]+red4[1])+(red4[2]+red4[3]);
  __syncthreads();
  float lZs = logf(Zs);
  float kl=0, mse=0;
  for(int j=threadIdx.x;j<1024;j+=256){
    float mkj = mk[j];
    float scj = sc[j>>3];
    float aj = a[j];
    if(mkj > -1.0f){
      float pt = expf(aj+mkj-ma)/Za;
      float logpt = logf(fmaxf(pt,1e-12f));
      float logp = (scj+mkj-ms) - lZs;
      kl += pt*(logpt-logp);
    }
    float sv = (mkj < -1.0f)?0.f:scj;
    float av = (mkj < -1.0f)?0.f:aj;
    float d = sv-av; mse += d*d;
  }
  kl = waveSum(kl);
  if((threadIdx.x&63)==0) red4[threadIdx.x>>6]=kl;
  __syncthreads();
  kl = (red4[0]+red4[1])+(red4[2]+red4[3]);
  __syncthreads();
  mse = waveSum(mse);
  if((threadIdx.x&63)==0) red4[threadIdx.x>>6]=mse;
  __syncthreads();
  if(threadIdx.x==0){
    mse = (red4[0]+red4[1])+(red4[2]+red4[3]);
    klrow[row]=kl; mserow[row]=mse;
  }
}

// ---------------- Kernel F: final loss ------------------------------------
__global__ __launch_bounds__(256) void finloss_kern(
    const float* __restrict__ klrow, const float* __restrict__ mserow,
    const float* __restrict__ mask, float* __restrict__ out0){
  __shared__ double reds[256];
  double kls=0, mses=0;
  for(int i=threadIdx.x;i<N_H*T_T;i+=256){ kls+=(double)klrow[i]; mses+=(double)mserow[i]; }
  double vcnt=0;
  for(int i=threadIdx.x;i<N_B*T_T;i+=256) if(mask[i] > -1.0f) vcnt+=1.0;
  reds[threadIdx.x]=kls; __syncthreads();
  for(int o=128;o;o>>=1){ if(threadIdx.x<o) reds[threadIdx.x]+=reds[threadIdx.x+o]; __syncthreads(); }
  double klsum = reds[0]; __syncthreads();
  reds[threadIdx.x]=mses; __syncthreads();
  for(int o=128;o;o>>=1){ if(threadIdx.x<o) reds[threadIdx.x]+=reds[threadIdx.x+o]; __syncthreads(); }
  double msesum = reds[0]; __syncthreads();
  reds[threadIdx.x]=vcnt; __syncthreads();
  for(int o=128;o;o>>=1){ if(threadIdx.x<o) reds[threadIdx.x]+=reds[threadIdx.x+o]; __syncthreads(); }
  if(threadIdx.x==0){
    double denom = reds[0] * (double)(H_H*T_T);
    double loss = klsum/denom*0.25 + msesum/((double)N_B*H_H*T_T*T_T);
    out0[0]=(float)loss;
  }
}

// ---------------- Top-k pipeline ------------------------------------------
__global__ void topk_init(unsigned* __restrict__ hist, unsigned* __restrict__ state,
                          unsigned* __restrict__ tiecnt){
  int i = blockIdx.x*256+threadIdx.x;
  if(i < 4*256) hist[i]=0;
  if(i < 4){ state[i*4+0]=0u; state[i*4+1]=KSEL; state[i*4+2]=0u; tiecnt[i]=0u; }
}

__global__ __launch_bounds__(256) void topk_hist(
    const float* __restrict__ probs, const float* __restrict__ mask,
    const unsigned* __restrict__ state, unsigned* __restrict__ hist, int level){
  __shared__ unsigned lh[4*256];
  for(int i=threadIdx.x;i<1024;i+=256) lh[i]=0;
  __syncthreads();
  unsigned pmask = (level==0)?0u:(0xFFFFFFFFu << (32-8*level));
  unsigned pref[4];
  for(int b=0;b<4;b++) pref[b]=state[b*4+0] & pmask;
  int shift = 24-8*level;
  size_t total = (size_t)N_B*PER_BATCH;
  for(size_t idx = (size_t)blockIdx.x*256+threadIdx.x; idx < total; idx += (size_t)gridDim.x*256){
    int b = (int)(idx / PER_BATCH);
    unsigned r = (unsigned)(idx - (size_t)b*PER_BATCH);
    int t = (int)((r>>7)&1023u);
    float val = probs[idx];
    if(!(mask[b*T_T+t] > -1.0f)) val = 0.0f;
    unsigned u = __float_as_uint(val);
    if((u & pmask) == pref[b]) atomicAdd(&lh[b*256+((u>>shift)&255u)],1u);
  }
  __syncthreads();
  for(int i=threadIdx.x;i<1024;i+=256){
    unsigned c = lh[i];
    if(c) atomicAdd(&hist[i], c);
  }
}

__global__ void topk_scan(unsigned* __restrict__ hist, unsigned* __restrict__ state, int level){
  int b = blockIdx.x;
  if(threadIdx.x==0){
    const unsigned* h = hist + b*256;
    unsigned remk = state[b*4+1];
    unsigned cum = 0; int sel=0;
    for(int bin=255; bin>=0; bin--){
      unsigned c = h[bin];
      if(remk <= cum + c){ sel=bin; break; }
      cum += c;
    }
    state[b*4+0] |= ((unsigned)sel) << (24-8*level);
    state[b*4+1] = remk - cum;
    state[b*4+2] += cum;
  }
  __syncthreads();
  for(int i=threadIdx.x;i<256;i+=blockDim.x) hist[b*256+i]=0;
}

__global__ __launch_bounds__(256) void topk_write(
    const float* __restrict__ probs, const float* __restrict__ mask,
    const unsigned* __restrict__ state, float* __restrict__ pam,
    unsigned* __restrict__ ties, unsigned* __restrict__ tiecnt){
  unsigned thr[4];
  for(int b=0;b<4;b++) thr[b]=state[b*4+0];
  size_t total=(size_t)N_B*PER_BATCH;
  for(size_t idx=(size_t)blockIdx.x*256+threadIdx.x; idx<total; idx += (size_t)gridDim.x*256){
    int b = (int)(idx / PER_BATCH);
    unsigned r = (unsigned)(idx - (size_t)b*PER_BATCH);
    int t = (int)((r>>7)&1023u);
    float val = probs[idx];
    if(!(mask[b*T_T+t] > -1.0f)) val=0.0f;
    unsigned u=__float_as_uint(val);
    float o = -10000.0f;
    if(u > thr[b]) o = 0.0f;
    else if(u == thr[b]){
      unsigned pos = atomicAdd(&tiecnt[b],1u);
      if(pos < 65536u) ties[(size_t)b*65536+pos]=r;
    }
    pam[idx]=o;
  }
}

__global__ __launch_bounds__(256) void topk_ties(
    const unsigned* __restrict__ state, const unsigned* __restrict__ ties,
    const unsigned* __restrict__ tiecnt, float* __restrict__ pam){
  int b = blockIdx.x;
  unsigned needed = state[b*4+1];
  unsigned nt = min(tiecnt[b], 65536u);
  __shared__ unsigned redu[256];
  __shared__ unsigned lohi[2];
  if(threadIdx.x==0){ lohi[0]=0u; lohi[1]=PER_BATCH; }
  __syncthreads();
  if(needed == 0 || nt == 0) return;
  while(true){
    __syncthreads();
    unsigned lo=lohi[0], hi=lohi[1];
    if(hi-lo<=1u) break;
    unsigned mid=(lo+hi)>>1;
    unsigned c=0;
    for(unsigned i=threadIdx.x;i<nt;i+=256) c += (ties[(size_t)b*65536+i] < mid)?1u:0u;
    redu[threadIdx.x]=c; __syncthreads();
    for(int o=128;o;o>>=1){ if(threadIdx.x<o) redu[threadIdx.x]+=redu[threadIdx.x+o]; __syncthreads(); }
    if(threadIdx.x==0){ if(redu[0]>=needed) lohi[1]=mid; else lohi[0]=mid; }
  }
  __syncthreads();
  unsigned X=lohi[1];
  for(unsigned i=threadIdx.x;i<nt;i+=256){
    unsigned r=ties[(size_t)b*65536+i];
    if(r < X) pam[(size_t)b*PER_BATCH + r]=0.0f;
  }
}

// ---------------- launcher ------------------------------------------------
extern "C" void kernel_launch(void* const* d_in, const int* in_sizes, int n_in,
                              void* d_out, int out_size, void* d_ws, size_t ws_size,
                              hipStream_t stream) {
  const float* v     = (const float*)d_in[2];
  const float* qfa   = (const float*)d_in[3];
  const float* kfa   = (const float*)d_in[4];
  const float* mask  = (const float*)d_in[8];
  const float* truth = (const float*)d_in[9];
  const float* pm    = (const float*)d_in[11];
  const float* encw  = (const float*)d_in[12];
  const float* encb  = (const float*)d_in[13];
  const float* lng   = (const float*)d_in[14];
  const float* lnb   = (const float*)d_in[15];
  const float* decw  = (const float*)d_in[16];
  const float* decb  = (const float*)d_in[17];
  float* out = (float*)d_out;
  float* ws  = (float*)d_ws;

  float* ctx    = ws + 1024;                   // 48*266*64 = 817152
  float* ksum   = ctx + (size_t)N_H*F_F*64;    // 12768
  float* klrow  = ksum + N_H*F_F;              // 49152
  float* mserow = klrow + N_H*T_T;             // 49152
  unsigned* hist   = (unsigned*)(mserow + N_H*T_T); // 1024
  unsigned* state  = hist + 1024;              // 16
  unsigned* tiecnt = state + 16;               // 4 (+pad)
  unsigned* ties   = tiecnt + 12;              // 4*65536
  float* mf       = (float*)(ties + 4*65536);  // 48*266 = 12768
  float* ksum_tot = mf + N_H*F_F;              // 48
  float* ctx_tot  = ksum_tot + 48;             // 48*64 = 3072

  float* pcl   = out + 1;
  float* probs = pcl + (size_t)N_H*T_T*D_H;
  float* pam   = probs + (size_t)N_H*T_T*TM_;

  keyfeat_kern<<<dim3(N_H,NCHUNK),256,0,stream>>>(kfa, pm, mask, ctx, ksum, mf);
  fixup_kern<<<N_H,256,0,stream>>>(mf, mask, ctx, ksum, ksum_tot, ctx_tot);
  qfeat_kern<<<dim3(N_H,16),256,0,stream>>>(qfa, pm, ctx, ksum, ksum_tot, ctx_tot, pcl);
  mlp_kern<<<dim3(N_H,32),256,0,stream>>>(pcl, v, mask, encw, encb, lng, lnb,
                                          decw, decb, probs, pam /*score*/);
  loss_kern<<<N_H*T_T,256,0,stream>>>(truth, mask, pam /*score*/, klrow, mserow);
  finloss_kern<<<1,256,0,stream>>>(klrow, mserow, mask, out);
  topk_init<<<4,256,0,stream>>>(hist, state, tiecnt);
  for(int lvl=0;lvl<4;lvl++){
    topk_hist<<<2048,256,0,stream>>>(probs, mask, state, hist, lvl);
    topk_scan<<<4,64,0,stream>>>(hist, state, lvl);
  }
  topk_write<<<2048,256,0,stream>>>(probs, mask, state, pam, ties, tiecnt);
  topk_ties<<<4,256,0,stream>>>(state, ties, tiecnt, pam);
}

// Round 6
// 721.388 us; speedup vs baseline: 2.4463x; 1.0207x over previous
//
#include <hip/hip_runtime.h>
#include <hip/hip_bf16.h>
#include <math.h>

#define N_B 4
#define H_H 12
#define T_T 1024
#define D_H 64
#define F_F 266
#define N_H 48          // N_B*H_H
#define TM_ 128
#define KSEL 98304u     // kk*T*H = 8*1024*12
#define PER_BATCH 1572864  // H*T*TM
#define FCHUNK 14
#define NCHUNK 19       // 19*14 = 266

static __device__ __forceinline__ float waveSum(float v){
  for(int o=32;o;o>>=1) v += __shfl_xor(v,o,64);
  return v;
}
static __device__ __forceinline__ float waveMax(float v){
  for(int o=32;o;o>>=1) v = fmaxf(v,__shfl_xor(v,o,64));
  return v;
}

#define DN_C 0.35355339059327373f   // 64^-0.25 = 2^-1.5
#define DIAG_C 0.0625f              // 0.5 * 64^-0.5
#define RATIO_C 0.06131393394849658f // 266^-0.5
#define EPS_C 1e-4f

// ---------------- Kernel B: key features (online max), raw outputs ---------
// v2: per-lane key row held in registers; pm read as uniform float4 LDS
// broadcasts. Arithmetic order bitwise-identical to R5 version.
__global__ __launch_bounds__(256) void keyfeat_kern(
    const float* __restrict__ kfa, const float* __restrict__ pm,
    const float* __restrict__ mask,
    float* __restrict__ ctx, float* __restrict__ ksum, float* __restrict__ mf){
  int head = blockIdx.x, fc = blockIdx.y;
  int f0 = fc*FCHUNK;
  int n = head / H_H;
  __shared__ float pms[FCHUNK*64];
  __shared__ float ctxs[FCHUNK][64];
  __shared__ float ksums[FCHUNK];
  for(int i=threadIdx.x;i<FCHUNK*64;i+=256) ((float*)ctxs)[i]=0.f;
  for(int i=threadIdx.x;i<FCHUNK;i+=256) ksums[i]=0.f;
  for(int i=threadIdx.x;i<FCHUNK*64;i+=256) pms[i] = pm[f0*64+i];
  int lane = threadIdx.x&63, w = threadIdx.x>>6;
  const float* mrow = mask + n*T_T;
  float mrun[4] = {-3.4e38f,-3.4e38f,-3.4e38f,-3.4e38f};
  __syncthreads();
  for(int tc=0;tc<16;tc++){
    int tg = tc*64 + lane;
    const float* xp = kfa + ((size_t)head*T_T + tg)*D_H;
    float4 xr[16];
    #pragma unroll
    for(int kk=0;kk<16;kk++) xr[kk] = ((const float4*)xp)[kk];
    float diag = 0.f;
    #pragma unroll
    for(int kk=0;kk<16;kk++)
      diag += xr[kk].x*xr[kk].x + xr[kk].y*xr[kk].y + xr[kk].z*xr[kk].z + xr[kk].w*xr[kk].w;
    diag *= DIAG_C;
    float vfac = (mrow[tg] > -1.0f) ? 1.f : 0.f;
    #pragma unroll
    for(int j=0;j<4;j++){
      int fl = w + 4*j;
      if(fl < FCHUNK){
        const float4* pr = (const float4*)(pms + fl*64);
        float s0=0,s1=0,s2=0,s3=0;
        #pragma unroll
        for(int kk=0;kk<16;kk++){ float4 w4 = pr[kk];
          s0+=xr[kk].x*w4.x; s1+=xr[kk].y*w4.y; s2+=xr[kk].z*w4.z; s3+=xr[kk].w*w4.w; }
        float dd = DN_C*((s0+s1)+(s2+s3));
        float cmax = waveMax(dd);
        if(cmax > mrun[j]){                       // wave-uniform
          float fac = expf(mrun[j]-cmax);         // first bump: exp(-huge)=0
          ctxs[fl][lane] *= fac;
          if(lane==0) ksums[fl] *= fac;
          mrun[j] = cmax;
        }
        float e = expf(dd - diag - mrun[j]);
        float tot = waveSum(e);
        if(lane==0) ksums[fl] += tot;
        float kv = e*vfac;
        kv += __shfl_down(kv,4,64); kv += __shfl_down(kv,2,64); kv += __shfl_down(kv,1,64);
        if((lane&15)==0) ctxs[fl][tg>>4] += kv;   // lanes t%16==0: sum of t%16 in [0,8)
      }
    }
  }
  __syncthreads();
  float* co = ctx + ((size_t)head*F_F + f0)*64;
  for(int i=threadIdx.x;i<FCHUNK*64;i+=256) co[i] = ((float*)ctxs)[i];
  float* ko = ksum + head*F_F + f0;
  for(int i=threadIdx.x;i<FCHUNK;i+=256) ko[i] = ksums[i];
  if(lane==0){
    #pragma unroll
    for(int j=0;j<4;j++){ int fl=w+4*j; if(fl<FCHUNK) mf[head*F_F+f0+fl]=mrun[j]; }
  }
}

// ---------------- Kernel B2: per-head fixup (global max, ratio+EPS, totals) -
__global__ __launch_bounds__(256) void fixup_kern(
    const float* __restrict__ mf, const float* __restrict__ mask,
    float* __restrict__ ctx, float* __restrict__ ksum,
    float* __restrict__ ksum_tot, float* __restrict__ ctx_tot){
  int head = blockIdx.x; int n = head/H_H;
  __shared__ float mred[4];
  __shared__ float segc[64];
  __shared__ float part[4][64];
  __shared__ float kpart[4];
  float mx = -3.4e38f;
  for(int f=threadIdx.x; f<F_F; f+=256) mx = fmaxf(mx, mf[head*F_F+f]);
  mx = waveMax(mx);
  if((threadIdx.x&63)==0) mred[threadIdx.x>>6]=mx;
  __syncthreads();
  float m_head = fmaxf(fmaxf(mred[0],mred[1]),fmaxf(mred[2],mred[3]));
  if(threadIdx.x < 64){
    int d = threadIdx.x; float c=0.f;
    for(int i=0;i<8;i++) c += (mask[n*T_T + 16*d + i] > -1.0f) ? 1.f : 0.f;
    segc[d] = c;
  }
  __syncthreads();
  int g = threadIdx.x>>6, d = threadIdx.x&63;
  float ct = 0.f, kt = 0.f;
  for(int f=g; f<F_F; f+=4){
    float s = expf(mf[head*F_F+f] - m_head);
    size_t cidx = ((size_t)head*F_F+f)*64 + d;
    float cf = RATIO_C*(ctx[cidx]*s + EPS_C*segc[d]);
    ctx[cidx] = cf;
    ct += cf;
    if(d==0){
      float kf = RATIO_C*(ksum[head*F_F+f]*s + EPS_C*(float)T_T);
      ksum[head*F_F+f] = kf;
      kt += kf;
    }
  }
  part[g][d] = ct;
  if(d==0) kpart[g] = kt;
  __syncthreads();
  if(threadIdx.x < 64)
    ctx_tot[head*64+threadIdx.x] =
      part[0][threadIdx.x]+part[1][threadIdx.x]+part[2][threadIdx.x]+part[3][threadIdx.x];
  if(threadIdx.x==0) ksum_tot[head] = kpart[0]+kpart[1]+kpart[2]+kpart[3];
}

// ---------------- Kernel C: query features + pcl (single sweep, online max) -
__global__ __launch_bounds__(256) void qfeat_kern(
    const float* __restrict__ qfa, const float* __restrict__ pm,
    const float* __restrict__ ctx, const float* __restrict__ ksum,
    const float* __restrict__ ksum_tot, const float* __restrict__ ctx_tot,
    float* __restrict__ pcl){
  int head = blockIdx.x, tc = blockIdx.y;   // grid (48,16), 256 threads
  int rl = threadIdx.x >> 2, fs = threadIdx.x & 3;
  int t = tc*64 + rl;
  __shared__ float pms[56*68];
  __shared__ float ctxs[56*68];
  __shared__ float ksums[56];
  const float* xp = qfa + ((size_t)head*T_T + t)*D_H;
  float4 xr[16];
  #pragma unroll
  for(int kk=0;kk<16;kk++) xr[kk] = ((const float4*)xp)[kk];
  float diag = 0.f;
  #pragma unroll
  for(int kk=0;kk<16;kk++)
    diag += xr[kk].x*xr[kk].x + xr[kk].y*xr[kk].y + xr[kk].z*xr[kk].z + xr[kk].w*xr[kk].w;
  diag *= DIAG_C;
  float m_run = -3.4e38f, S = 0.f;
  float4 acc[16];
  #pragma unroll
  for(int kk=0;kk<16;kk++) acc[kk] = make_float4(0.f,0.f,0.f,0.f);
  for(int c=0;c<5;c++){
    int f0 = c*56, CF = min(56, F_F-f0);
    __syncthreads();
    for(int i=threadIdx.x;i<CF*16;i+=256){
      int fl=i>>4, d4=i&15;
      ((float4*)(pms+fl*68))[d4]  = ((const float4*)(pm+(size_t)(f0+fl)*64))[d4];
      ((float4*)(ctxs+fl*68))[d4] = ((const float4*)(ctx+((size_t)head*F_F+f0+fl)*64))[d4];
    }
    for(int i=threadIdx.x;i<CF;i+=256) ksums[i]=ksum[head*F_F+f0+i];
    __syncthreads();
    int nj = (CF - fs + 3)>>2;
    for(int j=0;j<nj;j++){
      int fl = fs+4*j;
      const float4* pr = (const float4*)(pms + fl*68);
      float s0=0,s1=0,s2=0,s3=0;
      #pragma unroll
      for(int kk=0;kk<16;kk++){ float4 w4 = pr[kk];
        s0+=xr[kk].x*w4.x; s1+=xr[kk].y*w4.y; s2+=xr[kk].z*w4.z; s3+=xr[kk].w*w4.w; }
      float dd = DN_C*((s0+s1)+(s2+s3));
      if(dd > m_run){
        float fac = expf(m_run - dd);           // first: exp(-huge)=0 on zero accs
        S *= fac;
        #pragma unroll
        for(int kk=0;kk<16;kk++){
          acc[kk].x*=fac; acc[kk].y*=fac; acc[kk].z*=fac; acc[kk].w*=fac;
        }
        m_run = dd;
      }
      float e = expf(dd - diag - m_run);
      S += e * ksums[fl];
      const float4* cr = (const float4*)(ctxs + fl*68);
      #pragma unroll
      for(int kk=0;kk<16;kk++){ float4 c4=cr[kk];
        acc[kk].x+=e*c4.x; acc[kk].y+=e*c4.y; acc[kk].z+=e*c4.z; acc[kk].w+=e*c4.w; }
    }
  }
  // combine the 4 f-slices with max-rescale (butterfly)
  for(int st=1; st<=2; st<<=1){
    float mo = __shfl_xor(m_run, st, 64);
    float mc = fmaxf(m_run, mo);
    float fac = expf(m_run - mc);
    S *= fac;
    S += __shfl_xor(S, st, 64);
    #pragma unroll
    for(int kk=0;kk<16;kk++){
      acc[kk].x*=fac; acc[kk].y*=fac; acc[kk].z*=fac; acc[kk].w*=fac;
    }
    #pragma unroll
    for(int kk=0;kk<16;kk++){
      acc[kk].x += __shfl_xor(acc[kk].x,st,64);
      acc[kk].y += __shfl_xor(acc[kk].y,st,64);
      acc[kk].z += __shfl_xor(acc[kk].z,st,64);
      acc[kk].w += __shfl_xor(acc[kk].w,st,64);
    }
    m_run = mc;
  }
  float den = S + EPS_C * ksum_tot[head];
  float dinv = 1.0f/den;
  float4 w0,w1,w2,w3;
  if(fs==0){ w0=acc[0]; w1=acc[1]; w2=acc[2]; w3=acc[3]; }
  else if(fs==1){ w0=acc[4]; w1=acc[5]; w2=acc[6]; w3=acc[7]; }
  else if(fs==2){ w0=acc[8]; w1=acc[9]; w2=acc[10]; w3=acc[11]; }
  else { w0=acc[12]; w1=acc[13]; w2=acc[14]; w3=acc[15]; }
  const float4* ctp = ((const float4*)(ctx_tot + head*64)) + fs*4;
  float4 c0=ctp[0], c1=ctp[1], c2=ctp[2], c3=ctp[3];
  float4* po = (float4*)(pcl + ((size_t)head*T_T + t)*D_H) + fs*4;
  po[0] = make_float4((w0.x+EPS_C*c0.x)*dinv,(w0.y+EPS_C*c0.y)*dinv,(w0.z+EPS_C*c0.z)*dinv,(w0.w+EPS_C*c0.w)*dinv);
  po[1] = make_float4((w1.x+EPS_C*c1.x)*dinv,(w1.y+EPS_C*c1.y)*dinv,(w1.z+EPS_C*c1.z)*dinv,(w1.w+EPS_C*c1.w)*dinv);
  po[2] = make_float4((w2.x+EPS_C*c2.x)*dinv,(w2.y+EPS_C*c2.y)*dinv,(w2.z+EPS_C*c2.z)*dinv,(w2.w+EPS_C*c2.w)*dinv);
  po[3] = make_float4((w3.x+EPS_C*c3.x)*dinv,(w3.y+EPS_C*c3.y)*dinv,(w3.z+EPS_C*c3.z)*dinv,(w3.w+EPS_C*c3.w)*dinv);
}

// ---------------- Kernel D: MLP + LN + GELU + score + softmax -------------
#define FMA4(A,s,W) {A.x+=(s)*W.x; A.y+=(s)*W.y; A.z+=(s)*W.z; A.w+=(s)*W.w;}
__global__ __launch_bounds__(256) void mlp_kern(
    const float* __restrict__ pcl, const float* __restrict__ v,
    const float* __restrict__ mask,
    const float* __restrict__ encw, const float* __restrict__ encb,
    const float* __restrict__ lng, const float* __restrict__ lnb,
    const float* __restrict__ decw, const float* __restrict__ decb,
    float* __restrict__ probsout, float* __restrict__ scoreout){
  int head = blockIdx.x, tblk = blockIdx.y;   // grid (48,32)
  int t0 = tblk*32;
  int n = head / H_H;
  __shared__ float xs[32*132];
  __shared__ float wts[32*132];
  __shared__ float h1s[32*132];
  int colT = threadIdx.x & 15, rowT = threadIdx.x >> 4;
  int r0 = rowT, r1 = rowT + 16;
  const float* pclrow = pcl + ((size_t)head*T_T + t0)*D_H;
  const float* vrow   = v   + ((size_t)head*T_T + t0)*D_H;
  for(int i=threadIdx.x;i<512;i+=256){
    int r=i>>4, q=i&15;
    ((float4*)(xs + r*132))[q]      = ((const float4*)(pclrow + r*64))[q];
    ((float4*)(xs + r*132 + 64))[q] = ((const float4*)(vrow   + r*64))[q];
  }
  float4 bias0 = ((const float4*)encb)[colT];
  float4 bias1 = ((const float4*)encb)[colT+16];
  float4 A0=bias0, A1=bias1, B0=bias0, B1=bias1;
  for(int kc=0;kc<4;kc++){
    __syncthreads();
    for(int i=threadIdx.x;i<1024;i+=256){
      int k=i>>5, q=i&31;
      ((float4*)(wts + k*132))[q] = ((const float4*)(encw + (size_t)(kc*32+k)*128))[q];
    }
    __syncthreads();
    #pragma unroll
    for(int kq=0;kq<8;kq++){
      float4 x0 = ((const float4*)(xs + r0*132 + kc*32))[kq];
      float4 x1 = ((const float4*)(xs + r1*132 + kc*32))[kq];
      #pragma unroll
      for(int kk=0;kk<4;kk++){
        const float* wrow = wts + (kq*4+kk)*132;
        float4 wa = ((const float4*)wrow)[colT];
        float4 wb = ((const float4*)wrow)[colT+16];
        float xv0 = (kk==0)?x0.x:(kk==1)?x0.y:(kk==2)?x0.z:x0.w;
        float xv1 = (kk==0)?x1.x:(kk==1)?x1.y:(kk==2)?x1.z:x1.w;
        FMA4(A0,xv0,wa); FMA4(A1,xv0,wb);
        FMA4(B0,xv1,wa); FMA4(B1,xv1,wb);
      }
    }
  }
  float4 lg0 = ((const float4*)lng)[colT], lg1 = ((const float4*)lng)[colT+16];
  float4 lb0 = ((const float4*)lnb)[colT], lb1 = ((const float4*)lnb)[colT+16];
  float s0 = A0.x+A0.y+A0.z+A0.w + A1.x+A1.y+A1.z+A1.w;
  float s1 = B0.x+B0.y+B0.z+B0.w + B1.x+B1.y+B1.z+B1.w;
  for(int o=1;o<16;o<<=1){ s0 += __shfl_xor(s0,o,64); s1 += __shfl_xor(s1,o,64); }
  float mu0 = s0*(1.0f/128.0f), mu1 = s1*(1.0f/128.0f);
  float v0=0.f, v1=0.f;
  { float d;
    d=A0.x-mu0; v0+=d*d; d=A0.y-mu0; v0+=d*d; d=A0.z-mu0; v0+=d*d; d=A0.w-mu0; v0+=d*d;
    d=A1.x-mu0; v0+=d*d; d=A1.y-mu0; v0+=d*d; d=A1.z-mu0; v0+=d*d; d=A1.w-mu0; v0+=d*d;
    d=B0.x-mu1; v1+=d*d; d=B0.y-mu1; v1+=d*d; d=B0.z-mu1; v1+=d*d; d=B0.w-mu1; v1+=d*d;
    d=B1.x-mu1; v1+=d*d; d=B1.y-mu1; v1+=d*d; d=B1.z-mu1; v1+=d*d; d=B1.w-mu1; v1+=d*d; }
  for(int o=1;o<16;o<<=1){ v0 += __shfl_xor(v0,o,64); v1 += __shfl_xor(v1,o,64); }
  float den0 = sqrtf(v0*(1.0f/128.0f)+1e-5f);
  float den1 = sqrtf(v1*(1.0f/128.0f)+1e-5f);
  #define GELU(x) ((x)*0.5f*(1.0f+erff((x)*0.70710678118654752f)))
  #define LNG(a,mu,dn,g,b) GELU(((a)-(mu))/(dn)*(g)+(b))
  float4 H;
  H.x=LNG(A0.x,mu0,den0,lg0.x,lb0.x); H.y=LNG(A0.y,mu0,den0,lg0.y,lb0.y);
  H.z=LNG(A0.z,mu0,den0,lg0.z,lb0.z); H.w=LNG(A0.w,mu0,den0,lg0.w,lb0.w);
  ((float4*)(h1s + r0*132))[colT] = H;
  H.x=LNG(A1.x,mu0,den0,lg1.x,lb1.x); H.y=LNG(A1.y,mu0,den0,lg1.y,lb1.y);
  H.z=LNG(A1.z,mu0,den0,lg1.z,lb1.z); H.w=LNG(A1.w,mu0,den0,lg1.w,lb1.w);
  ((float4*)(h1s + r0*132))[colT+16] = H;
  H.x=LNG(B0.x,mu1,den1,lg0.x,lb0.x); H.y=LNG(B0.y,mu1,den1,lg0.y,lb0.y);
  H.z=LNG(B0.z,mu1,den1,lg0.z,lb0.z); H.w=LNG(B0.w,mu1,den1,lg0.w,lb0.w);
  ((float4*)(h1s + r1*132))[colT] = H;
  H.x=LNG(B1.x,mu1,den1,lg1.x,lb1.x); H.y=LNG(B1.y,mu1,den1,lg1.y,lb1.y);
  H.z=LNG(B1.z,mu1,den1,lg1.z,lb1.z); H.w=LNG(B1.w,mu1,den1,lg1.w,lb1.w);
  ((float4*)(h1s + r1*132))[colT+16] = H;
  bias0 = ((const float4*)decb)[colT];
  bias1 = ((const float4*)decb)[colT+16];
  A0=bias0; A1=bias1; B0=bias0; B1=bias1;
  for(int kc=0;kc<4;kc++){
    __syncthreads();
    for(int i=threadIdx.x;i<1024;i+=256){
      int k=i>>5, q=i&31;
      ((float4*)(wts + k*132))[q] = ((const float4*)(decw + (size_t)(kc*32+k)*128))[q];
    }
    __syncthreads();
    #pragma unroll
    for(int kq=0;kq<8;kq++){
      float4 x0 = ((const float4*)(h1s + r0*132 + kc*32))[kq];
      float4 x1 = ((const float4*)(h1s + r1*132 + kc*32))[kq];
      #pragma unroll
      for(int kk=0;kk<4;kk++){
        const float* wrow = wts + (kq*4+kk)*132;
        float4 wa = ((const float4*)wrow)[colT];
        float4 wb = ((const float4*)wrow)[colT+16];
        float xv0 = (kk==0)?x0.x:(kk==1)?x0.y:(kk==2)?x0.z:x0.w;
        float xv1 = (kk==0)?x1.x:(kk==1)?x1.y:(kk==2)?x1.z:x1.w;
        FMA4(A0,xv0,wa); FMA4(A1,xv0,wb);
        FMA4(B0,xv1,wa); FMA4(B1,xv1,wb);
      }
    }
  }
  const float* mrow = mask + n*T_T;
  int c0 = colT*4, c1 = colT*4 + 64;
  float rm0[4], rm1[4];
  #pragma unroll
  for(int i=0;i<4;i++){ rm0[i]=mrow[(c0+i)*8]; rm1[i]=mrow[(c1+i)*8]; }
  float sA[8], sB[8];
  sA[0]=(rm0[0]<-1.f)?-10000.f:A0.x; sA[1]=(rm0[1]<-1.f)?-10000.f:A0.y;
  sA[2]=(rm0[2]<-1.f)?-10000.f:A0.z; sA[3]=(rm0[3]<-1.f)?-10000.f:A0.w;
  sA[4]=(rm1[0]<-1.f)?-10000.f:A1.x; sA[5]=(rm1[1]<-1.f)?-10000.f:A1.y;
  sA[6]=(rm1[2]<-1.f)?-10000.f:A1.z; sA[7]=(rm1[3]<-1.f)?-10000.f:A1.w;
  sB[0]=(rm0[0]<-1.f)?-10000.f:B0.x; sB[1]=(rm0[1]<-1.f)?-10000.f:B0.y;
  sB[2]=(rm0[2]<-1.f)?-10000.f:B0.z; sB[3]=(rm0[3]<-1.f)?-10000.f:B0.w;
  sB[4]=(rm1[0]<-1.f)?-10000.f:B1.x; sB[5]=(rm1[1]<-1.f)?-10000.f:B1.y;
  sB[6]=(rm1[2]<-1.f)?-10000.f:B1.z; sB[7]=(rm1[3]<-1.f)?-10000.f:B1.w;
  float mx0=sA[0], mx1=sB[0];
  #pragma unroll
  for(int i=1;i<8;i++){ mx0=fmaxf(mx0,sA[i]); mx1=fmaxf(mx1,sB[i]); }
  for(int o=1;o<16;o<<=1){ mx0=fmaxf(mx0,__shfl_xor(mx0,o,64)); mx1=fmaxf(mx1,__shfl_xor(mx1,o,64)); }
  float Z0=0.f, Z1=0.f;
  #pragma unroll
  for(int i=0;i<8;i++){ sA[i]=expf(sA[i]-mx0); Z0+=sA[i]; sB[i]=expf(sB[i]-mx1); Z1+=sB[i]; }
  for(int o=1;o<16;o<<=1){ Z0+=__shfl_xor(Z0,o,64); Z1+=__shfl_xor(Z1,o,64); }
  float zi0=1.0f/Z0, zi1=1.0f/Z1;
  size_t rb0 = ((size_t)head*T_T + t0 + r0)*TM_;
  size_t rb1 = ((size_t)head*T_T + t0 + r1)*TM_;
  ((float4*)(probsout+rb0))[colT]    = make_float4(sA[0]*zi0,sA[1]*zi0,sA[2]*zi0,sA[3]*zi0);
  ((float4*)(probsout+rb0))[colT+16] = make_float4(sA[4]*zi0,sA[5]*zi0,sA[6]*zi0,sA[7]*zi0);
  ((float4*)(probsout+rb1))[colT]    = make_float4(sB[0]*zi1,sB[1]*zi1,sB[2]*zi1,sB[3]*zi1);
  ((float4*)(probsout+rb1))[colT+16] = make_float4(sB[4]*zi1,sB[5]*zi1,sB[6]*zi1,sB[7]*zi1);
  ((float4*)(scoreout+rb0))[colT]    = A0;
  ((float4*)(scoreout+rb0))[colT+16] = A1;
  ((float4*)(scoreout+rb1))[colT]    = B0;
  ((float4*)(scoreout+rb1))[colT+16] = B1;
}

// ---------------- Kernel E: per-row KL + MSE ------------------------------
__global__ __launch_bounds__(256) void loss_kern(
    const float* __restrict__ truth, const float* __restrict__ mask,
    const float* __restrict__ score, float* __restrict__ klrow,
    float* __restrict__ mserow){
  int row = blockIdx.x;               // head*1024 + t
  int n = row / (H_H*T_T);
  __shared__ float a[1024];
  __shared__ float mk[1024];
  __shared__ float sc[128];
  __shared__ float red4[4];
  const float* ar = truth + (size_t)row*T_T;
  const float* mr = mask + n*T_T;
  const float* sr = score + (size_t)row*TM_;
  if(threadIdx.x < 256){
    ((float4*)a)[threadIdx.x]  = ((const float4*)ar)[threadIdx.x];
    ((float4*)mk)[threadIdx.x] = ((const float4*)mr)[threadIdx.x];
  }
  for(int i=threadIdx.x;i<128;i+=256) sc[i]=sr[i];
  __syncthreads();
  float ma=-3.4e38f, ms=-3.4e38f;
  for(int j=threadIdx.x;j<1024;j+=256){
    ma=fmaxf(ma,a[j]+mk[j]);
    ms=fmaxf(ms,sc[j>>3]+mk[j]);
  }
  ma = waveMax(ma);
  if((threadIdx.x&63)==0) red4[threadIdx.x>>6]=ma;
  __syncthreads();
  ma = fmaxf(fmaxf(red4[0],red4[1]),fmaxf(red4[2],red4[3]));
  __syncthreads();
  ms = waveMax(ms);
  if((threadIdx.x&63)==0) red4[threadIdx.x>>6]=ms;
  __syncthreads();
  ms = fmaxf(fmaxf(red4[0],red4[1]),fmaxf(red4[2],red4[3]));
  __syncthreads();
  float Za=0, Zs=0;
  for(int j=threadIdx.x;j<1024;j+=256){
    Za += expf(a[j]+mk[j]-ma);
    Zs += expf(sc[j>>3]+mk[j]-ms);
  }
  Za = waveSum(Za);
  if((threadIdx.x&63)==0) red4[threadIdx.x>>6]=Za;
  __syncthreads();
  Za = (red4[0]+red4[1])+(red4[2]+red4[3]);
  __syncthreads();
  Zs = waveSum(Zs);
  if((threadIdx.x&63)==0) red4[threadIdx.x>>6]=Zs;
  __syncthreads();
  Zs = (red4[0]+red4[1])+(red4[2]+red4[3]);
  __syncthreads();
  float lZs = logf(Zs);
  float kl=0, mse=0;
  for(int j=threadIdx.x;j<1024;j+=256){
    float mkj = mk[j];
    float scj = sc[j>>3];
    float aj = a[j];
    if(mkj > -1.0f){
      float pt = expf(aj+mkj-ma)/Za;
      float logpt = logf(fmaxf(pt,1e-12f));
      float logp = (scj+mkj-ms) - lZs;
      kl += pt*(logpt-logp);
    }
    float sv = (mkj < -1.0f)?0.f:scj;
    float av = (mkj < -1.0f)?0.f:aj;
    float d = sv-av; mse += d*d;
  }
  kl = waveSum(kl);
  if((threadIdx.x&63)==0) red4[threadIdx.x>>6]=kl;
  __syncthreads();
  kl = (red4[0]+red4[1])+(red4[2]+red4[3]);
  __syncthreads();
  mse = waveSum(mse);
  if((threadIdx.x&63)==0) red4[threadIdx.x>>6]=mse;
  __syncthreads();
  if(threadIdx.x==0){
    mse = (red4[0]+red4[1])+(red4[2]+red4[3]);
    klrow[row]=kl; mserow[row]=mse;
  }
}

// ---------------- Kernel F: final loss ------------------------------------
__global__ __launch_bounds__(256) void finloss_kern(
    const float* __restrict__ klrow, const float* __restrict__ mserow,
    const float* __restrict__ mask, float* __restrict__ out0){
  __shared__ double reds[256];
  double kls=0, mses=0;
  for(int i=threadIdx.x;i<N_H*T_T;i+=256){ kls+=(double)klrow[i]; mses+=(double)mserow[i]; }
  double vcnt=0;
  for(int i=threadIdx.x;i<N_B*T_T;i+=256) if(mask[i] > -1.0f) vcnt+=1.0;
  reds[threadIdx.x]=kls; __syncthreads();
  for(int o=128;o;o>>=1){ if(threadIdx.x<o) reds[threadIdx.x]+=reds[threadIdx.x+o]; __syncthreads(); }
  double klsum = reds[0]; __syncthreads();
  reds[threadIdx.x]=mses; __syncthreads();
  for(int o=128;o;o>>=1){ if(threadIdx.x<o) reds[threadIdx.x]+=reds[threadIdx.x+o]; __syncthreads(); }
  double msesum = reds[0]; __syncthreads();
  reds[threadIdx.x]=vcnt; __syncthreads();
  for(int o=128;o;o>>=1){ if(threadIdx.x<o) reds[threadIdx.x]+=reds[threadIdx.x+o]; __syncthreads(); }
  if(threadIdx.x==0){
    double denom = reds[0] * (double)(H_H*T_T);
    double loss = klsum/denom*0.25 + msesum/((double)N_B*H_H*T_T*T_T);
    out0[0]=(float)loss;
  }
}

// ---------------- Top-k pipeline ------------------------------------------
__global__ void topk_init(unsigned* __restrict__ hist, unsigned* __restrict__ state,
                          unsigned* __restrict__ tiecnt){
  int i = blockIdx.x*256+threadIdx.x;
  if(i < 4*256) hist[i]=0;
  if(i < 4){ state[i*4+0]=0u; state[i*4+1]=KSEL; state[i*4+2]=0u; tiecnt[i]=0u; }
}

__global__ __launch_bounds__(256) void topk_hist(
    const float* __restrict__ probs, const float* __restrict__ mask,
    const unsigned* __restrict__ state, unsigned* __restrict__ hist, int level){
  __shared__ unsigned lh[4*256];
  for(int i=threadIdx.x;i<1024;i+=256) lh[i]=0;
  __syncthreads();
  unsigned pmask = (level==0)?0u:(0xFFFFFFFFu << (32-8*level));
  unsigned pref[4];
  for(int b=0;b<4;b++) pref[b]=state[b*4+0] & pmask;
  int shift = 24-8*level;
  size_t total = (size_t)N_B*PER_BATCH;
  for(size_t idx = (size_t)blockIdx.x*256+threadIdx.x; idx < total; idx += (size_t)gridDim.x*256){
    int b = (int)(idx / PER_BATCH);
    unsigned r = (unsigned)(idx - (size_t)b*PER_BATCH);
    int t = (int)((r>>7)&1023u);
    float val = probs[idx];
    if(!(mask[b*T_T+t] > -1.0f)) val = 0.0f;
    unsigned u = __float_as_uint(val);
    if((u & pmask) == pref[b]) atomicAdd(&lh[b*256+((u>>shift)&255u)],1u);
  }
  __syncthreads();
  for(int i=threadIdx.x;i<1024;i+=256){
    unsigned c = lh[i];
    if(c) atomicAdd(&hist[i], c);
  }
}

__global__ void topk_scan(unsigned* __restrict__ hist, unsigned* __restrict__ state, int level){
  int b = blockIdx.x;
  if(threadIdx.x==0){
    const unsigned* h = hist + b*256;
    unsigned remk = state[b*4+1];
    unsigned cum = 0; int sel=0;
    for(int bin=255; bin>=0; bin--){
      unsigned c = h[bin];
      if(remk <= cum + c){ sel=bin; break; }
      cum += c;
    }
    state[b*4+0] |= ((unsigned)sel) << (24-8*level);
    state[b*4+1] = remk - cum;
    state[b*4+2] += cum;
  }
  __syncthreads();
  for(int i=threadIdx.x;i<256;i+=blockDim.x) hist[b*256+i]=0;
}

__global__ __launch_bounds__(256) void topk_write(
    const float* __restrict__ probs, const float* __restrict__ mask,
    const unsigned* __restrict__ state, float* __restrict__ pam,
    unsigned* __restrict__ ties, unsigned* __restrict__ tiecnt){
  unsigned thr[4];
  for(int b=0;b<4;b++) thr[b]=state[b*4+0];
  size_t total=(size_t)N_B*PER_BATCH;
  for(size_t idx=(size_t)blockIdx.x*256+threadIdx.x; idx<total; idx += (size_t)gridDim.x*256){
    int b = (int)(idx / PER_BATCH);
    unsigned r = (unsigned)(idx - (size_t)b*PER_BATCH);
    int t = (int)((r>>7)&1023u);
    float val = probs[idx];
    if(!(mask[b*T_T+t] > -1.0f)) val=0.0f;
    unsigned u=__float_as_uint(val);
    float o = -10000.0f;
    if(u > thr[b]) o = 0.0f;
    else if(u == thr[b]){
      unsigned pos = atomicAdd(&tiecnt[b],1u);
      if(pos < 65536u) ties[(size_t)b*65536+pos]=r;
    }
    pam[idx]=o;
  }
}

__global__ __launch_bounds__(256) void topk_ties(
    const unsigned* __restrict__ state, const unsigned* __restrict__ ties,
    const unsigned* __restrict__ tiecnt, float* __restrict__ pam){
  int b = blockIdx.x;
  unsigned needed = state[b*4+1];
  unsigned nt = min(tiecnt[b], 65536u);
  __shared__ unsigned redu[256];
  __shared__ unsigned lohi[2];
  if(threadIdx.x==0){ lohi[0]=0u; lohi[1]=PER_BATCH; }
  __syncthreads();
  if(needed == 0 || nt == 0) return;
  while(true){
    __syncthreads();
    unsigned lo=lohi[0], hi=lohi[1];
    if(hi-lo<=1u) break;
    unsigned mid=(lo+hi)>>1;
    unsigned c=0;
    for(unsigned i=threadIdx.x;i<nt;i+=256) c += (ties[(size_t)b*65536+i] < mid)?1u:0u;
    redu[threadIdx.x]=c; __syncthreads();
    for(int o=128;o;o>>=1){ if(threadIdx.x<o) redu[threadIdx.x]+=redu[threadIdx.x+o]; __syncthreads(); }
    if(threadIdx.x==0){ if(redu[0]>=needed) lohi[1]=mid; else lohi[0]=mid; }
  }
  __syncthreads();
  unsigned X=lohi[1];
  for(unsigned i=threadIdx.x;i<nt;i+=256){
    unsigned r=ties[(size_t)b*65536+i];
    if(r < X) pam[(size_t)b*PER_BATCH + r]=0.0f;
  }
}

// ---------------- launcher ------------------------------------------------
extern "C" void kernel_launch(void* const* d_in, const int* in_sizes, int n_in,
                              void* d_out, int out_size, void* d_ws, size_t ws_size,
                              hipStream_t stream) {
  const float* v     = (const float*)d_in[2];
  const float* qfa   = (const float*)d_in[3];
  const float* kfa   = (const float*)d_in[4];
  const float* mask  = (const float*)d_in[8];
  const float* truth = (const float*)d_in[9];
  const float* pm    = (const float*)d_in[11];
  const float* encw  = (const float*)d_in[12];
  const float* encb  = (const float*)d_in[13];
  const float* lng   = (const float*)d_in[14];
  const float* lnb   = (const float*)d_in[15];
  const float* decw  = (const float*)d_in[16];
  const float* decb  = (const float*)d_in[17];
  float* out = (float*)d_out;
  float* ws  = (float*)d_ws;

  float* ctx    = ws + 1024;                   // 48*266*64 = 817152
  float* ksum   = ctx + (size_t)N_H*F_F*64;    // 12768
  float* klrow  = ksum + N_H*F_F;              // 49152
  float* mserow = klrow + N_H*T_T;             // 49152
  unsigned* hist   = (unsigned*)(mserow + N_H*T_T); // 1024
  unsigned* state  = hist + 1024;              // 16
  unsigned* tiecnt = state + 16;               // 4 (+pad)
  unsigned* ties   = tiecnt + 12;              // 4*65536
  float* mf       = (float*)(ties + 4*65536);  // 48*266 = 12768
  float* ksum_tot = mf + N_H*F_F;              // 48
  float* ctx_tot  = ksum_tot + 48;             // 48*64 = 3072

  float* pcl   = out + 1;
  float* probs = pcl + (size_t)N_H*T_T*D_H;
  float* pam   = probs + (size_t)N_H*T_T*TM_;

  keyfeat_kern<<<dim3(N_H,NCHUNK),256,0,stream>>>(kfa, pm, mask, ctx, ksum, mf);
  fixup_kern<<<N_H,256,0,stream>>>(mf, mask, ctx, ksum, ksum_tot, ctx_tot);
  qfeat_kern<<<dim3(N_H,16),256,0,stream>>>(qfa, pm, ctx, ksum, ksum_tot, ctx_tot, pcl);
  mlp_kern<<<dim3(N_H,32),256,0,stream>>>(pcl, v, mask, encw, encb, lng, lnb,
                                          decw, decb, probs, pam /*score*/);
  loss_kern<<<N_H*T_T,256,0,stream>>>(truth, mask, pam /*score*/, klrow, mserow);
  finloss_kern<<<1,256,0,stream>>>(klrow, mserow, mask, out);
  topk_init<<<4,256,0,stream>>>(hist, state, tiecnt);
  for(int lvl=0;lvl<4;lvl++){
    topk_hist<<<2048,256,0,stream>>>(probs, mask, state, hist, lvl);
    topk_scan<<<4,64,0,stream>>>(hist, state, lvl);
  }
  topk_write<<<2048,256,0,stream>>>(probs, mask, state, pam, ties, tiecnt);
  topk_ties<<<4,256,0,stream>>>(state, ties, tiecnt, pam);
}

// Round 7
// 703.199 us; speedup vs baseline: 2.5096x; 1.0259x over previous
//
#include <hip/hip_runtime.h>
#include <hip/hip_bf16.h>
#include <math.h>

#define N_B 4
#define H_H 12
#define T_T 1024
#define D_H 64
#define F_F 266
#define N_H 48          // N_B*H_H
#define TM_ 128
#define KSEL 98304u     // kk*T*H = 8*1024*12
#define PER_BATCH 1572864  // H*T*TM
#define FP_ 272         // padded F for partial buffers

static __device__ __forceinline__ float waveSum(float v){
  for(int o=32;o;o>>=1) v += __shfl_xor(v,o,64);
  return v;
}
static __device__ __forceinline__ float waveMax(float v){
  for(int o=32;o;o>>=1) v = fmaxf(v,__shfl_xor(v,o,64));
  return v;
}

#define DN_C 0.35355339059327373f   // 64^-0.25 = 2^-1.5
#define DIAG_C 0.0625f              // 0.5 * 64^-0.5
#define RATIO_C 0.06131393394849658f // 266^-0.5
#define EPS_C 1e-4f

// ---------------- Kernel A0: per-(head,t) diag ----------------------------
__global__ __launch_bounds__(256) void diag_kern(
    const float* __restrict__ kfa, float* __restrict__ diags){
  int head = blockIdx.x; int t = blockIdx.y*256 + threadIdx.x;
  const float4* xp = (const float4*)(kfa + ((size_t)head*T_T + t)*D_H);
  float diag = 0.f;
  #pragma unroll
  for(int kk=0;kk<16;kk++){ float4 x = xp[kk];
    diag += x.x*x.x + x.y*x.y + x.z*x.z + x.w*x.w; }
  diags[head*T_T + t] = diag * DIAG_C;
}

// ---------------- Kernel B: key features, lane-owns-f ---------------------
// grid (48, 5 fchunks, 4 tblocks), 64 threads (1 wave). Lane = feature.
// No max subtraction during accumulation (safe: |dd| << 88); per-lane max
// tracked with 1 fmax; global rescale exp(-m_head) applied in fixup.
// vfa sparsity: t contributes only to ctx[f][t>>4] when t%16<8 -> ctx rows
// for this tblock are d = tb*16..tb*16+15, disjoint across tblocks.
__global__ __launch_bounds__(64) void keyfeat_kern(
    const float* __restrict__ kfa, const float* __restrict__ pm,
    const float* __restrict__ mask, const float* __restrict__ diags,
    float* __restrict__ ctxraw, float* __restrict__ ksumP,
    float* __restrict__ mfP){
  int head = blockIdx.x, fc = blockIdx.y, tb = blockIdx.z;
  int lane = threadIdx.x;
  int f = fc*64 + lane;
  bool fv = (f < F_F);
  int n = head / H_H;
  float4 p[16];
  if(fv){
    const float4* pr = (const float4*)(pm + (size_t)f*D_H);
    #pragma unroll
    for(int kk=0;kk<16;kk++) p[kk] = pr[kk];
  } else {
    #pragma unroll
    for(int kk=0;kk<16;kk++) p[kk] = make_float4(0.f,0.f,0.f,0.f);
  }
  const float* xbase = kfa  + ((size_t)head*T_T + tb*256)*D_H;
  const float* mrow  = mask + n*T_T + tb*256;
  const float* drow  = diags + head*T_T + tb*256;
  float ksum = 0.f, mymax = -3.4e38f;
  for(int g=0; g<16; g++){
    float cg = 0.f;
    for(int tt=0; tt<16; tt++){
      int tl = g*16 + tt;
      const float4* xp = (const float4*)(xbase + (size_t)tl*D_H);
      float s0=0,s1=0,s2=0,s3=0;
      #pragma unroll
      for(int kk=0;kk<16;kk++){ float4 x4 = xp[kk];
        s0+=x4.x*p[kk].x; s1+=x4.y*p[kk].y; s2+=x4.z*p[kk].z; s3+=x4.w*p[kk].w; }
      float dd = DN_C*((s0+s1)+(s2+s3));
      mymax = fmaxf(mymax, dd);
      float e = expf(dd - drow[tl]);
      ksum += e;
      if(tt < 8){
        float vfac = (mrow[tl] > -1.0f) ? 1.f : 0.f;
        cg += e*vfac;
      }
    }
    if(fv) ctxraw[((size_t)head*D_H + tb*16 + g)*FP_ + f] = cg;
  }
  if(fv){
    ksumP[(size_t)(tb*N_H+head)*FP_ + f] = ksum;
    mfP  [(size_t)(tb*N_H+head)*FP_ + f] = mymax;
  }
}

// ---------------- Kernel B2: per-head fixup -------------------------------
__global__ __launch_bounds__(256) void fixup_kern(
    const float* __restrict__ mfP, const float* __restrict__ ksumP,
    const float* __restrict__ ctxraw, const float* __restrict__ mask,
    float* __restrict__ ctx, float* __restrict__ ksum,
    float* __restrict__ ksum_tot, float* __restrict__ ctx_tot){
  int head = blockIdx.x; int n = head/H_H;
  __shared__ float mred[4];
  __shared__ float segc[64];
  __shared__ float part[4][64];
  __shared__ float kpart[4];
  float mx = -3.4e38f;
  for(int tb=0;tb<4;tb++)
    for(int f=threadIdx.x; f<F_F; f+=256)
      mx = fmaxf(mx, mfP[(size_t)(tb*N_H+head)*FP_ + f]);
  mx = waveMax(mx);
  if((threadIdx.x&63)==0) mred[threadIdx.x>>6]=mx;
  __syncthreads();
  float m_head = fmaxf(fmaxf(mred[0],mred[1]),fmaxf(mred[2],mred[3]));
  float e_mh = expf(-m_head);
  if(threadIdx.x < 64){
    int d = threadIdx.x; float c=0.f;
    for(int i=0;i<8;i++) c += (mask[n*T_T + 16*d + i] > -1.0f) ? 1.f : 0.f;
    segc[d] = c;
  }
  __syncthreads();
  int g = threadIdx.x>>6, d = threadIdx.x&63;
  float ct = 0.f, kt = 0.f;
  for(int f=g; f<F_F; f+=4){
    float craw = ctxraw[((size_t)head*D_H + d)*FP_ + f];
    float cf = RATIO_C*(craw*e_mh + EPS_C*segc[d]);
    ctx[((size_t)head*F_F+f)*64 + d] = cf;
    ct += cf;
    if(d==0){
      float ks = ksumP[(size_t)(0*N_H+head)*FP_+f] + ksumP[(size_t)(1*N_H+head)*FP_+f]
               + ksumP[(size_t)(2*N_H+head)*FP_+f] + ksumP[(size_t)(3*N_H+head)*FP_+f];
      float kf = RATIO_C*(ks*e_mh + EPS_C*(float)T_T);
      ksum[head*F_F+f] = kf;
      kt += kf;
    }
  }
  part[g][d] = ct;
  if(d==0) kpart[g] = kt;
  __syncthreads();
  if(threadIdx.x < 64)
    ctx_tot[head*64+threadIdx.x] =
      part[0][threadIdx.x]+part[1][threadIdx.x]+part[2][threadIdx.x]+part[3][threadIdx.x];
  if(threadIdx.x==0) ksum_tot[head] = kpart[0]+kpart[1]+kpart[2]+kpart[3];
}

// ---------------- Kernel C: query features + pcl (single sweep, online max) -
__global__ __launch_bounds__(256) void qfeat_kern(
    const float* __restrict__ qfa, const float* __restrict__ pm,
    const float* __restrict__ ctx, const float* __restrict__ ksum,
    const float* __restrict__ ksum_tot, const float* __restrict__ ctx_tot,
    float* __restrict__ pcl){
  int head = blockIdx.x, tc = blockIdx.y;   // grid (48,16), 256 threads
  int rl = threadIdx.x >> 2, fs = threadIdx.x & 3;
  int t = tc*64 + rl;
  __shared__ float pms[56*68];
  __shared__ float ctxs[56*68];
  __shared__ float ksums[56];
  const float* xp = qfa + ((size_t)head*T_T + t)*D_H;
  float4 xr[16];
  #pragma unroll
  for(int kk=0;kk<16;kk++) xr[kk] = ((const float4*)xp)[kk];
  float diag = 0.f;
  #pragma unroll
  for(int kk=0;kk<16;kk++)
    diag += xr[kk].x*xr[kk].x + xr[kk].y*xr[kk].y + xr[kk].z*xr[kk].z + xr[kk].w*xr[kk].w;
  diag *= DIAG_C;
  float m_run = -3.4e38f, S = 0.f;
  float4 acc[16];
  #pragma unroll
  for(int kk=0;kk<16;kk++) acc[kk] = make_float4(0.f,0.f,0.f,0.f);
  for(int c=0;c<5;c++){
    int f0 = c*56, CF = min(56, F_F-f0);
    __syncthreads();
    for(int i=threadIdx.x;i<CF*16;i+=256){
      int fl=i>>4, d4=i&15;
      ((float4*)(pms+fl*68))[d4]  = ((const float4*)(pm+(size_t)(f0+fl)*64))[d4];
      ((float4*)(ctxs+fl*68))[d4] = ((const float4*)(ctx+((size_t)head*F_F+f0+fl)*64))[d4];
    }
    for(int i=threadIdx.x;i<CF;i+=256) ksums[i]=ksum[head*F_F+f0+i];
    __syncthreads();
    int nj = (CF - fs + 3)>>2;
    for(int j=0;j<nj;j++){
      int fl = fs+4*j;
      const float4* pr = (const float4*)(pms + fl*68);
      float s0=0,s1=0,s2=0,s3=0;
      #pragma unroll
      for(int kk=0;kk<16;kk++){ float4 w4 = pr[kk];
        s0+=xr[kk].x*w4.x; s1+=xr[kk].y*w4.y; s2+=xr[kk].z*w4.z; s3+=xr[kk].w*w4.w; }
      float dd = DN_C*((s0+s1)+(s2+s3));
      if(dd > m_run){
        float fac = expf(m_run - dd);           // first: exp(-huge)=0 on zero accs
        S *= fac;
        #pragma unroll
        for(int kk=0;kk<16;kk++){
          acc[kk].x*=fac; acc[kk].y*=fac; acc[kk].z*=fac; acc[kk].w*=fac;
        }
        m_run = dd;
      }
      float e = expf(dd - diag - m_run);
      S += e * ksums[fl];
      const float4* cr = (const float4*)(ctxs + fl*68);
      #pragma unroll
      for(int kk=0;kk<16;kk++){ float4 c4=cr[kk];
        acc[kk].x+=e*c4.x; acc[kk].y+=e*c4.y; acc[kk].z+=e*c4.z; acc[kk].w+=e*c4.w; }
    }
  }
  // combine the 4 f-slices with max-rescale (butterfly)
  for(int st=1; st<=2; st<<=1){
    float mo = __shfl_xor(m_run, st, 64);
    float mc = fmaxf(m_run, mo);
    float fac = expf(m_run - mc);
    S *= fac;
    S += __shfl_xor(S, st, 64);
    #pragma unroll
    for(int kk=0;kk<16;kk++){
      acc[kk].x*=fac; acc[kk].y*=fac; acc[kk].z*=fac; acc[kk].w*=fac;
    }
    #pragma unroll
    for(int kk=0;kk<16;kk++){
      acc[kk].x += __shfl_xor(acc[kk].x,st,64);
      acc[kk].y += __shfl_xor(acc[kk].y,st,64);
      acc[kk].z += __shfl_xor(acc[kk].z,st,64);
      acc[kk].w += __shfl_xor(acc[kk].w,st,64);
    }
    m_run = mc;
  }
  float den = S + EPS_C * ksum_tot[head];
  float dinv = 1.0f/den;
  float4 w0,w1,w2,w3;
  if(fs==0){ w0=acc[0]; w1=acc[1]; w2=acc[2]; w3=acc[3]; }
  else if(fs==1){ w0=acc[4]; w1=acc[5]; w2=acc[6]; w3=acc[7]; }
  else if(fs==2){ w0=acc[8]; w1=acc[9]; w2=acc[10]; w3=acc[11]; }
  else { w0=acc[12]; w1=acc[13]; w2=acc[14]; w3=acc[15]; }
  const float4* ctp = ((const float4*)(ctx_tot + head*64)) + fs*4;
  float4 c0=ctp[0], c1=ctp[1], c2=ctp[2], c3=ctp[3];
  float4* po = (float4*)(pcl + ((size_t)head*T_T + t)*D_H) + fs*4;
  po[0] = make_float4((w0.x+EPS_C*c0.x)*dinv,(w0.y+EPS_C*c0.y)*dinv,(w0.z+EPS_C*c0.z)*dinv,(w0.w+EPS_C*c0.w)*dinv);
  po[1] = make_float4((w1.x+EPS_C*c1.x)*dinv,(w1.y+EPS_C*c1.y)*dinv,(w1.z+EPS_C*c1.z)*dinv,(w1.w+EPS_C*c1.w)*dinv);
  po[2] = make_float4((w2.x+EPS_C*c2.x)*dinv,(w2.y+EPS_C*c2.y)*dinv,(w2.z+EPS_C*c2.z)*dinv,(w2.w+EPS_C*c2.w)*dinv);
  po[3] = make_float4((w3.x+EPS_C*c3.x)*dinv,(w3.y+EPS_C*c3.y)*dinv,(w3.z+EPS_C*c3.z)*dinv,(w3.w+EPS_C*c3.w)*dinv);
}

// ---------------- Kernel D: MLP + LN + GELU + score + softmax -------------
#define FMA4(A,s,W) {A.x+=(s)*W.x; A.y+=(s)*W.y; A.z+=(s)*W.z; A.w+=(s)*W.w;}
__global__ __launch_bounds__(256) void mlp_kern(
    const float* __restrict__ pcl, const float* __restrict__ v,
    const float* __restrict__ mask,
    const float* __restrict__ encw, const float* __restrict__ encb,
    const float* __restrict__ lng, const float* __restrict__ lnb,
    const float* __restrict__ decw, const float* __restrict__ decb,
    float* __restrict__ probsout, float* __restrict__ scoreout){
  int head = blockIdx.x, tblk = blockIdx.y;   // grid (48,32)
  int t0 = tblk*32;
  int n = head / H_H;
  __shared__ float xs[32*132];
  __shared__ float wts[32*132];
  __shared__ float h1s[32*132];
  int colT = threadIdx.x & 15, rowT = threadIdx.x >> 4;
  int r0 = rowT, r1 = rowT + 16;
  const float* pclrow = pcl + ((size_t)head*T_T + t0)*D_H;
  const float* vrow   = v   + ((size_t)head*T_T + t0)*D_H;
  for(int i=threadIdx.x;i<512;i+=256){
    int r=i>>4, q=i&15;
    ((float4*)(xs + r*132))[q]      = ((const float4*)(pclrow + r*64))[q];
    ((float4*)(xs + r*132 + 64))[q] = ((const float4*)(vrow   + r*64))[q];
  }
  float4 bias0 = ((const float4*)encb)[colT];
  float4 bias1 = ((const float4*)encb)[colT+16];
  float4 A0=bias0, A1=bias1, B0=bias0, B1=bias1;
  for(int kc=0;kc<4;kc++){
    __syncthreads();
    for(int i=threadIdx.x;i<1024;i+=256){
      int k=i>>5, q=i&31;
      ((float4*)(wts + k*132))[q] = ((const float4*)(encw + (size_t)(kc*32+k)*128))[q];
    }
    __syncthreads();
    #pragma unroll
    for(int kq=0;kq<8;kq++){
      float4 x0 = ((const float4*)(xs + r0*132 + kc*32))[kq];
      float4 x1 = ((const float4*)(xs + r1*132 + kc*32))[kq];
      #pragma unroll
      for(int kk=0;kk<4;kk++){
        const float* wrow = wts + (kq*4+kk)*132;
        float4 wa = ((const float4*)wrow)[colT];
        float4 wb = ((const float4*)wrow)[colT+16];
        float xv0 = (kk==0)?x0.x:(kk==1)?x0.y:(kk==2)?x0.z:x0.w;
        float xv1 = (kk==0)?x1.x:(kk==1)?x1.y:(kk==2)?x1.z:x1.w;
        FMA4(A0,xv0,wa); FMA4(A1,xv0,wb);
        FMA4(B0,xv1,wa); FMA4(B1,xv1,wb);
      }
    }
  }
  float4 lg0 = ((const float4*)lng)[colT], lg1 = ((const float4*)lng)[colT+16];
  float4 lb0 = ((const float4*)lnb)[colT], lb1 = ((const float4*)lnb)[colT+16];
  float s0 = A0.x+A0.y+A0.z+A0.w + A1.x+A1.y+A1.z+A1.w;
  float s1 = B0.x+B0.y+B0.z+B0.w + B1.x+B1.y+B1.z+B1.w;
  for(int o=1;o<16;o<<=1){ s0 += __shfl_xor(s0,o,64); s1 += __shfl_xor(s1,o,64); }
  float mu0 = s0*(1.0f/128.0f), mu1 = s1*(1.0f/128.0f);
  float v0=0.f, v1=0.f;
  { float d;
    d=A0.x-mu0; v0+=d*d; d=A0.y-mu0; v0+=d*d; d=A0.z-mu0; v0+=d*d; d=A0.w-mu0; v0+=d*d;
    d=A1.x-mu0; v0+=d*d; d=A1.y-mu0; v0+=d*d; d=A1.z-mu0; v0+=d*d; d=A1.w-mu0; v0+=d*d;
    d=B0.x-mu1; v1+=d*d; d=B0.y-mu1; v1+=d*d; d=B0.z-mu1; v1+=d*d; d=B0.w-mu1; v1+=d*d;
    d=B1.x-mu1; v1+=d*d; d=B1.y-mu1; v1+=d*d; d=B1.z-mu1; v1+=d*d; d=B1.w-mu1; v1+=d*d; }
  for(int o=1;o<16;o<<=1){ v0 += __shfl_xor(v0,o,64); v1 += __shfl_xor(v1,o,64); }
  float den0 = sqrtf(v0*(1.0f/128.0f)+1e-5f);
  float den1 = sqrtf(v1*(1.0f/128.0f)+1e-5f);
  #define GELU(x) ((x)*0.5f*(1.0f+erff((x)*0.70710678118654752f)))
  #define LNG(a,mu,dn,g,b) GELU(((a)-(mu))/(dn)*(g)+(b))
  float4 H;
  H.x=LNG(A0.x,mu0,den0,lg0.x,lb0.x); H.y=LNG(A0.y,mu0,den0,lg0.y,lb0.y);
  H.z=LNG(A0.z,mu0,den0,lg0.z,lb0.z); H.w=LNG(A0.w,mu0,den0,lg0.w,lb0.w);
  ((float4*)(h1s + r0*132))[colT] = H;
  H.x=LNG(A1.x,mu0,den0,lg1.x,lb1.x); H.y=LNG(A1.y,mu0,den0,lg1.y,lb1.y);
  H.z=LNG(A1.z,mu0,den0,lg1.z,lb1.z); H.w=LNG(A1.w,mu0,den0,lg1.w,lb1.w);
  ((float4*)(h1s + r0*132))[colT+16] = H;
  H.x=LNG(B0.x,mu1,den1,lg0.x,lb0.x); H.y=LNG(B0.y,mu1,den1,lg0.y,lb0.y);
  H.z=LNG(B0.z,mu1,den1,lg0.z,lb0.z); H.w=LNG(B0.w,mu1,den1,lg0.w,lb0.w);
  ((float4*)(h1s + r1*132))[colT] = H;
  H.x=LNG(B1.x,mu1,den1,lg1.x,lb1.x); H.y=LNG(B1.y,mu1,den1,lg1.y,lb1.y);
  H.z=LNG(B1.z,mu1,den1,lg1.z,lb1.z); H.w=LNG(B1.w,mu1,den1,lg1.w,lb1.w);
  ((float4*)(h1s + r1*132))[colT+16] = H;
  bias0 = ((const float4*)decb)[colT];
  bias1 = ((const float4*)decb)[colT+16];
  A0=bias0; A1=bias1; B0=bias0; B1=bias1;
  for(int kc=0;kc<4;kc++){
    __syncthreads();
    for(int i=threadIdx.x;i<1024;i+=256){
      int k=i>>5, q=i&31;
      ((float4*)(wts + k*132))[q] = ((const float4*)(decw + (size_t)(kc*32+k)*128))[q];
    }
    __syncthreads();
    #pragma unroll
    for(int kq=0;kq<8;kq++){
      float4 x0 = ((const float4*)(h1s + r0*132 + kc*32))[kq];
      float4 x1 = ((const float4*)(h1s + r1*132 + kc*32))[kq];
      #pragma unroll
      for(int kk=0;kk<4;kk++){
        const float* wrow = wts + (kq*4+kk)*132;
        float4 wa = ((const float4*)wrow)[colT];
        float4 wb = ((const float4*)wrow)[colT+16];
        float xv0 = (kk==0)?x0.x:(kk==1)?x0.y:(kk==2)?x0.z:x0.w;
        float xv1 = (kk==0)?x1.x:(kk==1)?x1.y:(kk==2)?x1.z:x1.w;
        FMA4(A0,xv0,wa); FMA4(A1,xv0,wb);
        FMA4(B0,xv1,wa); FMA4(B1,xv1,wb);
      }
    }
  }
  const float* mrow = mask + n*T_T;
  int c0 = colT*4, c1 = colT*4 + 64;
  float rm0[4], rm1[4];
  #pragma unroll
  for(int i=0;i<4;i++){ rm0[i]=mrow[(c0+i)*8]; rm1[i]=mrow[(c1+i)*8]; }
  float sA[8], sB[8];
  sA[0]=(rm0[0]<-1.f)?-10000.f:A0.x; sA[1]=(rm0[1]<-1.f)?-10000.f:A0.y;
  sA[2]=(rm0[2]<-1.f)?-10000.f:A0.z; sA[3]=(rm0[3]<-1.f)?-10000.f:A0.w;
  sA[4]=(rm1[0]<-1.f)?-10000.f:A1.x; sA[5]=(rm1[1]<-1.f)?-10000.f:A1.y;
  sA[6]=(rm1[2]<-1.f)?-10000.f:A1.z; sA[7]=(rm1[3]<-1.f)?-10000.f:A1.w;
  sB[0]=(rm0[0]<-1.f)?-10000.f:B0.x; sB[1]=(rm0[1]<-1.f)?-10000.f:B0.y;
  sB[2]=(rm0[2]<-1.f)?-10000.f:B0.z; sB[3]=(rm0[3]<-1.f)?-10000.f:B0.w;
  sB[4]=(rm1[0]<-1.f)?-10000.f:B1.x; sB[5]=(rm1[1]<-1.f)?-10000.f:B1.y;
  sB[6]=(rm1[2]<-1.f)?-10000.f:B1.z; sB[7]=(rm1[3]<-1.f)?-10000.f:B1.w;
  float mx0=sA[0], mx1=sB[0];
  #pragma unroll
  for(int i=1;i<8;i++){ mx0=fmaxf(mx0,sA[i]); mx1=fmaxf(mx1,sB[i]); }
  for(int o=1;o<16;o<<=1){ mx0=fmaxf(mx0,__shfl_xor(mx0,o,64)); mx1=fmaxf(mx1,__shfl_xor(mx1,o,64)); }
  float Z0=0.f, Z1=0.f;
  #pragma unroll
  for(int i=0;i<8;i++){ sA[i]=expf(sA[i]-mx0); Z0+=sA[i]; sB[i]=expf(sB[i]-mx1); Z1+=sB[i]; }
  for(int o=1;o<16;o<<=1){ Z0+=__shfl_xor(Z0,o,64); Z1+=__shfl_xor(Z1,o,64); }
  float zi0=1.0f/Z0, zi1=1.0f/Z1;
  size_t rb0 = ((size_t)head*T_T + t0 + r0)*TM_;
  size_t rb1 = ((size_t)head*T_T + t0 + r1)*TM_;
  ((float4*)(probsout+rb0))[colT]    = make_float4(sA[0]*zi0,sA[1]*zi0,sA[2]*zi0,sA[3]*zi0);
  ((float4*)(probsout+rb0))[colT+16] = make_float4(sA[4]*zi0,sA[5]*zi0,sA[6]*zi0,sA[7]*zi0);
  ((float4*)(probsout+rb1))[colT]    = make_float4(sB[0]*zi1,sB[1]*zi1,sB[2]*zi1,sB[3]*zi1);
  ((float4*)(probsout+rb1))[colT+16] = make_float4(sB[4]*zi1,sB[5]*zi1,sB[6]*zi1,sB[7]*zi1);
  ((float4*)(scoreout+rb0))[colT]    = A0;
  ((float4*)(scoreout+rb0))[colT+16] = A1;
  ((float4*)(scoreout+rb1))[colT]    = B0;
  ((float4*)(scoreout+rb1))[colT+16] = B1;
}

// ---------------- Kernel E: per-row KL + MSE (v2: no libm, es cache) ------
__global__ __launch_bounds__(256) void loss_kern(
    const float* __restrict__ truth, const float* __restrict__ mask,
    const float* __restrict__ score, float* __restrict__ klrow,
    float* __restrict__ mserow){
  int row = blockIdx.x;               // head*1024 + t
  int n = row / (H_H*T_T);
  __shared__ float a[1024];
  __shared__ float mk[1024];
  __shared__ float es[1024];
  __shared__ float sc[128];
  __shared__ float red4[4];
  const float* ar = truth + (size_t)row*T_T;
  const float* mr = mask + n*T_T;
  const float* sr = score + (size_t)row*TM_;
  if(threadIdx.x < 256){
    ((float4*)a)[threadIdx.x]  = ((const float4*)ar)[threadIdx.x];
    ((float4*)mk)[threadIdx.x] = ((const float4*)mr)[threadIdx.x];
  }
  for(int i=threadIdx.x;i<128;i+=256) sc[i]=sr[i];
  __syncthreads();
  float ma=-3.4e38f, ms=-3.4e38f;
  for(int j=threadIdx.x;j<1024;j+=256){
    ma=fmaxf(ma,a[j]+mk[j]);
    ms=fmaxf(ms,sc[j>>3]+mk[j]);
  }
  ma = waveMax(ma);
  if((threadIdx.x&63)==0) red4[threadIdx.x>>6]=ma;
  __syncthreads();
  ma = fmaxf(fmaxf(red4[0],red4[1]),fmaxf(red4[2],red4[3]));
  __syncthreads();
  ms = waveMax(ms);
  if((threadIdx.x&63)==0) red4[threadIdx.x>>6]=ms;
  __syncthreads();
  ms = fmaxf(fmaxf(red4[0],red4[1]),fmaxf(red4[2],red4[3]));
  __syncthreads();
  float Za=0, Zs=0;
  for(int j=threadIdx.x;j<1024;j+=256){
    float ea = __expf(a[j]+mk[j]-ma);
    es[j] = ea;
    Za += ea;
    Zs += __expf(sc[j>>3]+mk[j]-ms);
  }
  Za = waveSum(Za);
  if((threadIdx.x&63)==0) red4[threadIdx.x>>6]=Za;
  __syncthreads();
  Za = (red4[0]+red4[1])+(red4[2]+red4[3]);
  __syncthreads();
  Zs = waveSum(Zs);
  if((threadIdx.x&63)==0) red4[threadIdx.x>>6]=Zs;
  __syncthreads();
  Zs = (red4[0]+red4[1])+(red4[2]+red4[3]);
  __syncthreads();
  float lZs = __logf(Zs), lZa = __logf(Za);
  float invZa = 1.0f/Za;
  float kl=0, mse=0;
  for(int j=threadIdx.x;j<1024;j+=256){
    float mkj = mk[j];
    float scj = sc[j>>3];
    float aj = a[j];
    if(mkj > -1.0f){
      float pt = es[j]*invZa;
      // log(pt) = aj+mkj-ma-lZa exactly when pt not clipped at 1e-12
      float logpt = (pt >= 1e-12f) ? (aj+mkj-ma-lZa) : -27.631021116f;
      float logp = (scj+mkj-ms) - lZs;
      kl += pt*(logpt-logp);
    }
    float sv = (mkj < -1.0f)?0.f:scj;
    float av = (mkj < -1.0f)?0.f:aj;
    float d = sv-av; mse += d*d;
  }
  kl = waveSum(kl);
  if((threadIdx.x&63)==0) red4[threadIdx.x>>6]=kl;
  __syncthreads();
  kl = (red4[0]+red4[1])+(red4[2]+red4[3]);
  __syncthreads();
  mse = waveSum(mse);
  if((threadIdx.x&63)==0) red4[threadIdx.x>>6]=mse;
  __syncthreads();
  if(threadIdx.x==0){
    mse = (red4[0]+red4[1])+(red4[2]+red4[3]);
    klrow[row]=kl; mserow[row]=mse;
  }
}

// ---------------- Kernel F: final loss ------------------------------------
__global__ __launch_bounds__(256) void finloss_kern(
    const float* __restrict__ klrow, const float* __restrict__ mserow,
    const float* __restrict__ mask, float* __restrict__ out0){
  __shared__ double reds[256];
  double kls=0, mses=0;
  for(int i=threadIdx.x;i<N_H*T_T;i+=256){ kls+=(double)klrow[i]; mses+=(double)mserow[i]; }
  double vcnt=0;
  for(int i=threadIdx.x;i<N_B*T_T;i+=256) if(mask[i] > -1.0f) vcnt+=1.0;
  reds[threadIdx.x]=kls; __syncthreads();
  for(int o=128;o;o>>=1){ if(threadIdx.x<o) reds[threadIdx.x]+=reds[threadIdx.x+o]; __syncthreads(); }
  double klsum = reds[0]; __syncthreads();
  reds[threadIdx.x]=mses; __syncthreads();
  for(int o=128;o;o>>=1){ if(threadIdx.x<o) reds[threadIdx.x]+=reds[threadIdx.x+o]; __syncthreads(); }
  double msesum = reds[0]; __syncthreads();
  reds[threadIdx.x]=vcnt; __syncthreads();
  for(int o=128;o;o>>=1){ if(threadIdx.x<o) reds[threadIdx.x]+=reds[threadIdx.x+o]; __syncthreads(); }
  if(threadIdx.x==0){
    double denom = reds[0] * (double)(H_H*T_T);
    double loss = klsum/denom*0.25 + msesum/((double)N_B*H_H*T_T*T_T);
    out0[0]=(float)loss;
  }
}

// ---------------- Top-k pipeline ------------------------------------------
__global__ void topk_init(unsigned* __restrict__ hist, unsigned* __restrict__ state,
                          unsigned* __restrict__ tiecnt){
  int i = blockIdx.x*256+threadIdx.x;
  if(i < 4*256) hist[i]=0;
  if(i < 4){ state[i*4+0]=0u; state[i*4+1]=KSEL; state[i*4+2]=0u; tiecnt[i]=0u; }
}

__global__ __launch_bounds__(256) void topk_hist(
    const float* __restrict__ probs, const float* __restrict__ mask,
    const unsigned* __restrict__ state, unsigned* __restrict__ hist, int level){
  __shared__ unsigned lh[4*256];
  for(int i=threadIdx.x;i<1024;i+=256) lh[i]=0;
  __syncthreads();
  unsigned pmask = (level==0)?0u:(0xFFFFFFFFu << (32-8*level));
  unsigned pref[4];
  for(int b=0;b<4;b++) pref[b]=state[b*4+0] & pmask;
  int shift = 24-8*level;
  size_t total = (size_t)N_B*PER_BATCH;
  for(size_t idx = (size_t)blockIdx.x*256+threadIdx.x; idx < total; idx += (size_t)gridDim.x*256){
    int b = (int)(idx / PER_BATCH);
    unsigned r = (unsigned)(idx - (size_t)b*PER_BATCH);
    int t = (int)((r>>7)&1023u);
    float val = probs[idx];
    if(!(mask[b*T_T+t] > -1.0f)) val = 0.0f;
    unsigned u = __float_as_uint(val);
    if((u & pmask) == pref[b]) atomicAdd(&lh[b*256+((u>>shift)&255u)],1u);
  }
  __syncthreads();
  for(int i=threadIdx.x;i<1024;i+=256){
    unsigned c = lh[i];
    if(c) atomicAdd(&hist[i], c);
  }
}

__global__ void topk_scan(unsigned* __restrict__ hist, unsigned* __restrict__ state, int level){
  int b = blockIdx.x;
  if(threadIdx.x==0){
    const unsigned* h = hist + b*256;
    unsigned remk = state[b*4+1];
    unsigned cum = 0; int sel=0;
    for(int bin=255; bin>=0; bin--){
      unsigned c = h[bin];
      if(remk <= cum + c){ sel=bin; break; }
      cum += c;
    }
    state[b*4+0] |= ((unsigned)sel) << (24-8*level);
    state[b*4+1] = remk - cum;
    state[b*4+2] += cum;
  }
  __syncthreads();
  for(int i=threadIdx.x;i<256;i+=blockDim.x) hist[b*256+i]=0;
}

__global__ __launch_bounds__(256) void topk_write(
    const float* __restrict__ probs, const float* __restrict__ mask,
    const unsigned* __restrict__ state, float* __restrict__ pam,
    unsigned* __restrict__ ties, unsigned* __restrict__ tiecnt){
  unsigned thr[4];
  for(int b=0;b<4;b++) thr[b]=state[b*4+0];
  size_t total=(size_t)N_B*PER_BATCH;
  for(size_t idx=(size_t)blockIdx.x*256+threadIdx.x; idx<total; idx += (size_t)gridDim.x*256){
    int b = (int)(idx / PER_BATCH);
    unsigned r = (unsigned)(idx - (size_t)b*PER_BATCH);
    int t = (int)((r>>7)&1023u);
    float val = probs[idx];
    if(!(mask[b*T_T+t] > -1.0f)) val=0.0f;
    unsigned u=__float_as_uint(val);
    float o = -10000.0f;
    if(u > thr[b]) o = 0.0f;
    else if(u == thr[b]){
      unsigned pos = atomicAdd(&tiecnt[b],1u);
      if(pos < 65536u) ties[(size_t)b*65536+pos]=r;
    }
    pam[idx]=o;
  }
}

__global__ __launch_bounds__(256) void topk_ties(
    const unsigned* __restrict__ state, const unsigned* __restrict__ ties,
    const unsigned* __restrict__ tiecnt, float* __restrict__ pam){
  int b = blockIdx.x;
  unsigned needed = state[b*4+1];
  unsigned nt = min(tiecnt[b], 65536u);
  __shared__ unsigned redu[256];
  __shared__ unsigned lohi[2];
  if(threadIdx.x==0){ lohi[0]=0u; lohi[1]=PER_BATCH; }
  __syncthreads();
  if(needed == 0 || nt == 0) return;
  while(true){
    __syncthreads();
    unsigned lo=lohi[0], hi=lohi[1];
    if(hi-lo<=1u) break;
    unsigned mid=(lo+hi)>>1;
    unsigned c=0;
    for(unsigned i=threadIdx.x;i<nt;i+=256) c += (ties[(size_t)b*65536+i] < mid)?1u:0u;
    redu[threadIdx.x]=c; __syncthreads();
    for(int o=128;o;o>>=1){ if(threadIdx.x<o) redu[threadIdx.x]+=redu[threadIdx.x+o]; __syncthreads(); }
    if(threadIdx.x==0){ if(redu[0]>=needed) lohi[1]=mid; else lohi[0]=mid; }
  }
  __syncthreads();
  unsigned X=lohi[1];
  for(unsigned i=threadIdx.x;i<nt;i+=256){
    unsigned r=ties[(size_t)b*65536+i];
    if(r < X) pam[(size_t)b*PER_BATCH + r]=0.0f;
  }
}

// ---------------- launcher ------------------------------------------------
extern "C" void kernel_launch(void* const* d_in, const int* in_sizes, int n_in,
                              void* d_out, int out_size, void* d_ws, size_t ws_size,
                              hipStream_t stream) {
  const float* v     = (const float*)d_in[2];
  const float* qfa   = (const float*)d_in[3];
  const float* kfa   = (const float*)d_in[4];
  const float* mask  = (const float*)d_in[8];
  const float* truth = (const float*)d_in[9];
  const float* pm    = (const float*)d_in[11];
  const float* encw  = (const float*)d_in[12];
  const float* encb  = (const float*)d_in[13];
  const float* lng   = (const float*)d_in[14];
  const float* lnb   = (const float*)d_in[15];
  const float* decw  = (const float*)d_in[16];
  const float* decb  = (const float*)d_in[17];
  float* out = (float*)d_out;
  float* ws  = (float*)d_ws;

  float* ctx     = ws;                              // 48*266*64 = 817152
  float* ksum    = ctx + (size_t)N_H*F_F*64;        // 12768
  float* klrow   = ksum + N_H*F_F;                  // 49152
  float* mserow  = klrow + N_H*T_T;                 // 49152
  unsigned* hist   = (unsigned*)(mserow + N_H*T_T); // 1024
  unsigned* state  = hist + 1024;                   // 16
  unsigned* tiecnt = state + 16;                    // 4 (+pad)
  unsigned* ties   = tiecnt + 12;                   // 4*65536
  float* diags   = (float*)(ties + 4*65536);        // 48*1024 = 49152
  float* ctxraw  = diags + N_H*T_T;                 // 48*64*272 = 835584
  float* ksumP   = ctxraw + (size_t)N_H*64*FP_;     // 4*48*272 = 52224
  float* mfP     = ksumP + 4*N_H*FP_;               // 52224
  float* ksum_tot= mfP + 4*N_H*FP_;                 // 48
  float* ctx_tot = ksum_tot + 48;                   // 3072

  float* pcl   = out + 1;
  float* probs = pcl + (size_t)N_H*T_T*D_H;
  float* pam   = probs + (size_t)N_H*T_T*TM_;

  diag_kern<<<dim3(N_H,4),256,0,stream>>>(kfa, diags);
  keyfeat_kern<<<dim3(N_H,5,4),64,0,stream>>>(kfa, pm, mask, diags, ctxraw, ksumP, mfP);
  fixup_kern<<<N_H,256,0,stream>>>(mfP, ksumP, ctxraw, mask, ctx, ksum, ksum_tot, ctx_tot);
  qfeat_kern<<<dim3(N_H,16),256,0,stream>>>(qfa, pm, ctx, ksum, ksum_tot, ctx_tot, pcl);
  mlp_kern<<<dim3(N_H,32),256,0,stream>>>(pcl, v, mask, encw, encb, lng, lnb,
                                          decw, decb, probs, pam /*score*/);
  loss_kern<<<N_H*T_T,256,0,stream>>>(truth, mask, pam /*score*/, klrow, mserow);
  finloss_kern<<<1,256,0,stream>>>(klrow, mserow, mask, out);
  topk_init<<<4,256,0,stream>>>(hist, state, tiecnt);
  for(int lvl=0;lvl<4;lvl++){
    topk_hist<<<2048,256,0,stream>>>(probs, mask, state, hist, lvl);
    topk_scan<<<4,64,0,stream>>>(hist, state, lvl);
  }
  topk_write<<<2048,256,0,stream>>>(probs, mask, state, pam, ties, tiecnt);
  topk_ties<<<4,256,0,stream>>>(state, ties, tiecnt, pam);
}

// Round 8
// 637.114 us; speedup vs baseline: 2.7699x; 1.1037x over previous
//
#include <hip/hip_runtime.h>
#include <hip/hip_bf16.h>
#include <math.h>

#define N_B 4
#define H_H 12
#define T_T 1024
#define D_H 64
#define F_F 266
#define N_H 48          // N_B*H_H
#define TM_ 128
#define KSEL 98304u     // kk*T*H = 8*1024*12
#define PER_BATCH 1572864  // H*T*TM
#define FCH 14
#define NCH 19          // 19*14 = 266

static __device__ __forceinline__ float waveSum(float v){
  for(int o=32;o;o>>=1) v += __shfl_xor(v,o,64);
  return v;
}
static __device__ __forceinline__ float waveMax(float v){
  for(int o=32;o;o>>=1) v = fmaxf(v,__shfl_xor(v,o,64));
  return v;
}

#define DN_C 0.35355339059327373f   // 64^-0.25 = 2^-1.5
#define DIAG_C 0.0625f              // 0.5 * 64^-0.5
#define RATIO_C 0.06131393394849658f // 266^-0.5
#define EPS_C 1e-4f

// ---------------- Kernel A0: per-(head,t) diag ----------------------------
__global__ __launch_bounds__(256) void diag_kern(
    const float* __restrict__ kfa, float* __restrict__ diags){
  int head = blockIdx.x; int t = blockIdx.y*256 + threadIdx.x;
  const float4* xp = (const float4*)(kfa + ((size_t)head*T_T + t)*D_H);
  float diag = 0.f;
  #pragma unroll
  for(int kk=0;kk<16;kk++){ float4 x = xp[kk];
    diag += x.x*x.x + x.y*x.y + x.z*x.z + x.w*x.w; }
  diags[head*T_T + t] = diag * DIAG_C;
}

// ---------------- Kernel B v4: key features, lane-owns-t-strided ----------
// grid (48,19), 256 threads (4 waves, wave=tq). lane owns t = lane*16+tc:
// t>>4 == lane (ctx row is per-lane), t%16 == tc (vfa validity wave-uniform).
// kacc/cacc are per-lane REGISTERS -> zero cross-lane ops in hot loop.
// p fetched per-f at wave-uniform global addresses (scalar path); x held in
// 16 float4 regs per tc, reused across 14 f's (qfeat-proven pattern).
__global__ __launch_bounds__(256) void keyfeat_kern(
    const float* __restrict__ kfa, const float* __restrict__ pm,
    const float* __restrict__ mask, const float* __restrict__ diags,
    float* __restrict__ ctxraw, float* __restrict__ ksumP,
    float* __restrict__ mfP){
  int head = blockIdx.x, fc = blockIdx.y;
  int f0 = fc*FCH;
  int n = head / H_H;
  int lane = threadIdx.x & 63, tq = threadIdx.x >> 6;
  __shared__ float cred[FCH][64];
  __shared__ float kred[4][FCH];
  __shared__ float mred[4];
  float kacc[FCH], cacc[FCH];
  #pragma unroll
  for(int i=0;i<FCH;i++){ kacc[i]=0.f; cacc[i]=0.f; }
  float mymax = -3.4e38f;
  for(int tt=0; tt<4; tt++){
    int tc = tq*4 + tt;
    int t = lane*16 + tc;
    const float4* xp = (const float4*)(kfa + ((size_t)head*T_T + t)*D_H);
    float4 xr[16];
    #pragma unroll
    for(int kk=0;kk<16;kk++) xr[kk] = xp[kk];
    float dg = diags[head*T_T + t];
    float cmul = ((tc < 8) && (mask[n*T_T + t] > -1.0f)) ? 1.f : 0.f;
    for(int fi=0; fi<FCH; fi++){
      const float4* pr = (const float4*)(pm + (size_t)(f0+fi)*D_H);
      float s0=0,s1=0,s2=0,s3=0;
      #pragma unroll
      for(int kk=0;kk<16;kk++){ float4 w4 = pr[kk];
        s0+=xr[kk].x*w4.x; s1+=xr[kk].y*w4.y; s2+=xr[kk].z*w4.z; s3+=xr[kk].w*w4.w; }
      float dd = DN_C*((s0+s1)+(s2+s3));
      mymax = fmaxf(mymax, dd);
      float e = expf(dd - dg);
      kacc[fi] += e;
      cacc[fi] += e*cmul;
    }
  }
  // one-time block reductions
  #pragma unroll
  for(int fi=0;fi<FCH;fi++){
    float s = waveSum(kacc[fi]);
    if(lane==0) kred[tq][fi] = s;
  }
  mymax = waveMax(mymax);
  if(lane==0) mred[tq]=mymax;
  if(tq==0){
    #pragma unroll
    for(int fi=0;fi<FCH;fi++) cred[fi][lane] = cacc[fi];
  }
  __syncthreads();
  if(tq==1){
    #pragma unroll
    for(int fi=0;fi<FCH;fi++) cred[fi][lane] += cacc[fi];
  }
  __syncthreads();
  for(int i=threadIdx.x; i<FCH*64; i+=256){
    int fi=i>>6, d=i&63;
    ctxraw[((size_t)head*F_F + f0+fi)*64 + d] = cred[fi][d];
  }
  if(threadIdx.x < FCH)
    ksumP[head*F_F + f0 + threadIdx.x] =
      kred[0][threadIdx.x]+kred[1][threadIdx.x]+kred[2][threadIdx.x]+kred[3][threadIdx.x];
  if(threadIdx.x==0)
    mfP[head*NCH+fc] = fmaxf(fmaxf(mred[0],mred[1]),fmaxf(mred[2],mred[3]));
}

// ---------------- Kernel B2: per-head fixup -------------------------------
__global__ __launch_bounds__(256) void fixup_kern(
    const float* __restrict__ mfP, const float* __restrict__ ksumP,
    const float* __restrict__ ctxraw, const float* __restrict__ mask,
    float* __restrict__ ctx, float* __restrict__ ksum,
    float* __restrict__ ksum_tot, float* __restrict__ ctx_tot){
  int head = blockIdx.x; int n = head/H_H;
  __shared__ float segc[64];
  __shared__ float part[4][64];
  __shared__ float kpart[4];
  float m_head = mfP[head*NCH];
  for(int i=1;i<NCH;i++) m_head = fmaxf(m_head, mfP[head*NCH+i]);
  float e_mh = expf(-m_head);
  if(threadIdx.x < 64){
    int d = threadIdx.x; float c=0.f;
    for(int i=0;i<8;i++) c += (mask[n*T_T + 16*d + i] > -1.0f) ? 1.f : 0.f;
    segc[d] = c;
  }
  __syncthreads();
  int g = threadIdx.x>>6, d = threadIdx.x&63;
  float ct = 0.f, kt = 0.f;
  for(int f=g; f<F_F; f+=4){
    float craw = ctxraw[((size_t)head*F_F+f)*64 + d];
    float cf = RATIO_C*(craw*e_mh + EPS_C*segc[d]);
    ctx[((size_t)head*F_F+f)*64 + d] = cf;
    ct += cf;
    if(d==0){
      float kf = RATIO_C*(ksumP[head*F_F+f]*e_mh + EPS_C*(float)T_T);
      ksum[head*F_F+f] = kf;
      kt += kf;
    }
  }
  part[g][d] = ct;
  if(d==0) kpart[g] = kt;
  __syncthreads();
  if(threadIdx.x < 64)
    ctx_tot[head*64+threadIdx.x] =
      part[0][threadIdx.x]+part[1][threadIdx.x]+part[2][threadIdx.x]+part[3][threadIdx.x];
  if(threadIdx.x==0) ksum_tot[head] = kpart[0]+kpart[1]+kpart[2]+kpart[3];
}

// ---------------- Kernel C: query features + pcl (single sweep, online max) -
__global__ __launch_bounds__(256) void qfeat_kern(
    const float* __restrict__ qfa, const float* __restrict__ pm,
    const float* __restrict__ ctx, const float* __restrict__ ksum,
    const float* __restrict__ ksum_tot, const float* __restrict__ ctx_tot,
    float* __restrict__ pcl){
  int head = blockIdx.x, tc = blockIdx.y;   // grid (48,16), 256 threads
  int rl = threadIdx.x >> 2, fs = threadIdx.x & 3;
  int t = tc*64 + rl;
  __shared__ float pms[56*68];
  __shared__ float ctxs[56*68];
  __shared__ float ksums[56];
  const float* xp = qfa + ((size_t)head*T_T + t)*D_H;
  float4 xr[16];
  #pragma unroll
  for(int kk=0;kk<16;kk++) xr[kk] = ((const float4*)xp)[kk];
  float diag = 0.f;
  #pragma unroll
  for(int kk=0;kk<16;kk++)
    diag += xr[kk].x*xr[kk].x + xr[kk].y*xr[kk].y + xr[kk].z*xr[kk].z + xr[kk].w*xr[kk].w;
  diag *= DIAG_C;
  float m_run = -3.4e38f, S = 0.f;
  float4 acc[16];
  #pragma unroll
  for(int kk=0;kk<16;kk++) acc[kk] = make_float4(0.f,0.f,0.f,0.f);
  for(int c=0;c<5;c++){
    int f0 = c*56, CF = min(56, F_F-f0);
    __syncthreads();
    for(int i=threadIdx.x;i<CF*16;i+=256){
      int fl=i>>4, d4=i&15;
      ((float4*)(pms+fl*68))[d4]  = ((const float4*)(pm+(size_t)(f0+fl)*64))[d4];
      ((float4*)(ctxs+fl*68))[d4] = ((const float4*)(ctx+((size_t)head*F_F+f0+fl)*64))[d4];
    }
    for(int i=threadIdx.x;i<CF;i+=256) ksums[i]=ksum[head*F_F+f0+i];
    __syncthreads();
    int nj = (CF - fs + 3)>>2;
    for(int j=0;j<nj;j++){
      int fl = fs+4*j;
      const float4* pr = (const float4*)(pms + fl*68);
      float s0=0,s1=0,s2=0,s3=0;
      #pragma unroll
      for(int kk=0;kk<16;kk++){ float4 w4 = pr[kk];
        s0+=xr[kk].x*w4.x; s1+=xr[kk].y*w4.y; s2+=xr[kk].z*w4.z; s3+=xr[kk].w*w4.w; }
      float dd = DN_C*((s0+s1)+(s2+s3));
      if(dd > m_run){
        float fac = expf(m_run - dd);           // first: exp(-huge)=0 on zero accs
        S *= fac;
        #pragma unroll
        for(int kk=0;kk<16;kk++){
          acc[kk].x*=fac; acc[kk].y*=fac; acc[kk].z*=fac; acc[kk].w*=fac;
        }
        m_run = dd;
      }
      float e = expf(dd - diag - m_run);
      S += e * ksums[fl];
      const float4* cr = (const float4*)(ctxs + fl*68);
      #pragma unroll
      for(int kk=0;kk<16;kk++){ float4 c4=cr[kk];
        acc[kk].x+=e*c4.x; acc[kk].y+=e*c4.y; acc[kk].z+=e*c4.z; acc[kk].w+=e*c4.w; }
    }
  }
  // combine the 4 f-slices with max-rescale (butterfly)
  for(int st=1; st<=2; st<<=1){
    float mo = __shfl_xor(m_run, st, 64);
    float mc = fmaxf(m_run, mo);
    float fac = expf(m_run - mc);
    S *= fac;
    S += __shfl_xor(S, st, 64);
    #pragma unroll
    for(int kk=0;kk<16;kk++){
      acc[kk].x*=fac; acc[kk].y*=fac; acc[kk].z*=fac; acc[kk].w*=fac;
    }
    #pragma unroll
    for(int kk=0;kk<16;kk++){
      acc[kk].x += __shfl_xor(acc[kk].x,st,64);
      acc[kk].y += __shfl_xor(acc[kk].y,st,64);
      acc[kk].z += __shfl_xor(acc[kk].z,st,64);
      acc[kk].w += __shfl_xor(acc[kk].w,st,64);
    }
    m_run = mc;
  }
  float den = S + EPS_C * ksum_tot[head];
  float dinv = 1.0f/den;
  float4 w0,w1,w2,w3;
  if(fs==0){ w0=acc[0]; w1=acc[1]; w2=acc[2]; w3=acc[3]; }
  else if(fs==1){ w0=acc[4]; w1=acc[5]; w2=acc[6]; w3=acc[7]; }
  else if(fs==2){ w0=acc[8]; w1=acc[9]; w2=acc[10]; w3=acc[11]; }
  else { w0=acc[12]; w1=acc[13]; w2=acc[14]; w3=acc[15]; }
  const float4* ctp = ((const float4*)(ctx_tot + head*64)) + fs*4;
  float4 c0=ctp[0], c1=ctp[1], c2=ctp[2], c3=ctp[3];
  float4* po = (float4*)(pcl + ((size_t)head*T_T + t)*D_H) + fs*4;
  po[0] = make_float4((w0.x+EPS_C*c0.x)*dinv,(w0.y+EPS_C*c0.y)*dinv,(w0.z+EPS_C*c0.z)*dinv,(w0.w+EPS_C*c0.w)*dinv);
  po[1] = make_float4((w1.x+EPS_C*c1.x)*dinv,(w1.y+EPS_C*c1.y)*dinv,(w1.z+EPS_C*c1.z)*dinv,(w1.w+EPS_C*c1.w)*dinv);
  po[2] = make_float4((w2.x+EPS_C*c2.x)*dinv,(w2.y+EPS_C*c2.y)*dinv,(w2.z+EPS_C*c2.z)*dinv,(w2.w+EPS_C*c2.w)*dinv);
  po[3] = make_float4((w3.x+EPS_C*c3.x)*dinv,(w3.y+EPS_C*c3.y)*dinv,(w3.z+EPS_C*c3.z)*dinv,(w3.w+EPS_C*c3.w)*dinv);
}

// ---------------- Kernel D: MLP + LN + GELU + score + softmax -------------
#define FMA4(A,s,W) {A.x+=(s)*W.x; A.y+=(s)*W.y; A.z+=(s)*W.z; A.w+=(s)*W.w;}
__global__ __launch_bounds__(256) void mlp_kern(
    const float* __restrict__ pcl, const float* __restrict__ v,
    const float* __restrict__ mask,
    const float* __restrict__ encw, const float* __restrict__ encb,
    const float* __restrict__ lng, const float* __restrict__ lnb,
    const float* __restrict__ decw, const float* __restrict__ decb,
    float* __restrict__ probsout, float* __restrict__ scoreout){
  int head = blockIdx.x, tblk = blockIdx.y;   // grid (48,32)
  int t0 = tblk*32;
  int n = head / H_H;
  __shared__ float xs[32*132];
  __shared__ float wts[32*132];
  __shared__ float h1s[32*132];
  int colT = threadIdx.x & 15, rowT = threadIdx.x >> 4;
  int r0 = rowT, r1 = rowT + 16;
  const float* pclrow = pcl + ((size_t)head*T_T + t0)*D_H;
  const float* vrow   = v   + ((size_t)head*T_T + t0)*D_H;
  for(int i=threadIdx.x;i<512;i+=256){
    int r=i>>4, q=i&15;
    ((float4*)(xs + r*132))[q]      = ((const float4*)(pclrow + r*64))[q];
    ((float4*)(xs + r*132 + 64))[q] = ((const float4*)(vrow   + r*64))[q];
  }
  float4 bias0 = ((const float4*)encb)[colT];
  float4 bias1 = ((const float4*)encb)[colT+16];
  float4 A0=bias0, A1=bias1, B0=bias0, B1=bias1;
  for(int kc=0;kc<4;kc++){
    __syncthreads();
    for(int i=threadIdx.x;i<1024;i+=256){
      int k=i>>5, q=i&31;
      ((float4*)(wts + k*132))[q] = ((const float4*)(encw + (size_t)(kc*32+k)*128))[q];
    }
    __syncthreads();
    #pragma unroll
    for(int kq=0;kq<8;kq++){
      float4 x0 = ((const float4*)(xs + r0*132 + kc*32))[kq];
      float4 x1 = ((const float4*)(xs + r1*132 + kc*32))[kq];
      #pragma unroll
      for(int kk=0;kk<4;kk++){
        const float* wrow = wts + (kq*4+kk)*132;
        float4 wa = ((const float4*)wrow)[colT];
        float4 wb = ((const float4*)wrow)[colT+16];
        float xv0 = (kk==0)?x0.x:(kk==1)?x0.y:(kk==2)?x0.z:x0.w;
        float xv1 = (kk==0)?x1.x:(kk==1)?x1.y:(kk==2)?x1.z:x1.w;
        FMA4(A0,xv0,wa); FMA4(A1,xv0,wb);
        FMA4(B0,xv1,wa); FMA4(B1,xv1,wb);
      }
    }
  }
  float4 lg0 = ((const float4*)lng)[colT], lg1 = ((const float4*)lng)[colT+16];
  float4 lb0 = ((const float4*)lnb)[colT], lb1 = ((const float4*)lnb)[colT+16];
  float s0 = A0.x+A0.y+A0.z+A0.w + A1.x+A1.y+A1.z+A1.w;
  float s1 = B0.x+B0.y+B0.z+B0.w + B1.x+B1.y+B1.z+B1.w;
  for(int o=1;o<16;o<<=1){ s0 += __shfl_xor(s0,o,64); s1 += __shfl_xor(s1,o,64); }
  float mu0 = s0*(1.0f/128.0f), mu1 = s1*(1.0f/128.0f);
  float v0=0.f, v1=0.f;
  { float d;
    d=A0.x-mu0; v0+=d*d; d=A0.y-mu0; v0+=d*d; d=A0.z-mu0; v0+=d*d; d=A0.w-mu0; v0+=d*d;
    d=A1.x-mu0; v0+=d*d; d=A1.y-mu0; v0+=d*d; d=A1.z-mu0; v0+=d*d; d=A1.w-mu0; v0+=d*d;
    d=B0.x-mu1; v1+=d*d; d=B0.y-mu1; v1+=d*d; d=B0.z-mu1; v1+=d*d; d=B0.w-mu1; v1+=d*d;
    d=B1.x-mu1; v1+=d*d; d=B1.y-mu1; v1+=d*d; d=B1.z-mu1; v1+=d*d; d=B1.w-mu1; v1+=d*d; }
  for(int o=1;o<16;o<<=1){ v0 += __shfl_xor(v0,o,64); v1 += __shfl_xor(v1,o,64); }
  float den0 = sqrtf(v0*(1.0f/128.0f)+1e-5f);
  float den1 = sqrtf(v1*(1.0f/128.0f)+1e-5f);
  #define GELU(x) ((x)*0.5f*(1.0f+erff((x)*0.70710678118654752f)))
  #define LNG(a,mu,dn,g,b) GELU(((a)-(mu))/(dn)*(g)+(b))
  float4 H;
  H.x=LNG(A0.x,mu0,den0,lg0.x,lb0.x); H.y=LNG(A0.y,mu0,den0,lg0.y,lb0.y);
  H.z=LNG(A0.z,mu0,den0,lg0.z,lb0.z); H.w=LNG(A0.w,mu0,den0,lg0.w,lb0.w);
  ((float4*)(h1s + r0*132))[colT] = H;
  H.x=LNG(A1.x,mu0,den0,lg1.x,lb1.x); H.y=LNG(A1.y,mu0,den0,lg1.y,lb1.y);
  H.z=LNG(A1.z,mu0,den0,lg1.z,lb1.z); H.w=LNG(A1.w,mu0,den0,lg1.w,lb1.w);
  ((float4*)(h1s + r0*132))[colT+16] = H;
  H.x=LNG(B0.x,mu1,den1,lg0.x,lb0.x); H.y=LNG(B0.y,mu1,den1,lg0.y,lb0.y);
  H.z=LNG(B0.z,mu1,den1,lg0.z,lb0.z); H.w=LNG(B0.w,mu1,den1,lg0.w,lb0.w);
  ((float4*)(h1s + r1*132))[colT] = H;
  H.x=LNG(B1.x,mu1,den1,lg1.x,lb1.x); H.y=LNG(B1.y,mu1,den1,lg1.y,lb1.y);
  H.z=LNG(B1.z,mu1,den1,lg1.z,lb1.z); H.w=LNG(B1.w,mu1,den1,lg1.w,lb1.w);
  ((float4*)(h1s + r1*132))[colT+16] = H;
  bias0 = ((const float4*)decb)[colT];
  bias1 = ((const float4*)decb)[colT+16];
  A0=bias0; A1=bias1; B0=bias0; B1=bias1;
  for(int kc=0;kc<4;kc++){
    __syncthreads();
    for(int i=threadIdx.x;i<1024;i+=256){
      int k=i>>5, q=i&31;
      ((float4*)(wts + k*132))[q] = ((const float4*)(decw + (size_t)(kc*32+k)*128))[q];
    }
    __syncthreads();
    #pragma unroll
    for(int kq=0;kq<8;kq++){
      float4 x0 = ((const float4*)(h1s + r0*132 + kc*32))[kq];
      float4 x1 = ((const float4*)(h1s + r1*132 + kc*32))[kq];
      #pragma unroll
      for(int kk=0;kk<4;kk++){
        const float* wrow = wts + (kq*4+kk)*132;
        float4 wa = ((const float4*)wrow)[colT];
        float4 wb = ((const float4*)wrow)[colT+16];
        float xv0 = (kk==0)?x0.x:(kk==1)?x0.y:(kk==2)?x0.z:x0.w;
        float xv1 = (kk==0)?x1.x:(kk==1)?x1.y:(kk==2)?x1.z:x1.w;
        FMA4(A0,xv0,wa); FMA4(A1,xv0,wb);
        FMA4(B0,xv1,wa); FMA4(B1,xv1,wb);
      }
    }
  }
  const float* mrow = mask + n*T_T;
  int c0 = colT*4, c1 = colT*4 + 64;
  float rm0[4], rm1[4];
  #pragma unroll
  for(int i=0;i<4;i++){ rm0[i]=mrow[(c0+i)*8]; rm1[i]=mrow[(c1+i)*8]; }
  float sA[8], sB[8];
  sA[0]=(rm0[0]<-1.f)?-10000.f:A0.x; sA[1]=(rm0[1]<-1.f)?-10000.f:A0.y;
  sA[2]=(rm0[2]<-1.f)?-10000.f:A0.z; sA[3]=(rm0[3]<-1.f)?-10000.f:A0.w;
  sA[4]=(rm1[0]<-1.f)?-10000.f:A1.x; sA[5]=(rm1[1]<-1.f)?-10000.f:A1.y;
  sA[6]=(rm1[2]<-1.f)?-10000.f:A1.z; sA[7]=(rm1[3]<-1.f)?-10000.f:A1.w;
  sB[0]=(rm0[0]<-1.f)?-10000.f:B0.x; sB[1]=(rm0[1]<-1.f)?-10000.f:B0.y;
  sB[2]=(rm0[2]<-1.f)?-10000.f:B0.z; sB[3]=(rm0[3]<-1.f)?-10000.f:B0.w;
  sB[4]=(rm1[0]<-1.f)?-10000.f:B1.x; sB[5]=(rm1[1]<-1.f)?-10000.f:B1.y;
  sB[6]=(rm1[2]<-1.f)?-10000.f:B1.z; sB[7]=(rm1[3]<-1.f)?-10000.f:B1.w;
  float mx0=sA[0], mx1=sB[0];
  #pragma unroll
  for(int i=1;i<8;i++){ mx0=fmaxf(mx0,sA[i]); mx1=fmaxf(mx1,sB[i]); }
  for(int o=1;o<16;o<<=1){ mx0=fmaxf(mx0,__shfl_xor(mx0,o,64)); mx1=fmaxf(mx1,__shfl_xor(mx1,o,64)); }
  float Z0=0.f, Z1=0.f;
  #pragma unroll
  for(int i=0;i<8;i++){ sA[i]=expf(sA[i]-mx0); Z0+=sA[i]; sB[i]=expf(sB[i]-mx1); Z1+=sB[i]; }
  for(int o=1;o<16;o<<=1){ Z0+=__shfl_xor(Z0,o,64); Z1+=__shfl_xor(Z1,o,64); }
  float zi0=1.0f/Z0, zi1=1.0f/Z1;
  size_t rb0 = ((size_t)head*T_T + t0 + r0)*TM_;
  size_t rb1 = ((size_t)head*T_T + t0 + r1)*TM_;
  ((float4*)(probsout+rb0))[colT]    = make_float4(sA[0]*zi0,sA[1]*zi0,sA[2]*zi0,sA[3]*zi0);
  ((float4*)(probsout+rb0))[colT+16] = make_float4(sA[4]*zi0,sA[5]*zi0,sA[6]*zi0,sA[7]*zi0);
  ((float4*)(probsout+rb1))[colT]    = make_float4(sB[0]*zi1,sB[1]*zi1,sB[2]*zi1,sB[3]*zi1);
  ((float4*)(probsout+rb1))[colT+16] = make_float4(sB[4]*zi1,sB[5]*zi1,sB[6]*zi1,sB[7]*zi1);
  ((float4*)(scoreout+rb0))[colT]    = A0;
  ((float4*)(scoreout+rb0))[colT+16] = A1;
  ((float4*)(scoreout+rb1))[colT]    = B0;
  ((float4*)(scoreout+rb1))[colT+16] = B1;
}

// ---------------- Kernel E: per-row KL + MSE (no libm, es cache) ----------
__global__ __launch_bounds__(256) void loss_kern(
    const float* __restrict__ truth, const float* __restrict__ mask,
    const float* __restrict__ score, float* __restrict__ klrow,
    float* __restrict__ mserow){
  int row = blockIdx.x;               // head*1024 + t
  int n = row / (H_H*T_T);
  __shared__ float a[1024];
  __shared__ float mk[1024];
  __shared__ float es[1024];
  __shared__ float sc[128];
  __shared__ float red4[4];
  const float* ar = truth + (size_t)row*T_T;
  const float* mr = mask + n*T_T;
  const float* sr = score + (size_t)row*TM_;
  if(threadIdx.x < 256){
    ((float4*)a)[threadIdx.x]  = ((const float4*)ar)[threadIdx.x];
    ((float4*)mk)[threadIdx.x] = ((const float4*)mr)[threadIdx.x];
  }
  for(int i=threadIdx.x;i<128;i+=256) sc[i]=sr[i];
  __syncthreads();
  float ma=-3.4e38f, ms=-3.4e38f;
  for(int j=threadIdx.x;j<1024;j+=256){
    ma=fmaxf(ma,a[j]+mk[j]);
    ms=fmaxf(ms,sc[j>>3]+mk[j]);
  }
  ma = waveMax(ma);
  if((threadIdx.x&63)==0) red4[threadIdx.x>>6]=ma;
  __syncthreads();
  ma = fmaxf(fmaxf(red4[0],red4[1]),fmaxf(red4[2],red4[3]));
  __syncthreads();
  ms = waveMax(ms);
  if((threadIdx.x&63)==0) red4[threadIdx.x>>6]=ms;
  __syncthreads();
  ms = fmaxf(fmaxf(red4[0],red4[1]),fmaxf(red4[2],red4[3]));
  __syncthreads();
  float Za=0, Zs=0;
  for(int j=threadIdx.x;j<1024;j+=256){
    float ea = __expf(a[j]+mk[j]-ma);
    es[j] = ea;
    Za += ea;
    Zs += __expf(sc[j>>3]+mk[j]-ms);
  }
  Za = waveSum(Za);
  if((threadIdx.x&63)==0) red4[threadIdx.x>>6]=Za;
  __syncthreads();
  Za = (red4[0]+red4[1])+(red4[2]+red4[3]);
  __syncthreads();
  Zs = waveSum(Zs);
  if((threadIdx.x&63)==0) red4[threadIdx.x>>6]=Zs;
  __syncthreads();
  Zs = (red4[0]+red4[1])+(red4[2]+red4[3]);
  __syncthreads();
  float lZs = __logf(Zs), lZa = __logf(Za);
  float invZa = 1.0f/Za;
  float kl=0, mse=0;
  for(int j=threadIdx.x;j<1024;j+=256){
    float mkj = mk[j];
    float scj = sc[j>>3];
    float aj = a[j];
    if(mkj > -1.0f){
      float pt = es[j]*invZa;
      float logpt = (pt >= 1e-12f) ? (aj+mkj-ma-lZa) : -27.631021116f;
      float logp = (scj+mkj-ms) - lZs;
      kl += pt*(logpt-logp);
    }
    float sv = (mkj < -1.0f)?0.f:scj;
    float av = (mkj < -1.0f)?0.f:aj;
    float d = sv-av; mse += d*d;
  }
  kl = waveSum(kl);
  if((threadIdx.x&63)==0) red4[threadIdx.x>>6]=kl;
  __syncthreads();
  kl = (red4[0]+red4[1])+(red4[2]+red4[3]);
  __syncthreads();
  mse = waveSum(mse);
  if((threadIdx.x&63)==0) red4[threadIdx.x>>6]=mse;
  __syncthreads();
  if(threadIdx.x==0){
    mse = (red4[0]+red4[1])+(red4[2]+red4[3]);
    klrow[row]=kl; mserow[row]=mse;
  }
}

// ---------------- Kernel F: final loss ------------------------------------
__global__ __launch_bounds__(256) void finloss_kern(
    const float* __restrict__ klrow, const float* __restrict__ mserow,
    const float* __restrict__ mask, float* __restrict__ out0){
  __shared__ double reds[256];
  double kls=0, mses=0;
  for(int i=threadIdx.x;i<N_H*T_T;i+=256){ kls+=(double)klrow[i]; mses+=(double)mserow[i]; }
  double vcnt=0;
  for(int i=threadIdx.x;i<N_B*T_T;i+=256) if(mask[i] > -1.0f) vcnt+=1.0;
  reds[threadIdx.x]=kls; __syncthreads();
  for(int o=128;o;o>>=1){ if(threadIdx.x<o) reds[threadIdx.x]+=reds[threadIdx.x+o]; __syncthreads(); }
  double klsum = reds[0]; __syncthreads();
  reds[threadIdx.x]=mses; __syncthreads();
  for(int o=128;o;o>>=1){ if(threadIdx.x<o) reds[threadIdx.x]+=reds[threadIdx.x+o]; __syncthreads(); }
  double msesum = reds[0]; __syncthreads();
  reds[threadIdx.x]=vcnt; __syncthreads();
  for(int o=128;o;o>>=1){ if(threadIdx.x<o) reds[threadIdx.x]+=reds[threadIdx.x+o]; __syncthreads(); }
  if(threadIdx.x==0){
    double denom = reds[0] * (double)(H_H*T_T);
    double loss = klsum/denom*0.25 + msesum/((double)N_B*H_H*T_T*T_T);
    out0[0]=(float)loss;
  }
}

// ---------------- Top-k pipeline ------------------------------------------
__global__ void topk_init(unsigned* __restrict__ hist, unsigned* __restrict__ state,
                          unsigned* __restrict__ tiecnt){
  int i = blockIdx.x*256+threadIdx.x;
  if(i < 4*256) hist[i]=0;
  if(i < 4){ state[i*4+0]=0u; state[i*4+1]=KSEL; state[i*4+2]=0u; tiecnt[i]=0u; }
}

__global__ __launch_bounds__(256) void topk_hist(
    const float* __restrict__ probs, const float* __restrict__ mask,
    const unsigned* __restrict__ state, unsigned* __restrict__ hist, int level){
  __shared__ unsigned lh[4*256];
  for(int i=threadIdx.x;i<1024;i+=256) lh[i]=0;
  __syncthreads();
  unsigned pmask = (level==0)?0u:(0xFFFFFFFFu << (32-8*level));
  unsigned pref[4];
  for(int b=0;b<4;b++) pref[b]=state[b*4+0] & pmask;
  int shift = 24-8*level;
  size_t total = (size_t)N_B*PER_BATCH;
  for(size_t idx = (size_t)blockIdx.x*256+threadIdx.x; idx < total; idx += (size_t)gridDim.x*256){
    int b = (int)(idx / PER_BATCH);
    unsigned r = (unsigned)(idx - (size_t)b*PER_BATCH);
    int t = (int)((r>>7)&1023u);
    float val = probs[idx];
    if(!(mask[b*T_T+t] > -1.0f)) val = 0.0f;
    unsigned u = __float_as_uint(val);
    if((u & pmask) == pref[b]) atomicAdd(&lh[b*256+((u>>shift)&255u)],1u);
  }
  __syncthreads();
  for(int i=threadIdx.x;i<1024;i+=256){
    unsigned c = lh[i];
    if(c) atomicAdd(&hist[i], c);
  }
}

__global__ void topk_scan(unsigned* __restrict__ hist, unsigned* __restrict__ state, int level){
  int b = blockIdx.x;
  if(threadIdx.x==0){
    const unsigned* h = hist + b*256;
    unsigned remk = state[b*4+1];
    unsigned cum = 0; int sel=0;
    for(int bin=255; bin>=0; bin--){
      unsigned c = h[bin];
      if(remk <= cum + c){ sel=bin; break; }
      cum += c;
    }
    state[b*4+0] |= ((unsigned)sel) << (24-8*level);
    state[b*4+1] = remk - cum;
    state[b*4+2] += cum;
  }
  __syncthreads();
  for(int i=threadIdx.x;i<256;i+=blockDim.x) hist[b*256+i]=0;
}

__global__ __launch_bounds__(256) void topk_write(
    const float* __restrict__ probs, const float* __restrict__ mask,
    const unsigned* __restrict__ state, float* __restrict__ pam,
    unsigned* __restrict__ ties, unsigned* __restrict__ tiecnt){
  unsigned thr[4];
  for(int b=0;b<4;b++) thr[b]=state[b*4+0];
  size_t total=(size_t)N_B*PER_BATCH;
  for(size_t idx=(size_t)blockIdx.x*256+threadIdx.x; idx<total; idx += (size_t)gridDim.x*256){
    int b = (int)(idx / PER_BATCH);
    unsigned r = (unsigned)(idx - (size_t)b*PER_BATCH);
    int t = (int)((r>>7)&1023u);
    float val = probs[idx];
    if(!(mask[b*T_T+t] > -1.0f)) val=0.0f;
    unsigned u=__float_as_uint(val);
    float o = -10000.0f;
    if(u > thr[b]) o = 0.0f;
    else if(u == thr[b]){
      unsigned pos = atomicAdd(&tiecnt[b],1u);
      if(pos < 65536u) ties[(size_t)b*65536+pos]=r;
    }
    pam[idx]=o;
  }
}

__global__ __launch_bounds__(256) void topk_ties(
    const unsigned* __restrict__ state, const unsigned* __restrict__ ties,
    const unsigned* __restrict__ tiecnt, float* __restrict__ pam){
  int b = blockIdx.x;
  unsigned needed = state[b*4+1];
  unsigned nt = min(tiecnt[b], 65536u);
  __shared__ unsigned redu[256];
  __shared__ unsigned lohi[2];
  if(threadIdx.x==0){ lohi[0]=0u; lohi[1]=PER_BATCH; }
  __syncthreads();
  if(needed == 0 || nt == 0) return;
  while(true){
    __syncthreads();
    unsigned lo=lohi[0], hi=lohi[1];
    if(hi-lo<=1u) break;
    unsigned mid=(lo+hi)>>1;
    unsigned c=0;
    for(unsigned i=threadIdx.x;i<nt;i+=256) c += (ties[(size_t)b*65536+i] < mid)?1u:0u;
    redu[threadIdx.x]=c; __syncthreads();
    for(int o=128;o;o>>=1){ if(threadIdx.x<o) redu[threadIdx.x]+=redu[threadIdx.x+o]; __syncthreads(); }
    if(threadIdx.x==0){ if(redu[0]>=needed) lohi[1]=mid; else lohi[0]=mid; }
  }
  __syncthreads();
  unsigned X=lohi[1];
  for(unsigned i=threadIdx.x;i<nt;i+=256){
    unsigned r=ties[(size_t)b*65536+i];
    if(r < X) pam[(size_t)b*PER_BATCH + r]=0.0f;
  }
}

// ---------------- launcher ------------------------------------------------
extern "C" void kernel_launch(void* const* d_in, const int* in_sizes, int n_in,
                              void* d_out, int out_size, void* d_ws, size_t ws_size,
                              hipStream_t stream) {
  const float* v     = (const float*)d_in[2];
  const float* qfa   = (const float*)d_in[3];
  const float* kfa   = (const float*)d_in[4];
  const float* mask  = (const float*)d_in[8];
  const float* truth = (const float*)d_in[9];
  const float* pm    = (const float*)d_in[11];
  const float* encw  = (const float*)d_in[12];
  const float* encb  = (const float*)d_in[13];
  const float* lng   = (const float*)d_in[14];
  const float* lnb   = (const float*)d_in[15];
  const float* decw  = (const float*)d_in[16];
  const float* decb  = (const float*)d_in[17];
  float* out = (float*)d_out;
  float* ws  = (float*)d_ws;

  float* ctx     = ws;                              // 48*266*64 = 817152
  float* ksum    = ctx + (size_t)N_H*F_F*64;        // 12768
  float* klrow   = ksum + N_H*F_F;                  // 49152
  float* mserow  = klrow + N_H*T_T;                 // 49152
  unsigned* hist   = (unsigned*)(mserow + N_H*T_T); // 1024
  unsigned* state  = hist + 1024;                   // 16
  unsigned* tiecnt = state + 16;                    // 4 (+pad)
  unsigned* ties   = tiecnt + 12;                   // 4*65536
  float* diags   = (float*)(ties + 4*65536);        // 48*1024 = 49152
  float* ctxraw  = diags + N_H*T_T;                 // 48*266*64 = 817152
  float* ksumP   = ctxraw + (size_t)N_H*F_F*64;     // 48*266 = 12768
  float* mfP     = ksumP + N_H*F_F;                 // 48*19 = 912
  float* ksum_tot= mfP + 1024;                      // 48
  float* ctx_tot = ksum_tot + 48;                   // 3072

  float* pcl   = out + 1;
  float* probs = pcl + (size_t)N_H*T_T*D_H;
  float* pam   = probs + (size_t)N_H*T_T*TM_;

  diag_kern<<<dim3(N_H,4),256,0,stream>>>(kfa, diags);
  keyfeat_kern<<<dim3(N_H,NCH),256,0,stream>>>(kfa, pm, mask, diags, ctxraw, ksumP, mfP);
  fixup_kern<<<N_H,256,0,stream>>>(mfP, ksumP, ctxraw, mask, ctx, ksum, ksum_tot, ctx_tot);
  qfeat_kern<<<dim3(N_H,16),256,0,stream>>>(qfa, pm, ctx, ksum, ksum_tot, ctx_tot, pcl);
  mlp_kern<<<dim3(N_H,32),256,0,stream>>>(pcl, v, mask, encw, encb, lng, lnb,
                                          decw, decb, probs, pam /*score*/);
  loss_kern<<<N_H*T_T,256,0,stream>>>(truth, mask, pam /*score*/, klrow, mserow);
  finloss_kern<<<1,256,0,stream>>>(klrow, mserow, mask, out);
  topk_init<<<4,256,0,stream>>>(hist, state, tiecnt);
  for(int lvl=0;lvl<4;lvl++){
    topk_hist<<<2048,256,0,stream>>>(probs, mask, state, hist, lvl);
    topk_scan<<<4,64,0,stream>>>(hist, state, lvl);
  }
  topk_write<<<2048,256,0,stream>>>(probs, mask, state, pam, ties, tiecnt);
  topk_ties<<<4,256,0,stream>>>(state, ties, tiecnt, pam);
}

// Round 9
// 595.388 us; speedup vs baseline: 2.9640x; 1.0701x over previous
//
#include <hip/hip_runtime.h>
#include <hip/hip_bf16.h>
#include <math.h>

#define N_B 4
#define H_H 12
#define T_T 1024
#define D_H 64
#define F_F 266
#define N_H 48          // N_B*H_H
#define TM_ 128
#define KSEL 98304u     // kk*T*H = 8*1024*12
#define PER_BATCH 1572864  // H*T*TM
#define FCH 14
#define NCH 19          // 19*14 = 266

static __device__ __forceinline__ float waveSum(float v){
  for(int o=32;o;o>>=1) v += __shfl_xor(v,o,64);
  return v;
}
static __device__ __forceinline__ float waveMax(float v){
  for(int o=32;o;o>>=1) v = fmaxf(v,__shfl_xor(v,o,64));
  return v;
}

#define DN_C 0.35355339059327373f   // 64^-0.25 = 2^-1.5
#define DIAG_C 0.0625f              // 0.5 * 64^-0.5
#define RATIO_C 0.06131393394849658f // 266^-0.5
#define EPS_C 1e-4f

// ---------------- Kernel A0: per-(head,t) diag ----------------------------
__global__ __launch_bounds__(256) void diag_kern(
    const float* __restrict__ kfa, float* __restrict__ diags){
  int head = blockIdx.x; int t = blockIdx.y*256 + threadIdx.x;
  const float4* xp = (const float4*)(kfa + ((size_t)head*T_T + t)*D_H);
  float diag = 0.f;
  #pragma unroll
  for(int kk=0;kk<16;kk++){ float4 x = xp[kk];
    diag += x.x*x.x + x.y*x.y + x.z*x.z + x.w*x.w; }
  diags[head*T_T + t] = diag * DIAG_C;
}

// ---------------- Kernel B v4: key features, lane-owns-t-strided ----------
__global__ __launch_bounds__(256) void keyfeat_kern(
    const float* __restrict__ kfa, const float* __restrict__ pm,
    const float* __restrict__ mask, const float* __restrict__ diags,
    float* __restrict__ ctxraw, float* __restrict__ ksumP,
    float* __restrict__ mfP){
  int head = blockIdx.x, fc = blockIdx.y;
  int f0 = fc*FCH;
  int n = head / H_H;
  int lane = threadIdx.x & 63, tq = threadIdx.x >> 6;
  __shared__ float cred[FCH][64];
  __shared__ float kred[4][FCH];
  __shared__ float mred[4];
  float kacc[FCH], cacc[FCH];
  #pragma unroll
  for(int i=0;i<FCH;i++){ kacc[i]=0.f; cacc[i]=0.f; }
  float mymax = -3.4e38f;
  for(int tt=0; tt<4; tt++){
    int tc = tq*4 + tt;
    int t = lane*16 + tc;
    const float4* xp = (const float4*)(kfa + ((size_t)head*T_T + t)*D_H);
    float4 xr[16];
    #pragma unroll
    for(int kk=0;kk<16;kk++) xr[kk] = xp[kk];
    float dg = diags[head*T_T + t];
    float cmul = ((tc < 8) && (mask[n*T_T + t] > -1.0f)) ? 1.f : 0.f;
    for(int fi=0; fi<FCH; fi++){
      const float4* pr = (const float4*)(pm + (size_t)(f0+fi)*D_H);
      float s0=0,s1=0,s2=0,s3=0;
      #pragma unroll
      for(int kk=0;kk<16;kk++){ float4 w4 = pr[kk];
        s0+=xr[kk].x*w4.x; s1+=xr[kk].y*w4.y; s2+=xr[kk].z*w4.z; s3+=xr[kk].w*w4.w; }
      float dd = DN_C*((s0+s1)+(s2+s3));
      mymax = fmaxf(mymax, dd);
      float e = expf(dd - dg);
      kacc[fi] += e;
      cacc[fi] += e*cmul;
    }
  }
  #pragma unroll
  for(int fi=0;fi<FCH;fi++){
    float s = waveSum(kacc[fi]);
    if(lane==0) kred[tq][fi] = s;
  }
  mymax = waveMax(mymax);
  if(lane==0) mred[tq]=mymax;
  if(tq==0){
    #pragma unroll
    for(int fi=0;fi<FCH;fi++) cred[fi][lane] = cacc[fi];
  }
  __syncthreads();
  if(tq==1){
    #pragma unroll
    for(int fi=0;fi<FCH;fi++) cred[fi][lane] += cacc[fi];
  }
  __syncthreads();
  for(int i=threadIdx.x; i<FCH*64; i+=256){
    int fi=i>>6, d=i&63;
    ctxraw[((size_t)head*F_F + f0+fi)*64 + d] = cred[fi][d];
  }
  if(threadIdx.x < FCH)
    ksumP[head*F_F + f0 + threadIdx.x] =
      kred[0][threadIdx.x]+kred[1][threadIdx.x]+kred[2][threadIdx.x]+kred[3][threadIdx.x];
  if(threadIdx.x==0)
    mfP[head*NCH+fc] = fmaxf(fmaxf(mred[0],mred[1]),fmaxf(mred[2],mred[3]));
}

// ---------------- Kernel B2: per-head fixup -------------------------------
__global__ __launch_bounds__(256) void fixup_kern(
    const float* __restrict__ mfP, const float* __restrict__ ksumP,
    const float* __restrict__ ctxraw, const float* __restrict__ mask,
    float* __restrict__ ctx, float* __restrict__ ksum,
    float* __restrict__ ksum_tot, float* __restrict__ ctx_tot){
  int head = blockIdx.x; int n = head/H_H;
  __shared__ float segc[64];
  __shared__ float part[4][64];
  __shared__ float kpart[4];
  float m_head = mfP[head*NCH];
  for(int i=1;i<NCH;i++) m_head = fmaxf(m_head, mfP[head*NCH+i]);
  float e_mh = expf(-m_head);
  if(threadIdx.x < 64){
    int d = threadIdx.x; float c=0.f;
    for(int i=0;i<8;i++) c += (mask[n*T_T + 16*d + i] > -1.0f) ? 1.f : 0.f;
    segc[d] = c;
  }
  __syncthreads();
  int g = threadIdx.x>>6, d = threadIdx.x&63;
  float ct = 0.f, kt = 0.f;
  for(int f=g; f<F_F; f+=4){
    float craw = ctxraw[((size_t)head*F_F+f)*64 + d];
    float cf = RATIO_C*(craw*e_mh + EPS_C*segc[d]);
    ctx[((size_t)head*F_F+f)*64 + d] = cf;
    ct += cf;
    if(d==0){
      float kf = RATIO_C*(ksumP[head*F_F+f]*e_mh + EPS_C*(float)T_T);
      ksum[head*F_F+f] = kf;
      kt += kf;
    }
  }
  part[g][d] = ct;
  if(d==0) kpart[g] = kt;
  __syncthreads();
  if(threadIdx.x < 64)
    ctx_tot[head*64+threadIdx.x] =
      part[0][threadIdx.x]+part[1][threadIdx.x]+part[2][threadIdx.x]+part[3][threadIdx.x];
  if(threadIdx.x==0) ksum_tot[head] = kpart[0]+kpart[1]+kpart[2]+kpart[3];
}

// ---------------- Kernel C: query features + pcl (single sweep, online max) -
__global__ __launch_bounds__(256) void qfeat_kern(
    const float* __restrict__ qfa, const float* __restrict__ pm,
    const float* __restrict__ ctx, const float* __restrict__ ksum,
    const float* __restrict__ ksum_tot, const float* __restrict__ ctx_tot,
    float* __restrict__ pcl){
  int head = blockIdx.x, tc = blockIdx.y;   // grid (48,16), 256 threads
  int rl = threadIdx.x >> 2, fs = threadIdx.x & 3;
  int t = tc*64 + rl;
  __shared__ float pms[56*68];
  __shared__ float ctxs[56*68];
  __shared__ float ksums[56];
  const float* xp = qfa + ((size_t)head*T_T + t)*D_H;
  float4 xr[16];
  #pragma unroll
  for(int kk=0;kk<16;kk++) xr[kk] = ((const float4*)xp)[kk];
  float diag = 0.f;
  #pragma unroll
  for(int kk=0;kk<16;kk++)
    diag += xr[kk].x*xr[kk].x + xr[kk].y*xr[kk].y + xr[kk].z*xr[kk].z + xr[kk].w*xr[kk].w;
  diag *= DIAG_C;
  float m_run = -3.4e38f, S = 0.f;
  float4 acc[16];
  #pragma unroll
  for(int kk=0;kk<16;kk++) acc[kk] = make_float4(0.f,0.f,0.f,0.f);
  for(int c=0;c<5;c++){
    int f0 = c*56, CF = min(56, F_F-f0);
    __syncthreads();
    for(int i=threadIdx.x;i<CF*16;i+=256){
      int fl=i>>4, d4=i&15;
      ((float4*)(pms+fl*68))[d4]  = ((const float4*)(pm+(size_t)(f0+fl)*64))[d4];
      ((float4*)(ctxs+fl*68))[d4] = ((const float4*)(ctx+((size_t)head*F_F+f0+fl)*64))[d4];
    }
    for(int i=threadIdx.x;i<CF;i+=256) ksums[i]=ksum[head*F_F+f0+i];
    __syncthreads();
    int nj = (CF - fs + 3)>>2;
    for(int j=0;j<nj;j++){
      int fl = fs+4*j;
      const float4* pr = (const float4*)(pms + fl*68);
      float s0=0,s1=0,s2=0,s3=0;
      #pragma unroll
      for(int kk=0;kk<16;kk++){ float4 w4 = pr[kk];
        s0+=xr[kk].x*w4.x; s1+=xr[kk].y*w4.y; s2+=xr[kk].z*w4.z; s3+=xr[kk].w*w4.w; }
      float dd = DN_C*((s0+s1)+(s2+s3));
      if(dd > m_run){
        float fac = expf(m_run - dd);
        S *= fac;
        #pragma unroll
        for(int kk=0;kk<16;kk++){
          acc[kk].x*=fac; acc[kk].y*=fac; acc[kk].z*=fac; acc[kk].w*=fac;
        }
        m_run = dd;
      }
      float e = expf(dd - diag - m_run);
      S += e * ksums[fl];
      const float4* cr = (const float4*)(ctxs + fl*68);
      #pragma unroll
      for(int kk=0;kk<16;kk++){ float4 c4=cr[kk];
        acc[kk].x+=e*c4.x; acc[kk].y+=e*c4.y; acc[kk].z+=e*c4.z; acc[kk].w+=e*c4.w; }
    }
  }
  for(int st=1; st<=2; st<<=1){
    float mo = __shfl_xor(m_run, st, 64);
    float mc = fmaxf(m_run, mo);
    float fac = expf(m_run - mc);
    S *= fac;
    S += __shfl_xor(S, st, 64);
    #pragma unroll
    for(int kk=0;kk<16;kk++){
      acc[kk].x*=fac; acc[kk].y*=fac; acc[kk].z*=fac; acc[kk].w*=fac;
    }
    #pragma unroll
    for(int kk=0;kk<16;kk++){
      acc[kk].x += __shfl_xor(acc[kk].x,st,64);
      acc[kk].y += __shfl_xor(acc[kk].y,st,64);
      acc[kk].z += __shfl_xor(acc[kk].z,st,64);
      acc[kk].w += __shfl_xor(acc[kk].w,st,64);
    }
    m_run = mc;
  }
  float den = S + EPS_C * ksum_tot[head];
  float dinv = 1.0f/den;
  float4 w0,w1,w2,w3;
  if(fs==0){ w0=acc[0]; w1=acc[1]; w2=acc[2]; w3=acc[3]; }
  else if(fs==1){ w0=acc[4]; w1=acc[5]; w2=acc[6]; w3=acc[7]; }
  else if(fs==2){ w0=acc[8]; w1=acc[9]; w2=acc[10]; w3=acc[11]; }
  else { w0=acc[12]; w1=acc[13]; w2=acc[14]; w3=acc[15]; }
  const float4* ctp = ((const float4*)(ctx_tot + head*64)) + fs*4;
  float4 c0=ctp[0], c1=ctp[1], c2=ctp[2], c3=ctp[3];
  float4* po = (float4*)(pcl + ((size_t)head*T_T + t)*D_H) + fs*4;
  po[0] = make_float4((w0.x+EPS_C*c0.x)*dinv,(w0.y+EPS_C*c0.y)*dinv,(w0.z+EPS_C*c0.z)*dinv,(w0.w+EPS_C*c0.w)*dinv);
  po[1] = make_float4((w1.x+EPS_C*c1.x)*dinv,(w1.y+EPS_C*c1.y)*dinv,(w1.z+EPS_C*c1.z)*dinv,(w1.w+EPS_C*c1.w)*dinv);
  po[2] = make_float4((w2.x+EPS_C*c2.x)*dinv,(w2.y+EPS_C*c2.y)*dinv,(w2.z+EPS_C*c2.z)*dinv,(w2.w+EPS_C*c2.w)*dinv);
  po[3] = make_float4((w3.x+EPS_C*c3.x)*dinv,(w3.y+EPS_C*c3.y)*dinv,(w3.z+EPS_C*c3.z)*dinv,(w3.w+EPS_C*c3.w)*dinv);
}

// ---------------- Kernel D: MLP + LN + GELU + score + softmax -------------
#define FMA4(A,s,W) {A.x+=(s)*W.x; A.y+=(s)*W.y; A.z+=(s)*W.z; A.w+=(s)*W.w;}
__global__ __launch_bounds__(256) void mlp_kern(
    const float* __restrict__ pcl, const float* __restrict__ v,
    const float* __restrict__ mask,
    const float* __restrict__ encw, const float* __restrict__ encb,
    const float* __restrict__ lng, const float* __restrict__ lnb,
    const float* __restrict__ decw, const float* __restrict__ decb,
    float* __restrict__ probsout, float* __restrict__ scoreout){
  int head = blockIdx.x, tblk = blockIdx.y;   // grid (48,32)
  int t0 = tblk*32;
  int n = head / H_H;
  __shared__ float xs[32*132];
  __shared__ float wts[32*132];
  __shared__ float h1s[32*132];
  int colT = threadIdx.x & 15, rowT = threadIdx.x >> 4;
  int r0 = rowT, r1 = rowT + 16;
  const float* pclrow = pcl + ((size_t)head*T_T + t0)*D_H;
  const float* vrow   = v   + ((size_t)head*T_T + t0)*D_H;
  for(int i=threadIdx.x;i<512;i+=256){
    int r=i>>4, q=i&15;
    ((float4*)(xs + r*132))[q]      = ((const float4*)(pclrow + r*64))[q];
    ((float4*)(xs + r*132 + 64))[q] = ((const float4*)(vrow   + r*64))[q];
  }
  float4 bias0 = ((const float4*)encb)[colT];
  float4 bias1 = ((const float4*)encb)[colT+16];
  float4 A0=bias0, A1=bias1, B0=bias0, B1=bias1;
  for(int kc=0;kc<4;kc++){
    __syncthreads();
    for(int i=threadIdx.x;i<1024;i+=256){
      int k=i>>5, q=i&31;
      ((float4*)(wts + k*132))[q] = ((const float4*)(encw + (size_t)(kc*32+k)*128))[q];
    }
    __syncthreads();
    #pragma unroll
    for(int kq=0;kq<8;kq++){
      float4 x0 = ((const float4*)(xs + r0*132 + kc*32))[kq];
      float4 x1 = ((const float4*)(xs + r1*132 + kc*32))[kq];
      #pragma unroll
      for(int kk=0;kk<4;kk++){
        const float* wrow = wts + (kq*4+kk)*132;
        float4 wa = ((const float4*)wrow)[colT];
        float4 wb = ((const float4*)wrow)[colT+16];
        float xv0 = (kk==0)?x0.x:(kk==1)?x0.y:(kk==2)?x0.z:x0.w;
        float xv1 = (kk==0)?x1.x:(kk==1)?x1.y:(kk==2)?x1.z:x1.w;
        FMA4(A0,xv0,wa); FMA4(A1,xv0,wb);
        FMA4(B0,xv1,wa); FMA4(B1,xv1,wb);
      }
    }
  }
  float4 lg0 = ((const float4*)lng)[colT], lg1 = ((const float4*)lng)[colT+16];
  float4 lb0 = ((const float4*)lnb)[colT], lb1 = ((const float4*)lnb)[colT+16];
  float s0 = A0.x+A0.y+A0.z+A0.w + A1.x+A1.y+A1.z+A1.w;
  float s1 = B0.x+B0.y+B0.z+B0.w + B1.x+B1.y+B1.z+B1.w;
  for(int o=1;o<16;o<<=1){ s0 += __shfl_xor(s0,o,64); s1 += __shfl_xor(s1,o,64); }
  float mu0 = s0*(1.0f/128.0f), mu1 = s1*(1.0f/128.0f);
  float v0=0.f, v1=0.f;
  { float d;
    d=A0.x-mu0; v0+=d*d; d=A0.y-mu0; v0+=d*d; d=A0.z-mu0; v0+=d*d; d=A0.w-mu0; v0+=d*d;
    d=A1.x-mu0; v0+=d*d; d=A1.y-mu0; v0+=d*d; d=A1.z-mu0; v0+=d*d; d=A1.w-mu0; v0+=d*d;
    d=B0.x-mu1; v1+=d*d; d=B0.y-mu1; v1+=d*d; d=B0.z-mu1; v1+=d*d; d=B0.w-mu1; v1+=d*d;
    d=B1.x-mu1; v1+=d*d; d=B1.y-mu1; v1+=d*d; d=B1.z-mu1; v1+=d*d; d=B1.w-mu1; v1+=d*d; }
  for(int o=1;o<16;o<<=1){ v0 += __shfl_xor(v0,o,64); v1 += __shfl_xor(v1,o,64); }
  float den0 = sqrtf(v0*(1.0f/128.0f)+1e-5f);
  float den1 = sqrtf(v1*(1.0f/128.0f)+1e-5f);
  #define GELU(x) ((x)*0.5f*(1.0f+erff((x)*0.70710678118654752f)))
  #define LNG(a,mu,dn,g,b) GELU(((a)-(mu))/(dn)*(g)+(b))
  float4 H;
  H.x=LNG(A0.x,mu0,den0,lg0.x,lb0.x); H.y=LNG(A0.y,mu0,den0,lg0.y,lb0.y);
  H.z=LNG(A0.z,mu0,den0,lg0.z,lb0.z); H.w=LNG(A0.w,mu0,den0,lg0.w,lb0.w);
  ((float4*)(h1s + r0*132))[colT] = H;
  H.x=LNG(A1.x,mu0,den0,lg1.x,lb1.x); H.y=LNG(A1.y,mu0,den0,lg1.y,lb1.y);
  H.z=LNG(A1.z,mu0,den0,lg1.z,lb1.z); H.w=LNG(A1.w,mu0,den0,lg1.w,lb1.w);
  ((float4*)(h1s + r0*132))[colT+16] = H;
  H.x=LNG(B0.x,mu1,den1,lg0.x,lb0.x); H.y=LNG(B0.y,mu1,den1,lg0.y,lb0.y);
  H.z=LNG(B0.z,mu1,den1,lg0.z,lb0.z); H.w=LNG(B0.w,mu1,den1,lg0.w,lb0.w);
  ((float4*)(h1s + r1*132))[colT] = H;
  H.x=LNG(B1.x,mu1,den1,lg1.x,lb1.x); H.y=LNG(B1.y,mu1,den1,lg1.y,lb1.y);
  H.z=LNG(B1.z,mu1,den1,lg1.z,lb1.z); H.w=LNG(B1.w,mu1,den1,lg1.w,lb1.w);
  ((float4*)(h1s + r1*132))[colT+16] = H;
  bias0 = ((const float4*)decb)[colT];
  bias1 = ((const float4*)decb)[colT+16];
  A0=bias0; A1=bias1; B0=bias0; B1=bias1;
  for(int kc=0;kc<4;kc++){
    __syncthreads();
    for(int i=threadIdx.x;i<1024;i+=256){
      int k=i>>5, q=i&31;
      ((float4*)(wts + k*132))[q] = ((const float4*)(decw + (size_t)(kc*32+k)*128))[q];
    }
    __syncthreads();
    #pragma unroll
    for(int kq=0;kq<8;kq++){
      float4 x0 = ((const float4*)(h1s + r0*132 + kc*32))[kq];
      float4 x1 = ((const float4*)(h1s + r1*132 + kc*32))[kq];
      #pragma unroll
      for(int kk=0;kk<4;kk++){
        const float* wrow = wts + (kq*4+kk)*132;
        float4 wa = ((const float4*)wrow)[colT];
        float4 wb = ((const float4*)wrow)[colT+16];
        float xv0 = (kk==0)?x0.x:(kk==1)?x0.y:(kk==2)?x0.z:x0.w;
        float xv1 = (kk==0)?x1.x:(kk==1)?x1.y:(kk==2)?x1.z:x1.w;
        FMA4(A0,xv0,wa); FMA4(A1,xv0,wb);
        FMA4(B0,xv1,wa); FMA4(B1,xv1,wb);
      }
    }
  }
  const float* mrow = mask + n*T_T;
  int c0 = colT*4, c1 = colT*4 + 64;
  float rm0[4], rm1[4];
  #pragma unroll
  for(int i=0;i<4;i++){ rm0[i]=mrow[(c0+i)*8]; rm1[i]=mrow[(c1+i)*8]; }
  float sA[8], sB[8];
  sA[0]=(rm0[0]<-1.f)?-10000.f:A0.x; sA[1]=(rm0[1]<-1.f)?-10000.f:A0.y;
  sA[2]=(rm0[2]<-1.f)?-10000.f:A0.z; sA[3]=(rm0[3]<-1.f)?-10000.f:A0.w;
  sA[4]=(rm1[0]<-1.f)?-10000.f:A1.x; sA[5]=(rm1[1]<-1.f)?-10000.f:A1.y;
  sA[6]=(rm1[2]<-1.f)?-10000.f:A1.z; sA[7]=(rm1[3]<-1.f)?-10000.f:A1.w;
  sB[0]=(rm0[0]<-1.f)?-10000.f:B0.x; sB[1]=(rm0[1]<-1.f)?-10000.f:B0.y;
  sB[2]=(rm0[2]<-1.f)?-10000.f:B0.z; sB[3]=(rm0[3]<-1.f)?-10000.f:B0.w;
  sB[4]=(rm1[0]<-1.f)?-10000.f:B1.x; sB[5]=(rm1[1]<-1.f)?-10000.f:B1.y;
  sB[6]=(rm1[2]<-1.f)?-10000.f:B1.z; sB[7]=(rm1[3]<-1.f)?-10000.f:B1.w;
  float mx0=sA[0], mx1=sB[0];
  #pragma unroll
  for(int i=1;i<8;i++){ mx0=fmaxf(mx0,sA[i]); mx1=fmaxf(mx1,sB[i]); }
  for(int o=1;o<16;o<<=1){ mx0=fmaxf(mx0,__shfl_xor(mx0,o,64)); mx1=fmaxf(mx1,__shfl_xor(mx1,o,64)); }
  float Z0=0.f, Z1=0.f;
  #pragma unroll
  for(int i=0;i<8;i++){ sA[i]=expf(sA[i]-mx0); Z0+=sA[i]; sB[i]=expf(sB[i]-mx1); Z1+=sB[i]; }
  for(int o=1;o<16;o<<=1){ Z0+=__shfl_xor(Z0,o,64); Z1+=__shfl_xor(Z1,o,64); }
  float zi0=1.0f/Z0, zi1=1.0f/Z1;
  size_t rb0 = ((size_t)head*T_T + t0 + r0)*TM_;
  size_t rb1 = ((size_t)head*T_T + t0 + r1)*TM_;
  ((float4*)(probsout+rb0))[colT]    = make_float4(sA[0]*zi0,sA[1]*zi0,sA[2]*zi0,sA[3]*zi0);
  ((float4*)(probsout+rb0))[colT+16] = make_float4(sA[4]*zi0,sA[5]*zi0,sA[6]*zi0,sA[7]*zi0);
  ((float4*)(probsout+rb1))[colT]    = make_float4(sB[0]*zi1,sB[1]*zi1,sB[2]*zi1,sB[3]*zi1);
  ((float4*)(probsout+rb1))[colT+16] = make_float4(sB[4]*zi1,sB[5]*zi1,sB[6]*zi1,sB[7]*zi1);
  ((float4*)(scoreout+rb0))[colT]    = A0;
  ((float4*)(scoreout+rb0))[colT+16] = A1;
  ((float4*)(scoreout+rb1))[colT]    = B0;
  ((float4*)(scoreout+rb1))[colT+16] = B1;
}

// ---------------- Kernel E v3: per-row KL + MSE, register-resident --------
// thread owns j = 4t..4t+3 (contiguous); j>>3 == t>>1 constant per thread.
// a/mk/es live in registers across all passes; LDS only for sc + reductions.
__global__ __launch_bounds__(256) void loss_kern(
    const float* __restrict__ truth, const float* __restrict__ mask,
    const float* __restrict__ score, float* __restrict__ klrow,
    float* __restrict__ mserow){
  int row = blockIdx.x;               // head*1024 + t
  int n = row / (H_H*T_T);
  int t = threadIdx.x;
  int lane = t & 63, tq = t >> 6;
  __shared__ float sc[128];
  __shared__ float red[8];
  float4 av  = ((const float4*)(truth + (size_t)row*T_T))[t];
  float4 mkv = ((const float4*)(mask + (size_t)n*T_T))[t];
  if(t < 128) sc[t] = score[(size_t)row*TM_ + t];
  __syncthreads();
  float scv = sc[t>>1];
  // pass 1: maxes (register math)
  float ma = fmaxf(fmaxf(av.x+mkv.x, av.y+mkv.y), fmaxf(av.z+mkv.z, av.w+mkv.w));
  float ms = scv + fmaxf(fmaxf(mkv.x, mkv.y), fmaxf(mkv.z, mkv.w));
  for(int o=32;o;o>>=1){ ma=fmaxf(ma,__shfl_xor(ma,o,64)); ms=fmaxf(ms,__shfl_xor(ms,o,64)); }
  if(lane==0){ red[tq]=ma; red[4+tq]=ms; }
  __syncthreads();
  ma = fmaxf(fmaxf(red[0],red[1]),fmaxf(red[2],red[3]));
  ms = fmaxf(fmaxf(red[4],red[5]),fmaxf(red[6],red[7]));
  __syncthreads();
  // pass 2: exp sums (es kept in registers)
  float e0=__expf(av.x+mkv.x-ma), e1=__expf(av.y+mkv.y-ma),
        e2=__expf(av.z+mkv.z-ma), e3=__expf(av.w+mkv.w-ma);
  float Za = (e0+e1)+(e2+e3);
  float Zs = (__expf(scv+mkv.x-ms)+__expf(scv+mkv.y-ms))
           + (__expf(scv+mkv.z-ms)+__expf(scv+mkv.w-ms));
  for(int o=32;o;o>>=1){ Za+=__shfl_xor(Za,o,64); Zs+=__shfl_xor(Zs,o,64); }
  if(lane==0){ red[tq]=Za; red[4+tq]=Zs; }
  __syncthreads();
  Za = (red[0]+red[1])+(red[2]+red[3]);
  Zs = (red[4]+red[5])+(red[6]+red[7]);
  __syncthreads();
  float lZs = __logf(Zs), lZa = __logf(Za);
  float invZa = 1.0f/Za;
  float kl=0.f, mse=0.f;
  #define LKL(AJ,MKJ,EJ) { \
    if((MKJ) > -1.0f){ \
      float pt = (EJ)*invZa; \
      float logpt = (pt >= 1e-12f) ? ((AJ)+(MKJ)-ma-lZa) : -27.631021116f; \
      float logp = (scv+(MKJ)-ms) - lZs; \
      kl += pt*(logpt-logp); } \
    float sv = ((MKJ) < -1.0f)?0.f:scv; \
    float avv = ((MKJ) < -1.0f)?0.f:(AJ); \
    float dd = sv-avv; mse += dd*dd; }
  LKL(av.x,mkv.x,e0) LKL(av.y,mkv.y,e1) LKL(av.z,mkv.z,e2) LKL(av.w,mkv.w,e3)
  #undef LKL
  for(int o=32;o;o>>=1){ kl+=__shfl_xor(kl,o,64); mse+=__shfl_xor(mse,o,64); }
  if(lane==0){ red[tq]=kl; red[4+tq]=mse; }
  __syncthreads();
  if(t==0){
    klrow[row]  = (red[0]+red[1])+(red[2]+red[3]);
    mserow[row] = (red[4]+red[5])+(red[6]+red[7]);
  }
}

// ---------------- Kernel F: final loss ------------------------------------
__global__ __launch_bounds__(256) void finloss_kern(
    const float* __restrict__ klrow, const float* __restrict__ mserow,
    const float* __restrict__ mask, float* __restrict__ out0){
  __shared__ double reds[256];
  double kls=0, mses=0;
  for(int i=threadIdx.x;i<N_H*T_T;i+=256){ kls+=(double)klrow[i]; mses+=(double)mserow[i]; }
  double vcnt=0;
  for(int i=threadIdx.x;i<N_B*T_T;i+=256) if(mask[i] > -1.0f) vcnt+=1.0;
  reds[threadIdx.x]=kls; __syncthreads();
  for(int o=128;o;o>>=1){ if(threadIdx.x<o) reds[threadIdx.x]+=reds[threadIdx.x+o]; __syncthreads(); }
  double klsum = reds[0]; __syncthreads();
  reds[threadIdx.x]=mses; __syncthreads();
  for(int o=128;o;o>>=1){ if(threadIdx.x<o) reds[threadIdx.x]+=reds[threadIdx.x+o]; __syncthreads(); }
  double msesum = reds[0]; __syncthreads();
  reds[threadIdx.x]=vcnt; __syncthreads();
  for(int o=128;o;o>>=1){ if(threadIdx.x<o) reds[threadIdx.x]+=reds[threadIdx.x+o]; __syncthreads(); }
  if(threadIdx.x==0){
    double denom = reds[0] * (double)(H_H*T_T);
    double loss = klsum/denom*0.25 + msesum/((double)N_B*H_H*T_T*T_T);
    out0[0]=(float)loss;
  }
}

// ---------------- Top-k pipeline ------------------------------------------
__global__ void topk_init(unsigned* __restrict__ hist, unsigned* __restrict__ state,
                          unsigned* __restrict__ tiecnt){
  int i = blockIdx.x*256+threadIdx.x;
  if(i < 4*256) hist[i]=0;
  if(i < 4){ state[i*4+0]=0u; state[i*4+1]=KSEL; state[i*4+2]=0u; tiecnt[i]=0u; }
}

__global__ __launch_bounds__(256) void topk_hist(
    const float* __restrict__ probs, const float* __restrict__ mask,
    const unsigned* __restrict__ state, unsigned* __restrict__ hist, int level){
  __shared__ unsigned lh[4*256];
  for(int i=threadIdx.x;i<1024;i+=256) lh[i]=0;
  __syncthreads();
  unsigned pmask = (level==0)?0u:(0xFFFFFFFFu << (32-8*level));
  unsigned pref[4];
  for(int b=0;b<4;b++) pref[b]=state[b*4+0] & pmask;
  int shift = 24-8*level;
  size_t total = (size_t)N_B*PER_BATCH;
  for(size_t idx = (size_t)blockIdx.x*256+threadIdx.x; idx < total; idx += (size_t)gridDim.x*256){
    int b = (int)(idx / PER_BATCH);
    unsigned r = (unsigned)(idx - (size_t)b*PER_BATCH);
    int t = (int)((r>>7)&1023u);
    float val = probs[idx];
    if(!(mask[b*T_T+t] > -1.0f)) val = 0.0f;
    unsigned u = __float_as_uint(val);
    if((u & pmask) == pref[b]) atomicAdd(&lh[b*256+((u>>shift)&255u)],1u);
  }
  __syncthreads();
  for(int i=threadIdx.x;i<1024;i+=256){
    unsigned c = lh[i];
    if(c) atomicAdd(&hist[i], c);
  }
}

__global__ void topk_scan(unsigned* __restrict__ hist, unsigned* __restrict__ state, int level){
  int b = blockIdx.x;
  if(threadIdx.x==0){
    const unsigned* h = hist + b*256;
    unsigned remk = state[b*4+1];
    unsigned cum = 0; int sel=0;
    for(int bin=255; bin>=0; bin--){
      unsigned c = h[bin];
      if(remk <= cum + c){ sel=bin; break; }
      cum += c;
    }
    state[b*4+0] |= ((unsigned)sel) << (24-8*level);
    state[b*4+1] = remk - cum;
    state[b*4+2] += cum;
  }
  __syncthreads();
  for(int i=threadIdx.x;i<256;i+=blockDim.x) hist[b*256+i]=0;
}

__global__ __launch_bounds__(256) void topk_write(
    const float* __restrict__ probs, const float* __restrict__ mask,
    const unsigned* __restrict__ state, float* __restrict__ pam,
    unsigned* __restrict__ ties, unsigned* __restrict__ tiecnt){
  unsigned thr[4];
  for(int b=0;b<4;b++) thr[b]=state[b*4+0];
  size_t total=(size_t)N_B*PER_BATCH;
  for(size_t idx=(size_t)blockIdx.x*256+threadIdx.x; idx<total; idx += (size_t)gridDim.x*256){
    int b = (int)(idx / PER_BATCH);
    unsigned r = (unsigned)(idx - (size_t)b*PER_BATCH);
    int t = (int)((r>>7)&1023u);
    float val = probs[idx];
    if(!(mask[b*T_T+t] > -1.0f)) val=0.0f;
    unsigned u=__float_as_uint(val);
    float o = -10000.0f;
    if(u > thr[b]) o = 0.0f;
    else if(u == thr[b]){
      unsigned pos = atomicAdd(&tiecnt[b],1u);
      if(pos < 65536u) ties[(size_t)b*65536+pos]=r;
    }
    pam[idx]=o;
  }
}

__global__ __launch_bounds__(256) void topk_ties(
    const unsigned* __restrict__ state, const unsigned* __restrict__ ties,
    const unsigned* __restrict__ tiecnt, float* __restrict__ pam){
  int b = blockIdx.x;
  unsigned needed = state[b*4+1];
  unsigned nt = min(tiecnt[b], 65536u);
  __shared__ unsigned redu[256];
  __shared__ unsigned lohi[2];
  if(threadIdx.x==0){ lohi[0]=0u; lohi[1]=PER_BATCH; }
  __syncthreads();
  if(needed == 0 || nt == 0) return;
  while(true){
    __syncthreads();
    unsigned lo=lohi[0], hi=lohi[1];
    if(hi-lo<=1u) break;
    unsigned mid=(lo+hi)>>1;
    unsigned c=0;
    for(unsigned i=threadIdx.x;i<nt;i+=256) c += (ties[(size_t)b*65536+i] < mid)?1u:0u;
    redu[threadIdx.x]=c; __syncthreads();
    for(int o=128;o;o>>=1){ if(threadIdx.x<o) redu[threadIdx.x]+=redu[threadIdx.x+o]; __syncthreads(); }
    if(threadIdx.x==0){ if(redu[0]>=needed) lohi[1]=mid; else lohi[0]=mid; }
  }
  __syncthreads();
  unsigned X=lohi[1];
  for(unsigned i=threadIdx.x;i<nt;i+=256){
    unsigned r=ties[(size_t)b*65536+i];
    if(r < X) pam[(size_t)b*PER_BATCH + r]=0.0f;
  }
}

// ---------------- launcher ------------------------------------------------
extern "C" void kernel_launch(void* const* d_in, const int* in_sizes, int n_in,
                              void* d_out, int out_size, void* d_ws, size_t ws_size,
                              hipStream_t stream) {
  const float* v     = (const float*)d_in[2];
  const float* qfa   = (const float*)d_in[3];
  const float* kfa   = (const float*)d_in[4];
  const float* mask  = (const float*)d_in[8];
  const float* truth = (const float*)d_in[9];
  const float* pm    = (const float*)d_in[11];
  const float* encw  = (const float*)d_in[12];
  const float* encb  = (const float*)d_in[13];
  const float* lng   = (const float*)d_in[14];
  const float* lnb   = (const float*)d_in[15];
  const float* decw  = (const float*)d_in[16];
  const float* decb  = (const float*)d_in[17];
  float* out = (float*)d_out;
  float* ws  = (float*)d_ws;

  float* ctx     = ws;                              // 48*266*64 = 817152
  float* ksum    = ctx + (size_t)N_H*F_F*64;        // 12768
  float* klrow   = ksum + N_H*F_F;                  // 49152
  float* mserow  = klrow + N_H*T_T;                 // 49152
  unsigned* hist   = (unsigned*)(mserow + N_H*T_T); // 1024
  unsigned* state  = hist + 1024;                   // 16
  unsigned* tiecnt = state + 16;                    // 4 (+pad)
  unsigned* ties   = tiecnt + 12;                   // 4*65536
  float* diags   = (float*)(ties + 4*65536);        // 48*1024 = 49152
  float* ctxraw  = diags + N_H*T_T;                 // 48*266*64 = 817152
  float* ksumP   = ctxraw + (size_t)N_H*F_F*64;     // 48*266 = 12768
  float* mfP     = ksumP + N_H*F_F;                 // 48*19 = 912
  float* ksum_tot= mfP + 1024;                      // 48
  float* ctx_tot = ksum_tot + 48;                   // 3072

  float* pcl   = out + 1;
  float* probs = pcl + (size_t)N_H*T_T*D_H;
  float* pam   = probs + (size_t)N_H*T_T*TM_;

  diag_kern<<<dim3(N_H,4),256,0,stream>>>(kfa, diags);
  keyfeat_kern<<<dim3(N_H,NCH),256,0,stream>>>(kfa, pm, mask, diags, ctxraw, ksumP, mfP);
  fixup_kern<<<N_H,256,0,stream>>>(mfP, ksumP, ctxraw, mask, ctx, ksum, ksum_tot, ctx_tot);
  qfeat_kern<<<dim3(N_H,16),256,0,stream>>>(qfa, pm, ctx, ksum, ksum_tot, ctx_tot, pcl);
  mlp_kern<<<dim3(N_H,32),256,0,stream>>>(pcl, v, mask, encw, encb, lng, lnb,
                                          decw, decb, probs, pam /*score*/);
  loss_kern<<<N_H*T_T,256,0,stream>>>(truth, mask, pam /*score*/, klrow, mserow);
  finloss_kern<<<1,256,0,stream>>>(klrow, mserow, mask, out);
  topk_init<<<4,256,0,stream>>>(hist, state, tiecnt);
  for(int lvl=0;lvl<4;lvl++){
    topk_hist<<<2048,256,0,stream>>>(probs, mask, state, hist, lvl);
    topk_scan<<<4,64,0,stream>>>(hist, state, lvl);
  }
  topk_write<<<2048,256,0,stream>>>(probs, mask, state, pam, ties, tiecnt);
  topk_ties<<<4,256,0,stream>>>(state, ties, tiecnt, pam);
}

// Round 10
// 595.137 us; speedup vs baseline: 2.9653x; 1.0004x over previous
//
#include <hip/hip_runtime.h>
#include <hip/hip_bf16.h>
#include <math.h>

#define N_B 4
#define H_H 12
#define T_T 1024
#define D_H 64
#define F_F 266
#define N_H 48          // N_B*H_H
#define TM_ 128
#define KSEL 98304u     // kk*T*H = 8*1024*12
#define PER_BATCH 1572864  // H*T*TM
#define FCH 14
#define NCH 19          // 19*14 = 266

static __device__ __forceinline__ float waveSum(float v){
  for(int o=32;o;o>>=1) v += __shfl_xor(v,o,64);
  return v;
}
static __device__ __forceinline__ float waveMax(float v){
  for(int o=32;o;o>>=1) v = fmaxf(v,__shfl_xor(v,o,64));
  return v;
}

#define DN_C 0.35355339059327373f   // 64^-0.25 = 2^-1.5
#define DIAG_C 0.0625f              // 0.5 * 64^-0.5
#define RATIO_C 0.06131393394849658f // 266^-0.5
#define EPS_C 1e-4f

// ---------------- Kernel A0: per-(head,t) diag ----------------------------
__global__ __launch_bounds__(256) void diag_kern(
    const float* __restrict__ kfa, float* __restrict__ diags){
  int head = blockIdx.x; int t = blockIdx.y*256 + threadIdx.x;
  const float4* xp = (const float4*)(kfa + ((size_t)head*T_T + t)*D_H);
  float diag = 0.f;
  #pragma unroll
  for(int kk=0;kk<16;kk++){ float4 x = xp[kk];
    diag += x.x*x.x + x.y*x.y + x.z*x.z + x.w*x.w; }
  diags[head*T_T + t] = diag * DIAG_C;
}

// ---------------- Kernel B v4: key features, lane-owns-t-strided ----------
__global__ __launch_bounds__(256) void keyfeat_kern(
    const float* __restrict__ kfa, const float* __restrict__ pm,
    const float* __restrict__ mask, const float* __restrict__ diags,
    float* __restrict__ ctxraw, float* __restrict__ ksumP,
    float* __restrict__ mfP){
  int head = blockIdx.x, fc = blockIdx.y;
  int f0 = fc*FCH;
  int n = head / H_H;
  int lane = threadIdx.x & 63, tq = threadIdx.x >> 6;
  __shared__ float cred[FCH][64];
  __shared__ float kred[4][FCH];
  __shared__ float mred[4];
  float kacc[FCH], cacc[FCH];
  #pragma unroll
  for(int i=0;i<FCH;i++){ kacc[i]=0.f; cacc[i]=0.f; }
  float mymax = -3.4e38f;
  for(int tt=0; tt<4; tt++){
    int tc = tq*4 + tt;
    int t = lane*16 + tc;
    const float4* xp = (const float4*)(kfa + ((size_t)head*T_T + t)*D_H);
    float4 xr[16];
    #pragma unroll
    for(int kk=0;kk<16;kk++) xr[kk] = xp[kk];
    float dg = diags[head*T_T + t];
    float cmul = ((tc < 8) && (mask[n*T_T + t] > -1.0f)) ? 1.f : 0.f;
    for(int fi=0; fi<FCH; fi++){
      const float4* pr = (const float4*)(pm + (size_t)(f0+fi)*D_H);
      float s0=0,s1=0,s2=0,s3=0;
      #pragma unroll
      for(int kk=0;kk<16;kk++){ float4 w4 = pr[kk];
        s0+=xr[kk].x*w4.x; s1+=xr[kk].y*w4.y; s2+=xr[kk].z*w4.z; s3+=xr[kk].w*w4.w; }
      float dd = DN_C*((s0+s1)+(s2+s3));
      mymax = fmaxf(mymax, dd);
      float e = expf(dd - dg);
      kacc[fi] += e;
      cacc[fi] += e*cmul;
    }
  }
  #pragma unroll
  for(int fi=0;fi<FCH;fi++){
    float s = waveSum(kacc[fi]);
    if(lane==0) kred[tq][fi] = s;
  }
  mymax = waveMax(mymax);
  if(lane==0) mred[tq]=mymax;
  if(tq==0){
    #pragma unroll
    for(int fi=0;fi<FCH;fi++) cred[fi][lane] = cacc[fi];
  }
  __syncthreads();
  if(tq==1){
    #pragma unroll
    for(int fi=0;fi<FCH;fi++) cred[fi][lane] += cacc[fi];
  }
  __syncthreads();
  for(int i=threadIdx.x; i<FCH*64; i+=256){
    int fi=i>>6, d=i&63;
    ctxraw[((size_t)head*F_F + f0+fi)*64 + d] = cred[fi][d];
  }
  if(threadIdx.x < FCH)
    ksumP[head*F_F + f0 + threadIdx.x] =
      kred[0][threadIdx.x]+kred[1][threadIdx.x]+kred[2][threadIdx.x]+kred[3][threadIdx.x];
  if(threadIdx.x==0)
    mfP[head*NCH+fc] = fmaxf(fmaxf(mred[0],mred[1]),fmaxf(mred[2],mred[3]));
}

// ---------------- Kernel B2: per-head fixup -------------------------------
__global__ __launch_bounds__(256) void fixup_kern(
    const float* __restrict__ mfP, const float* __restrict__ ksumP,
    const float* __restrict__ ctxraw, const float* __restrict__ mask,
    float* __restrict__ ctx, float* __restrict__ ksum,
    float* __restrict__ ksum_tot, float* __restrict__ ctx_tot){
  int head = blockIdx.x; int n = head/H_H;
  __shared__ float segc[64];
  __shared__ float part[4][64];
  __shared__ float kpart[4];
  float m_head = mfP[head*NCH];
  for(int i=1;i<NCH;i++) m_head = fmaxf(m_head, mfP[head*NCH+i]);
  float e_mh = expf(-m_head);
  if(threadIdx.x < 64){
    int d = threadIdx.x; float c=0.f;
    for(int i=0;i<8;i++) c += (mask[n*T_T + 16*d + i] > -1.0f) ? 1.f : 0.f;
    segc[d] = c;
  }
  __syncthreads();
  int g = threadIdx.x>>6, d = threadIdx.x&63;
  float ct = 0.f, kt = 0.f;
  for(int f=g; f<F_F; f+=4){
    float craw = ctxraw[((size_t)head*F_F+f)*64 + d];
    float cf = RATIO_C*(craw*e_mh + EPS_C*segc[d]);
    ctx[((size_t)head*F_F+f)*64 + d] = cf;
    ct += cf;
    if(d==0){
      float kf = RATIO_C*(ksumP[head*F_F+f]*e_mh + EPS_C*(float)T_T);
      ksum[head*F_F+f] = kf;
      kt += kf;
    }
  }
  part[g][d] = ct;
  if(d==0) kpart[g] = kt;
  __syncthreads();
  if(threadIdx.x < 64)
    ctx_tot[head*64+threadIdx.x] =
      part[0][threadIdx.x]+part[1][threadIdx.x]+part[2][threadIdx.x]+part[3][threadIdx.x];
  if(threadIdx.x==0) ksum_tot[head] = kpart[0]+kpart[1]+kpart[2]+kpart[3];
}

// ---------------- Kernel C v4: query features + pcl (deferred max) --------
// Accumulate S/acc against a FIXED per-thread base m_acc (first dd seen);
// track m_run with 1 fmax per f; single rescale exp(m_acc-m_run) at end.
// Removes the divergent 65-op in-loop rescale (~50% of kernel time).
// Safe: dd spread for this data is ~±9, far below exp overflow.
__global__ __launch_bounds__(256) void qfeat_kern(
    const float* __restrict__ qfa, const float* __restrict__ pm,
    const float* __restrict__ ctx, const float* __restrict__ ksum,
    const float* __restrict__ ksum_tot, const float* __restrict__ ctx_tot,
    float* __restrict__ pcl){
  int head = blockIdx.x, tc = blockIdx.y;   // grid (48,16), 256 threads
  int rl = threadIdx.x >> 2, fs = threadIdx.x & 3;
  int t = tc*64 + rl;
  __shared__ float pms[56*68];
  __shared__ float ctxs[56*68];
  __shared__ float ksums[56];
  const float* xp = qfa + ((size_t)head*T_T + t)*D_H;
  float4 xr[16];
  #pragma unroll
  for(int kk=0;kk<16;kk++) xr[kk] = ((const float4*)xp)[kk];
  float diag = 0.f;
  #pragma unroll
  for(int kk=0;kk<16;kk++)
    diag += xr[kk].x*xr[kk].x + xr[kk].y*xr[kk].y + xr[kk].z*xr[kk].z + xr[kk].w*xr[kk].w;
  diag *= DIAG_C;
  float m_run = -3.4e38f, m_acc = 0.f, S = 0.f;
  bool first = true;
  float4 acc[16];
  #pragma unroll
  for(int kk=0;kk<16;kk++) acc[kk] = make_float4(0.f,0.f,0.f,0.f);
  for(int c=0;c<5;c++){
    int f0 = c*56, CF = min(56, F_F-f0);
    __syncthreads();
    for(int i=threadIdx.x;i<CF*16;i+=256){
      int fl=i>>4, d4=i&15;
      ((float4*)(pms+fl*68))[d4]  = ((const float4*)(pm+(size_t)(f0+fl)*64))[d4];
      ((float4*)(ctxs+fl*68))[d4] = ((const float4*)(ctx+((size_t)head*F_F+f0+fl)*64))[d4];
    }
    for(int i=threadIdx.x;i<CF;i+=256) ksums[i]=ksum[head*F_F+f0+i];
    __syncthreads();
    int nj = (CF - fs + 3)>>2;
    for(int j=0;j<nj;j++){
      int fl = fs+4*j;
      const float4* pr = (const float4*)(pms + fl*68);
      float s0=0,s1=0,s2=0,s3=0;
      #pragma unroll
      for(int kk=0;kk<16;kk++){ float4 w4 = pr[kk];
        s0+=xr[kk].x*w4.x; s1+=xr[kk].y*w4.y; s2+=xr[kk].z*w4.z; s3+=xr[kk].w*w4.w; }
      float dd = DN_C*((s0+s1)+(s2+s3));
      if(first){ m_acc = dd; first = false; }
      m_run = fmaxf(m_run, dd);
      float e = expf(dd - diag - m_acc);
      S += e * ksums[fl];
      const float4* cr = (const float4*)(ctxs + fl*68);
      #pragma unroll
      for(int kk=0;kk<16;kk++){ float4 c4=cr[kk];
        acc[kk].x+=e*c4.x; acc[kk].y+=e*c4.y; acc[kk].z+=e*c4.z; acc[kk].w+=e*c4.w; }
    }
  }
  // single deferred rescale to m_run base
  {
    float fac = expf(m_acc - m_run);
    S *= fac;
    #pragma unroll
    for(int kk=0;kk<16;kk++){
      acc[kk].x*=fac; acc[kk].y*=fac; acc[kk].z*=fac; acc[kk].w*=fac;
    }
  }
  // combine the 4 f-slices with max-rescale (butterfly)
  for(int st=1; st<=2; st<<=1){
    float mo = __shfl_xor(m_run, st, 64);
    float mc = fmaxf(m_run, mo);
    float fac = expf(m_run - mc);
    S *= fac;
    S += __shfl_xor(S, st, 64);
    #pragma unroll
    for(int kk=0;kk<16;kk++){
      acc[kk].x*=fac; acc[kk].y*=fac; acc[kk].z*=fac; acc[kk].w*=fac;
    }
    #pragma unroll
    for(int kk=0;kk<16;kk++){
      acc[kk].x += __shfl_xor(acc[kk].x,st,64);
      acc[kk].y += __shfl_xor(acc[kk].y,st,64);
      acc[kk].z += __shfl_xor(acc[kk].z,st,64);
      acc[kk].w += __shfl_xor(acc[kk].w,st,64);
    }
    m_run = mc;
  }
  float den = S + EPS_C * ksum_tot[head];
  float dinv = 1.0f/den;
  float4 w0,w1,w2,w3;
  if(fs==0){ w0=acc[0]; w1=acc[1]; w2=acc[2]; w3=acc[3]; }
  else if(fs==1){ w0=acc[4]; w1=acc[5]; w2=acc[6]; w3=acc[7]; }
  else if(fs==2){ w0=acc[8]; w1=acc[9]; w2=acc[10]; w3=acc[11]; }
  else { w0=acc[12]; w1=acc[13]; w2=acc[14]; w3=acc[15]; }
  const float4* ctp = ((const float4*)(ctx_tot + head*64)) + fs*4;
  float4 c0=ctp[0], c1=ctp[1], c2=ctp[2], c3=ctp[3];
  float4* po = (float4*)(pcl + ((size_t)head*T_T + t)*D_H) + fs*4;
  po[0] = make_float4((w0.x+EPS_C*c0.x)*dinv,(w0.y+EPS_C*c0.y)*dinv,(w0.z+EPS_C*c0.z)*dinv,(w0.w+EPS_C*c0.w)*dinv);
  po[1] = make_float4((w1.x+EPS_C*c1.x)*dinv,(w1.y+EPS_C*c1.y)*dinv,(w1.z+EPS_C*c1.z)*dinv,(w1.w+EPS_C*c1.w)*dinv);
  po[2] = make_float4((w2.x+EPS_C*c2.x)*dinv,(w2.y+EPS_C*c2.y)*dinv,(w2.z+EPS_C*c2.z)*dinv,(w2.w+EPS_C*c2.w)*dinv);
  po[3] = make_float4((w3.x+EPS_C*c3.x)*dinv,(w3.y+EPS_C*c3.y)*dinv,(w3.z+EPS_C*c3.z)*dinv,(w3.w+EPS_C*c3.w)*dinv);
}

// ---------------- Kernel D: MLP + LN + GELU + score + softmax -------------
#define FMA4(A,s,W) {A.x+=(s)*W.x; A.y+=(s)*W.y; A.z+=(s)*W.z; A.w+=(s)*W.w;}
__global__ __launch_bounds__(256) void mlp_kern(
    const float* __restrict__ pcl, const float* __restrict__ v,
    const float* __restrict__ mask,
    const float* __restrict__ encw, const float* __restrict__ encb,
    const float* __restrict__ lng, const float* __restrict__ lnb,
    const float* __restrict__ decw, const float* __restrict__ decb,
    float* __restrict__ probsout, float* __restrict__ scoreout){
  int head = blockIdx.x, tblk = blockIdx.y;   // grid (48,32)
  int t0 = tblk*32;
  int n = head / H_H;
  __shared__ float xs[32*132];
  __shared__ float wts[32*132];
  __shared__ float h1s[32*132];
  int colT = threadIdx.x & 15, rowT = threadIdx.x >> 4;
  int r0 = rowT, r1 = rowT + 16;
  const float* pclrow = pcl + ((size_t)head*T_T + t0)*D_H;
  const float* vrow   = v   + ((size_t)head*T_T + t0)*D_H;
  for(int i=threadIdx.x;i<512;i+=256){
    int r=i>>4, q=i&15;
    ((float4*)(xs + r*132))[q]      = ((const float4*)(pclrow + r*64))[q];
    ((float4*)(xs + r*132 + 64))[q] = ((const float4*)(vrow   + r*64))[q];
  }
  float4 bias0 = ((const float4*)encb)[colT];
  float4 bias1 = ((const float4*)encb)[colT+16];
  float4 A0=bias0, A1=bias1, B0=bias0, B1=bias1;
  for(int kc=0;kc<4;kc++){
    __syncthreads();
    for(int i=threadIdx.x;i<1024;i+=256){
      int k=i>>5, q=i&31;
      ((float4*)(wts + k*132))[q] = ((const float4*)(encw + (size_t)(kc*32+k)*128))[q];
    }
    __syncthreads();
    #pragma unroll
    for(int kq=0;kq<8;kq++){
      float4 x0 = ((const float4*)(xs + r0*132 + kc*32))[kq];
      float4 x1 = ((const float4*)(xs + r1*132 + kc*32))[kq];
      #pragma unroll
      for(int kk=0;kk<4;kk++){
        const float* wrow = wts + (kq*4+kk)*132;
        float4 wa = ((const float4*)wrow)[colT];
        float4 wb = ((const float4*)wrow)[colT+16];
        float xv0 = (kk==0)?x0.x:(kk==1)?x0.y:(kk==2)?x0.z:x0.w;
        float xv1 = (kk==0)?x1.x:(kk==1)?x1.y:(kk==2)?x1.z:x1.w;
        FMA4(A0,xv0,wa); FMA4(A1,xv0,wb);
        FMA4(B0,xv1,wa); FMA4(B1,xv1,wb);
      }
    }
  }
  float4 lg0 = ((const float4*)lng)[colT], lg1 = ((const float4*)lng)[colT+16];
  float4 lb0 = ((const float4*)lnb)[colT], lb1 = ((const float4*)lnb)[colT+16];
  float s0 = A0.x+A0.y+A0.z+A0.w + A1.x+A1.y+A1.z+A1.w;
  float s1 = B0.x+B0.y+B0.z+B0.w + B1.x+B1.y+B1.z+B1.w;
  for(int o=1;o<16;o<<=1){ s0 += __shfl_xor(s0,o,64); s1 += __shfl_xor(s1,o,64); }
  float mu0 = s0*(1.0f/128.0f), mu1 = s1*(1.0f/128.0f);
  float v0=0.f, v1=0.f;
  { float d;
    d=A0.x-mu0; v0+=d*d; d=A0.y-mu0; v0+=d*d; d=A0.z-mu0; v0+=d*d; d=A0.w-mu0; v0+=d*d;
    d=A1.x-mu0; v0+=d*d; d=A1.y-mu0; v0+=d*d; d=A1.z-mu0; v0+=d*d; d=A1.w-mu0; v0+=d*d;
    d=B0.x-mu1; v1+=d*d; d=B0.y-mu1; v1+=d*d; d=B0.z-mu1; v1+=d*d; d=B0.w-mu1; v1+=d*d;
    d=B1.x-mu1; v1+=d*d; d=B1.y-mu1; v1+=d*d; d=B1.z-mu1; v1+=d*d; d=B1.w-mu1; v1+=d*d; }
  for(int o=1;o<16;o<<=1){ v0 += __shfl_xor(v0,o,64); v1 += __shfl_xor(v1,o,64); }
  float den0 = sqrtf(v0*(1.0f/128.0f)+1e-5f);
  float den1 = sqrtf(v1*(1.0f/128.0f)+1e-5f);
  #define GELU(x) ((x)*0.5f*(1.0f+erff((x)*0.70710678118654752f)))
  #define LNG(a,mu,dn,g,b) GELU(((a)-(mu))/(dn)*(g)+(b))
  float4 H;
  H.x=LNG(A0.x,mu0,den0,lg0.x,lb0.x); H.y=LNG(A0.y,mu0,den0,lg0.y,lb0.y);
  H.z=LNG(A0.z,mu0,den0,lg0.z,lb0.z); H.w=LNG(A0.w,mu0,den0,lg0.w,lb0.w);
  ((float4*)(h1s + r0*132))[colT] = H;
  H.x=LNG(A1.x,mu0,den0,lg1.x,lb1.x); H.y=LNG(A1.y,mu0,den0,lg1.y,lb1.y);
  H.z=LNG(A1.z,mu0,den0,lg1.z,lb1.z); H.w=LNG(A1.w,mu0,den0,lg1.w,lb1.w);
  ((float4*)(h1s + r0*132))[colT+16] = H;
  H.x=LNG(B0.x,mu1,den1,lg0.x,lb0.x); H.y=LNG(B0.y,mu1,den1,lg0.y,lb0.y);
  H.z=LNG(B0.z,mu1,den1,lg0.z,lb0.z); H.w=LNG(B0.w,mu1,den1,lg0.w,lb0.w);
  ((float4*)(h1s + r1*132))[colT] = H;
  H.x=LNG(B1.x,mu1,den1,lg1.x,lb1.x); H.y=LNG(B1.y,mu1,den1,lg1.y,lb1.y);
  H.z=LNG(B1.z,mu1,den1,lg1.z,lb1.z); H.w=LNG(B1.w,mu1,den1,lg1.w,lb1.w);
  ((float4*)(h1s + r1*132))[colT+16] = H;
  bias0 = ((const float4*)decb)[colT];
  bias1 = ((const float4*)decb)[colT+16];
  A0=bias0; A1=bias1; B0=bias0; B1=bias1;
  for(int kc=0;kc<4;kc++){
    __syncthreads();
    for(int i=threadIdx.x;i<1024;i+=256){
      int k=i>>5, q=i&31;
      ((float4*)(wts + k*132))[q] = ((const float4*)(decw + (size_t)(kc*32+k)*128))[q];
    }
    __syncthreads();
    #pragma unroll
    for(int kq=0;kq<8;kq++){
      float4 x0 = ((const float4*)(h1s + r0*132 + kc*32))[kq];
      float4 x1 = ((const float4*)(h1s + r1*132 + kc*32))[kq];
      #pragma unroll
      for(int kk=0;kk<4;kk++){
        const float* wrow = wts + (kq*4+kk)*132;
        float4 wa = ((const float4*)wrow)[colT];
        float4 wb = ((const float4*)wrow)[colT+16];
        float xv0 = (kk==0)?x0.x:(kk==1)?x0.y:(kk==2)?x0.z:x0.w;
        float xv1 = (kk==0)?x1.x:(kk==1)?x1.y:(kk==2)?x1.z:x1.w;
        FMA4(A0,xv0,wa); FMA4(A1,xv0,wb);
        FMA4(B0,xv1,wa); FMA4(B1,xv1,wb);
      }
    }
  }
  const float* mrow = mask + n*T_T;
  int c0 = colT*4, c1 = colT*4 + 64;
  float rm0[4], rm1[4];
  #pragma unroll
  for(int i=0;i<4;i++){ rm0[i]=mrow[(c0+i)*8]; rm1[i]=mrow[(c1+i)*8]; }
  float sA[8], sB[8];
  sA[0]=(rm0[0]<-1.f)?-10000.f:A0.x; sA[1]=(rm0[1]<-1.f)?-10000.f:A0.y;
  sA[2]=(rm0[2]<-1.f)?-10000.f:A0.z; sA[3]=(rm0[3]<-1.f)?-10000.f:A0.w;
  sA[4]=(rm1[0]<-1.f)?-10000.f:A1.x; sA[5]=(rm1[1]<-1.f)?-10000.f:A1.y;
  sA[6]=(rm1[2]<-1.f)?-10000.f:A1.z; sA[7]=(rm1[3]<-1.f)?-10000.f:A1.w;
  sB[0]=(rm0[0]<-1.f)?-10000.f:B0.x; sB[1]=(rm0[1]<-1.f)?-10000.f:B0.y;
  sB[2]=(rm0[2]<-1.f)?-10000.f:B0.z; sB[3]=(rm0[3]<-1.f)?-10000.f:B0.w;
  sB[4]=(rm1[0]<-1.f)?-10000.f:B1.x; sB[5]=(rm1[1]<-1.f)?-10000.f:B1.y;
  sB[6]=(rm1[2]<-1.f)?-10000.f:B1.z; sB[7]=(rm1[3]<-1.f)?-10000.f:B1.w;
  float mx0=sA[0], mx1=sB[0];
  #pragma unroll
  for(int i=1;i<8;i++){ mx0=fmaxf(mx0,sA[i]); mx1=fmaxf(mx1,sB[i]); }
  for(int o=1;o<16;o<<=1){ mx0=fmaxf(mx0,__shfl_xor(mx0,o,64)); mx1=fmaxf(mx1,__shfl_xor(mx1,o,64)); }
  float Z0=0.f, Z1=0.f;
  #pragma unroll
  for(int i=0;i<8;i++){ sA[i]=expf(sA[i]-mx0); Z0+=sA[i]; sB[i]=expf(sB[i]-mx1); Z1+=sB[i]; }
  for(int o=1;o<16;o<<=1){ Z0+=__shfl_xor(Z0,o,64); Z1+=__shfl_xor(Z1,o,64); }
  float zi0=1.0f/Z0, zi1=1.0f/Z1;
  size_t rb0 = ((size_t)head*T_T + t0 + r0)*TM_;
  size_t rb1 = ((size_t)head*T_T + t0 + r1)*TM_;
  ((float4*)(probsout+rb0))[colT]    = make_float4(sA[0]*zi0,sA[1]*zi0,sA[2]*zi0,sA[3]*zi0);
  ((float4*)(probsout+rb0))[colT+16] = make_float4(sA[4]*zi0,sA[5]*zi0,sA[6]*zi0,sA[7]*zi0);
  ((float4*)(probsout+rb1))[colT]    = make_float4(sB[0]*zi1,sB[1]*zi1,sB[2]*zi1,sB[3]*zi1);
  ((float4*)(probsout+rb1))[colT+16] = make_float4(sB[4]*zi1,sB[5]*zi1,sB[6]*zi1,sB[7]*zi1);
  ((float4*)(scoreout+rb0))[colT]    = A0;
  ((float4*)(scoreout+rb0))[colT+16] = A1;
  ((float4*)(scoreout+rb1))[colT]    = B0;
  ((float4*)(scoreout+rb1))[colT+16] = B1;
}

// ---------------- Kernel E v3: per-row KL + MSE, register-resident --------
__global__ __launch_bounds__(256) void loss_kern(
    const float* __restrict__ truth, const float* __restrict__ mask,
    const float* __restrict__ score, float* __restrict__ klrow,
    float* __restrict__ mserow){
  int row = blockIdx.x;               // head*1024 + t
  int n = row / (H_H*T_T);
  int t = threadIdx.x;
  int lane = t & 63, tq = t >> 6;
  __shared__ float sc[128];
  __shared__ float red[8];
  float4 av  = ((const float4*)(truth + (size_t)row*T_T))[t];
  float4 mkv = ((const float4*)(mask + (size_t)n*T_T))[t];
  if(t < 128) sc[t] = score[(size_t)row*TM_ + t];
  __syncthreads();
  float scv = sc[t>>1];
  float ma = fmaxf(fmaxf(av.x+mkv.x, av.y+mkv.y), fmaxf(av.z+mkv.z, av.w+mkv.w));
  float ms = scv + fmaxf(fmaxf(mkv.x, mkv.y), fmaxf(mkv.z, mkv.w));
  for(int o=32;o;o>>=1){ ma=fmaxf(ma,__shfl_xor(ma,o,64)); ms=fmaxf(ms,__shfl_xor(ms,o,64)); }
  if(lane==0){ red[tq]=ma; red[4+tq]=ms; }
  __syncthreads();
  ma = fmaxf(fmaxf(red[0],red[1]),fmaxf(red[2],red[3]));
  ms = fmaxf(fmaxf(red[4],red[5]),fmaxf(red[6],red[7]));
  __syncthreads();
  float e0=__expf(av.x+mkv.x-ma), e1=__expf(av.y+mkv.y-ma),
        e2=__expf(av.z+mkv.z-ma), e3=__expf(av.w+mkv.w-ma);
  float Za = (e0+e1)+(e2+e3);
  float Zs = (__expf(scv+mkv.x-ms)+__expf(scv+mkv.y-ms))
           + (__expf(scv+mkv.z-ms)+__expf(scv+mkv.w-ms));
  for(int o=32;o;o>>=1){ Za+=__shfl_xor(Za,o,64); Zs+=__shfl_xor(Zs,o,64); }
  if(lane==0){ red[tq]=Za; red[4+tq]=Zs; }
  __syncthreads();
  Za = (red[0]+red[1])+(red[2]+red[3]);
  Zs = (red[4]+red[5])+(red[6]+red[7]);
  __syncthreads();
  float lZs = __logf(Zs), lZa = __logf(Za);
  float invZa = 1.0f/Za;
  float kl=0.f, mse=0.f;
  #define LKL(AJ,MKJ,EJ) { \
    if((MKJ) > -1.0f){ \
      float pt = (EJ)*invZa; \
      float logpt = (pt >= 1e-12f) ? ((AJ)+(MKJ)-ma-lZa) : -27.631021116f; \
      float logp = (scv+(MKJ)-ms) - lZs; \
      kl += pt*(logpt-logp); } \
    float sv = ((MKJ) < -1.0f)?0.f:scv; \
    float avv = ((MKJ) < -1.0f)?0.f:(AJ); \
    float dd = sv-avv; mse += dd*dd; }
  LKL(av.x,mkv.x,e0) LKL(av.y,mkv.y,e1) LKL(av.z,mkv.z,e2) LKL(av.w,mkv.w,e3)
  #undef LKL
  for(int o=32;o;o>>=1){ kl+=__shfl_xor(kl,o,64); mse+=__shfl_xor(mse,o,64); }
  if(lane==0){ red[tq]=kl; red[4+tq]=mse; }
  __syncthreads();
  if(t==0){
    klrow[row]  = (red[0]+red[1])+(red[2]+red[3]);
    mserow[row] = (red[4]+red[5])+(red[6]+red[7]);
  }
}

// ---------------- Kernel F: final loss ------------------------------------
__global__ __launch_bounds__(256) void finloss_kern(
    const float* __restrict__ klrow, const float* __restrict__ mserow,
    const float* __restrict__ mask, float* __restrict__ out0){
  __shared__ double reds[256];
  double kls=0, mses=0;
  for(int i=threadIdx.x;i<N_H*T_T;i+=256){ kls+=(double)klrow[i]; mses+=(double)mserow[i]; }
  double vcnt=0;
  for(int i=threadIdx.x;i<N_B*T_T;i+=256) if(mask[i] > -1.0f) vcnt+=1.0;
  reds[threadIdx.x]=kls; __syncthreads();
  for(int o=128;o;o>>=1){ if(threadIdx.x<o) reds[threadIdx.x]+=reds[threadIdx.x+o]; __syncthreads(); }
  double klsum = reds[0]; __syncthreads();
  reds[threadIdx.x]=mses; __syncthreads();
  for(int o=128;o;o>>=1){ if(threadIdx.x<o) reds[threadIdx.x]+=reds[threadIdx.x+o]; __syncthreads(); }
  double msesum = reds[0]; __syncthreads();
  reds[threadIdx.x]=vcnt; __syncthreads();
  for(int o=128;o;o>>=1){ if(threadIdx.x<o) reds[threadIdx.x]+=reds[threadIdx.x+o]; __syncthreads(); }
  if(threadIdx.x==0){
    double denom = reds[0] * (double)(H_H*T_T);
    double loss = klsum/denom*0.25 + msesum/((double)N_B*H_H*T_T*T_T);
    out0[0]=(float)loss;
  }
}

// ---------------- Top-k pipeline ------------------------------------------
__global__ void topk_init(unsigned* __restrict__ hist, unsigned* __restrict__ state,
                          unsigned* __restrict__ tiecnt){
  int i = blockIdx.x*256+threadIdx.x;
  if(i < 4*256) hist[i]=0;
  if(i < 4){ state[i*4+0]=0u; state[i*4+1]=KSEL; state[i*4+2]=0u; tiecnt[i]=0u; }
}

__global__ __launch_bounds__(256) void topk_hist(
    const float* __restrict__ probs, const float* __restrict__ mask,
    const unsigned* __restrict__ state, unsigned* __restrict__ hist, int level){
  __shared__ unsigned lh[4*256];
  for(int i=threadIdx.x;i<1024;i+=256) lh[i]=0;
  __syncthreads();
  unsigned pmask = (level==0)?0u:(0xFFFFFFFFu << (32-8*level));
  unsigned pref[4];
  for(int b=0;b<4;b++) pref[b]=state[b*4+0] & pmask;
  int shift = 24-8*level;
  size_t total = (size_t)N_B*PER_BATCH;
  for(size_t idx = (size_t)blockIdx.x*256+threadIdx.x; idx < total; idx += (size_t)gridDim.x*256){
    int b = (int)(idx / PER_BATCH);
    unsigned r = (unsigned)(idx - (size_t)b*PER_BATCH);
    int t = (int)((r>>7)&1023u);
    float val = probs[idx];
    if(!(mask[b*T_T+t] > -1.0f)) val = 0.0f;
    unsigned u = __float_as_uint(val);
    if((u & pmask) == pref[b]) atomicAdd(&lh[b*256+((u>>shift)&255u)],1u);
  }
  __syncthreads();
  for(int i=threadIdx.x;i<1024;i+=256){
    unsigned c = lh[i];
    if(c) atomicAdd(&hist[i], c);
  }
}

__global__ void topk_scan(unsigned* __restrict__ hist, unsigned* __restrict__ state, int level){
  int b = blockIdx.x;
  if(threadIdx.x==0){
    const unsigned* h = hist + b*256;
    unsigned remk = state[b*4+1];
    unsigned cum = 0; int sel=0;
    for(int bin=255; bin>=0; bin--){
      unsigned c = h[bin];
      if(remk <= cum + c){ sel=bin; break; }
      cum += c;
    }
    state[b*4+0] |= ((unsigned)sel) << (24-8*level);
    state[b*4+1] = remk - cum;
    state[b*4+2] += cum;
  }
  __syncthreads();
  for(int i=threadIdx.x;i<256;i+=blockDim.x) hist[b*256+i]=0;
}

__global__ __launch_bounds__(256) void topk_write(
    const float* __restrict__ probs, const float* __restrict__ mask,
    const unsigned* __restrict__ state, float* __restrict__ pam,
    unsigned* __restrict__ ties, unsigned* __restrict__ tiecnt){
  unsigned thr[4];
  for(int b=0;b<4;b++) thr[b]=state[b*4+0];
  size_t total=(size_t)N_B*PER_BATCH;
  for(size_t idx=(size_t)blockIdx.x*256+threadIdx.x; idx<total; idx += (size_t)gridDim.x*256){
    int b = (int)(idx / PER_BATCH);
    unsigned r = (unsigned)(idx - (size_t)b*PER_BATCH);
    int t = (int)((r>>7)&1023u);
    float val = probs[idx];
    if(!(mask[b*T_T+t] > -1.0f)) val=0.0f;
    unsigned u=__float_as_uint(val);
    float o = -10000.0f;
    if(u > thr[b]) o = 0.0f;
    else if(u == thr[b]){
      unsigned pos = atomicAdd(&tiecnt[b],1u);
      if(pos < 65536u) ties[(size_t)b*65536+pos]=r;
    }
    pam[idx]=o;
  }
}

__global__ __launch_bounds__(256) void topk_ties(
    const unsigned* __restrict__ state, const unsigned* __restrict__ ties,
    const unsigned* __restrict__ tiecnt, float* __restrict__ pam){
  int b = blockIdx.x;
  unsigned needed = state[b*4+1];
  unsigned nt = min(tiecnt[b], 65536u);
  __shared__ unsigned redu[256];
  __shared__ unsigned lohi[2];
  if(threadIdx.x==0){ lohi[0]=0u; lohi[1]=PER_BATCH; }
  __syncthreads();
  if(needed == 0 || nt == 0) return;
  while(true){
    __syncthreads();
    unsigned lo=lohi[0], hi=lohi[1];
    if(hi-lo<=1u) break;
    unsigned mid=(lo+hi)>>1;
    unsigned c=0;
    for(unsigned i=threadIdx.x;i<nt;i+=256) c += (ties[(size_t)b*65536+i] < mid)?1u:0u;
    redu[threadIdx.x]=c; __syncthreads();
    for(int o=128;o;o>>=1){ if(threadIdx.x<o) redu[threadIdx.x]+=redu[threadIdx.x+o]; __syncthreads(); }
    if(threadIdx.x==0){ if(redu[0]>=needed) lohi[1]=mid; else lohi[0]=mid; }
  }
  __syncthreads();
  unsigned X=lohi[1];
  for(unsigned i=threadIdx.x;i<nt;i+=256){
    unsigned r=ties[(size_t)b*65536+i];
    if(r < X) pam[(size_t)b*PER_BATCH + r]=0.0f;
  }
}

// ---------------- launcher ------------------------------------------------
extern "C" void kernel_launch(void* const* d_in, const int* in_sizes, int n_in,
                              void* d_out, int out_size, void* d_ws, size_t ws_size,
                              hipStream_t stream) {
  const float* v     = (const float*)d_in[2];
  const float* qfa   = (const float*)d_in[3];
  const float* kfa   = (const float*)d_in[4];
  const float* mask  = (const float*)d_in[8];
  const float* truth = (const float*)d_in[9];
  const float* pm    = (const float*)d_in[11];
  const float* encw  = (const float*)d_in[12];
  const float* encb  = (const float*)d_in[13];
  const float* lng   = (const float*)d_in[14];
  const float* lnb   = (const float*)d_in[15];
  const float* decw  = (const float*)d_in[16];
  const float* decb  = (const float*)d_in[17];
  float* out = (float*)d_out;
  float* ws  = (float*)d_ws;

  float* ctx     = ws;                              // 48*266*64 = 817152
  float* ksum    = ctx + (size_t)N_H*F_F*64;        // 12768
  float* klrow   = ksum + N_H*F_F;                  // 49152
  float* mserow  = klrow + N_H*T_T;                 // 49152
  unsigned* hist   = (unsigned*)(mserow + N_H*T_T); // 1024
  unsigned* state  = hist + 1024;                   // 16
  unsigned* tiecnt = state + 16;                    // 4 (+pad)
  unsigned* ties   = tiecnt + 12;                   // 4*65536
  float* diags   = (float*)(ties + 4*65536);        // 48*1024 = 49152
  float* ctxraw  = diags + N_H*T_T;                 // 48*266*64 = 817152
  float* ksumP   = ctxraw + (size_t)N_H*F_F*64;     // 48*266 = 12768
  float* mfP     = ksumP + N_H*F_F;                 // 48*19 = 912
  float* ksum_tot= mfP + 1024;                      // 48
  float* ctx_tot = ksum_tot + 48;                   // 3072

  float* pcl   = out + 1;
  float* probs = pcl + (size_t)N_H*T_T*D_H;
  float* pam   = probs + (size_t)N_H*T_T*TM_;

  diag_kern<<<dim3(N_H,4),256,0,stream>>>(kfa, diags);
  keyfeat_kern<<<dim3(N_H,NCH),256,0,stream>>>(kfa, pm, mask, diags, ctxraw, ksumP, mfP);
  fixup_kern<<<N_H,256,0,stream>>>(mfP, ksumP, ctxraw, mask, ctx, ksum, ksum_tot, ctx_tot);
  qfeat_kern<<<dim3(N_H,16),256,0,stream>>>(qfa, pm, ctx, ksum, ksum_tot, ctx_tot, pcl);
  mlp_kern<<<dim3(N_H,32),256,0,stream>>>(pcl, v, mask, encw, encb, lng, lnb,
                                          decw, decb, probs, pam /*score*/);
  loss_kern<<<N_H*T_T,256,0,stream>>>(truth, mask, pam /*score*/, klrow, mserow);
  finloss_kern<<<1,256,0,stream>>>(klrow, mserow, mask, out);
  topk_init<<<4,256,0,stream>>>(hist, state, tiecnt);
  for(int lvl=0;lvl<4;lvl++){
    topk_hist<<<2048,256,0,stream>>>(probs, mask, state, hist, lvl);
    topk_scan<<<4,64,0,stream>>>(hist, state, lvl);
  }
  topk_write<<<2048,256,0,stream>>>(probs, mask, state, pam, ties, tiecnt);
  topk_ties<<<4,256,0,stream>>>(state, ties, tiecnt, pam);
}